// Round 1
// baseline (5519.486 us; speedup 1.0000x reference)
//
#include <hip/hip_runtime.h>
#include <math.h>

#define N_ 8192
#define H_ 128
#define E_ 262144
#define K_ 16

// ---------------- degree / normalization ----------------
__global__ void k_deg_init(float* deg) {
  int i = blockIdx.x * 256 + threadIdx.x;
  deg[i] = 1.0f;  // self-loop weight
}

__global__ void k_deg_scatter(const int* __restrict__ ei, const float* __restrict__ ew,
                              float* deg) {
  int e = blockIdx.x * 256 + threadIdx.x;
  atomicAdd(&deg[ei[E_ + e]], ew[e]);
}

__global__ void k_dis(float* deg) {
  int i = blockIdx.x * 256 + threadIdx.x;
  deg[i] = rsqrtf(deg[i]);  // deg >= 1 always
}

// ---------------- generic [M x 128] @ [128 x 128] GEMM ----------------
// mode 0: B = W (128x128 row-major)
// mode 1: B built from w1 (256x64): B[k][c<64] = w1[k][c]-w1[128+k][c]; B[k][c>=64] = w1[128+k][c-64]
__global__ __launch_bounds__(256) void k_gemm128(const float* __restrict__ A,
                                                 const float* __restrict__ W,
                                                 float* __restrict__ C, int mode) {
  __shared__ float Bs[32 * 132];
  __shared__ float Ast[32 * 33];
  int t = threadIdx.x;
  int r0 = blockIdx.x * 32;
  int ty = t >> 4, tx = t & 15;
  float acc[2][8];
#pragma unroll
  for (int i = 0; i < 2; ++i)
#pragma unroll
    for (int j = 0; j < 8; ++j) acc[i][j] = 0.f;

  for (int kt = 0; kt < 4; ++kt) {
#pragma unroll
    for (int p = 0; p < 16; ++p) {
      int v = t + 256 * p;  // 4096
      int k = v >> 7, c = v & 127;
      int kg = kt * 32 + k;
      float val;
      if (mode == 0) val = W[kg * 128 + c];
      else val = (c < 64) ? (W[kg * 64 + c] - W[(128 + kg) * 64 + c])
                          : W[(128 + kg) * 64 + (c - 64)];
      Bs[k * 132 + c] = val;
    }
#pragma unroll
    for (int p = 0; p < 4; ++p) {
      int v = t + 256 * p;  // 1024
      int r = v >> 5, k = v & 31;
      Ast[k * 33 + r] = A[(r0 + r) * 128 + kt * 32 + k];
    }
    __syncthreads();
    for (int k = 0; k < 32; ++k) {
      float a0 = Ast[k * 33 + ty * 2];
      float a1 = Ast[k * 33 + ty * 2 + 1];
      float4 b0 = *(const float4*)&Bs[k * 132 + tx * 8];
      float4 b1 = *(const float4*)&Bs[k * 132 + tx * 8 + 4];
      float bb[8] = {b0.x, b0.y, b0.z, b0.w, b1.x, b1.y, b1.z, b1.w};
#pragma unroll
      for (int j = 0; j < 8; ++j) {
        acc[0][j] += a0 * bb[j];
        acc[1][j] += a1 * bb[j];
      }
    }
    __syncthreads();
  }
#pragma unroll
  for (int rr = 0; rr < 2; ++rr) {
    float4 o0 = {acc[rr][0], acc[rr][1], acc[rr][2], acc[rr][3]};
    float4 o1 = {acc[rr][4], acc[rr][5], acc[rr][6], acc[rr][7]};
    *(float4*)&C[(r0 + ty * 2 + rr) * 128 + tx * 8] = o0;
    *(float4*)&C[(r0 + ty * 2 + rr) * 128 + tx * 8 + 4] = o1;
  }
}

// ---------------- GCN aggregation ----------------
__global__ void k_gcn_init(const float* __restrict__ h, const float* __restrict__ dis,
                           float* acc) {
  int v = blockIdx.x * 256 + threadIdx.x;
  int i = v >> 7;
  float d = dis[i];
  acc[v] = d * d * h[v];  // self-loop: dis[i]*1*dis[i]*h[i]
}

__global__ void k_gcn_scatter(const int* __restrict__ ei, const float* __restrict__ ew,
                              const float* __restrict__ dis, const float* __restrict__ h,
                              float* acc) {
  int t = threadIdx.x;
  int e = blockIdx.x * 2 + (t >> 7);
  int c = t & 127;
  int s = ei[e], d2 = ei[E_ + e];
  float nm = dis[s] * ew[e] * dis[d2];
  atomicAdd(&acc[d2 * 128 + c], nm * h[s * 128 + c]);
}

__global__ void k_gcn_fin(const float* __restrict__ acc, const float* __restrict__ bg,
                          float* n_out, float* sn) {
  __shared__ float part[4];
  int t = threadIdx.x;
  int i = blockIdx.x * 2 + (t >> 7);
  int c = t & 127;
  float v = tanhf(acc[i * 128 + c] + bg[c]);
  n_out[i * 128 + c] = v;
  float vv = v * v;
#pragma unroll
  for (int off = 32; off; off >>= 1) vv += __shfl_down(vv, off, 64);
  if ((t & 63) == 0) part[t >> 6] = vv;
  __syncthreads();
  if ((t & 127) == 0) sn[i] = part[t >> 6] + part[(t >> 6) + 1];
}

// ---------------- transpose (for kNN staging) ----------------
__global__ void k_transpose(const float* __restrict__ n_in, float* __restrict__ nT) {
  __shared__ float tile[32][33];
  int t = threadIdx.x;
  int bi = blockIdx.x;  // node tile (256)
  int bc = blockIdx.y;  // col tile (4)
  int tx = t & 31, ty4 = t >> 5;  // ty4 0..7
#pragma unroll
  for (int p = 0; p < 4; ++p) {
    int ty = ty4 + p * 8;
    tile[ty][tx] = n_in[(bi * 32 + ty) * 128 + bc * 32 + tx];
  }
  __syncthreads();
#pragma unroll
  for (int p = 0; p < 4; ++p) {
    int ty = ty4 + p * 8;
    nT[(bc * 32 + ty) * N_ + bi * 32 + tx] = tile[tx][ty];
  }
}

// ---------------- fused kNN (distances + running top-16) ----------------
__global__ __launch_bounds__(256) void k_knn(const float* __restrict__ x,
                                             const float* __restrict__ xT,
                                             const float* __restrict__ sn,
                                             int* __restrict__ idxo) {
  __shared__ float xqs[32 * 128];     // 16 KB
  __shared__ float xjT[2 * 8 * 512];  // 32 KB (double-buffered f-chunks)
  __shared__ float Dbuf[128 * 32];    // 16 KB (swizzled dot tile quarter)
  int t = threadIdx.x;
  int q0 = blockIdx.x * 32;

#pragma unroll
  for (int p = 0; p < 4; ++p) {
    int v = t + 256 * p;  // 1024 float4
    int r = v >> 5, c4 = v & 31;
    *(float4*)&xqs[r * 128 + c4 * 4] = *(const float4*)&x[(q0 + r) * 128 + c4 * 4];
  }
  int qg = t >> 6;   // gemm query group 0..3
  int jg = t & 63;   // gemm j group
  int sq = t & 31;   // scan query
  int so = t >> 5;   // scan slice 0..7

  float topd[16];
  int topi[16];
#pragma unroll
  for (int s = 0; s < 16; ++s) { topd[s] = INFINITY; topi[s] = 0x7fffffff; }
  float wd = INFINITY; int wi = 0x7fffffff; int wslot = 15;
  float snq = sn[q0 + sq];
  __syncthreads();

  for (int jt = 0; jt < 16; ++jt) {
    int j0 = jt * 512;
    float acc[8][8];
#pragma unroll
    for (int qi = 0; qi < 8; ++qi)
#pragma unroll
      for (int jj = 0; jj < 8; ++jj) acc[qi][jj] = 0.f;

    for (int fc = 0; fc < 16; ++fc) {
      float* buf = &xjT[(fc & 1) * 4096];
#pragma unroll
      for (int p = 0; p < 4; ++p) {
        int v = t + 256 * p;  // 1024 float4
        int f = v >> 7, j4 = v & 127;
        *(float4*)&buf[f * 512 + j4 * 4] =
            *(const float4*)&xT[(fc * 8 + f) * N_ + j0 + j4 * 4];
      }
      __syncthreads();
      float xq[8][8];
#pragma unroll
      for (int qi = 0; qi < 8; ++qi) {
        *(float4*)&xq[qi][0] = *(const float4*)&xqs[(qg * 8 + qi) * 128 + fc * 8];
        *(float4*)&xq[qi][4] = *(const float4*)&xqs[(qg * 8 + qi) * 128 + fc * 8 + 4];
      }
#pragma unroll
      for (int f = 0; f < 8; ++f) {
        float4 xa = *(const float4*)&buf[f * 512 + jg * 4];
        float4 xb = *(const float4*)&buf[f * 512 + 256 + jg * 4];
        float aj[8] = {xa.x, xa.y, xa.z, xa.w, xb.x, xb.y, xb.z, xb.w};
#pragma unroll
        for (int qi = 0; qi < 8; ++qi) {
          float qv = xq[qi][f];
#pragma unroll
          for (int jj = 0; jj < 8; ++jj) acc[qi][jj] += qv * aj[jj];
        }
      }
      // double-buffered: one barrier per chunk is sufficient
    }

    // 4 quarters of 128 j's each: (qq&1)=jg-half, (qq>>1)=acc col-half
#pragma unroll
    for (int qq = 0; qq < 4; ++qq) {
      __syncthreads();  // protect Dbuf from previous readers
      if ((jg >> 5) == (qq & 1)) {
#pragma unroll
        for (int qi = 0; qi < 8; ++qi)
#pragma unroll
          for (int jc = 0; jc < 4; ++jc) {
            int row = (jg & 31) * 4 + jc;  // 0..127
            Dbuf[row * 32 + ((qg * 8 + qi) ^ (row & 31))] = acc[qi][(qq >> 1) * 4 + jc];
          }
      }
      __syncthreads();
      int jb = j0 + qq * 128;
      for (int jj = 0; jj < 16; ++jj) {
        int row = so * 16 + jj;
        float dot = Dbuf[row * 32 + (sq ^ (row & 31))];
        int jglob = jb + row;
        float d = snq + sn[jglob] - 2.f * dot;
        if (d < wd || (d == wd && jglob < wi)) {
#pragma unroll
          for (int s = 0; s < 16; ++s) {
            if (s == wslot) { topd[s] = d; topi[s] = jglob; }
          }
          float nd = topd[0]; int ni = topi[0]; int ns = 0;
#pragma unroll
          for (int s = 1; s < 16; ++s) {
            bool gt = (topd[s] > nd) || (topd[s] == nd && topi[s] > ni);
            if (gt) { nd = topd[s]; ni = topi[s]; ns = s; }
          }
          wd = nd; wi = ni; wslot = ns;
        }
      }
    }
  }

  // merge 8 slices x 16 candidates per query -> top 16
  float* cd = Dbuf;         // 32 x 128
  int* ci = (int*)xjT;      // 32 x 128
  __syncthreads();
#pragma unroll
  for (int s = 0; s < 16; ++s) {
    int col = (so * 16 + s) ^ (sq & 31);
    cd[sq * 128 + col] = topd[s];
    ci[sq * 128 + col] = topi[s];
  }
  __syncthreads();
  if (t < 32) {
    int q = t;
    for (int pass = 0; pass < 16; ++pass) {
      float bd = INFINITY; int bi = 0x7fffffff; int bs = 0;
      for (int ph = 0; ph < 128; ++ph) {
        float d = cd[q * 128 + ph];
        int ii = ci[q * 128 + ph];
        if (d < bd || (d == bd && ii < bi)) { bd = d; bi = ii; bs = ph; }
      }
      idxo[(q0 + q) * 16 + pass] = bi;
      cd[q * 128 + bs] = INFINITY;
      ci[q * 128 + bs] = 0x7fffffff;
    }
  }
}

// ---------------- fused EdgeConv MLP (h1 gather -> G2 -> G3 -> max) ----------------
__global__ __launch_bounds__(256) void k_mlp(const float* __restrict__ ab,
                                             const int* __restrict__ idx,
                                             const float* __restrict__ w2,
                                             const float* __restrict__ b1g,
                                             const float* __restrict__ b2g,
                                             const float* __restrict__ w3,
                                             const float* __restrict__ b3g,
                                             float* __restrict__ eout) {
  __shared__ float A1c[32 * 68];   // h1 k-chunk, [k][r] stride 68
  __shared__ float wc[32 * 128];   // w2/w3 k-tile
  __shared__ float H2t[128 * 68];  // h2 transposed, [k2][r] stride 68
  int t = threadIdx.x;
  int n0 = blockIdx.x * 4;  // 4 nodes = 64 rows
  int ty = t >> 4, tx = t & 15;

  float acc2[4][8];
#pragma unroll
  for (int i = 0; i < 4; ++i)
#pragma unroll
    for (int j = 0; j < 8; ++j) acc2[i][j] = 0.f;

  for (int kc = 0; kc < 2; ++kc) {
#pragma unroll
    for (int p = 0; p < 8; ++p) {
      int v = t + 256 * p;  // 2048
      int r = v >> 5, k = v & 31;
      int node = n0 + (r >> 4);
      int jn = idx[node * 16 + (r & 15)];
      int kk = kc * 32 + k;
      float val = ab[node * 128 + kk] + ab[jn * 128 + 64 + kk] + b1g[kk];
      A1c[k * 68 + r] = fmaxf(val, 0.f);
    }
#pragma unroll
    for (int p = 0; p < 16; ++p) {
      int v = t + 256 * p;  // 4096
      int k = v >> 7, c = v & 127;
      wc[k * 128 + c] = w2[(kc * 32 + k) * 128 + c];
    }
    __syncthreads();
    for (int k = 0; k < 32; ++k) {
      float4 a = *(const float4*)&A1c[k * 68 + ty * 4];
      float4 b0 = *(const float4*)&wc[k * 128 + tx * 8];
      float4 b1 = *(const float4*)&wc[k * 128 + tx * 8 + 4];
      float aa[4] = {a.x, a.y, a.z, a.w};
      float bb[8] = {b0.x, b0.y, b0.z, b0.w, b1.x, b1.y, b1.z, b1.w};
#pragma unroll
      for (int ri = 0; ri < 4; ++ri)
#pragma unroll
        for (int cii = 0; cii < 8; ++cii) acc2[ri][cii] += aa[ri] * bb[cii];
    }
    __syncthreads();
  }

  // h2 = relu(acc2 + b2) -> H2t transposed
#pragma unroll
  for (int cii = 0; cii < 8; ++cii) {
    float bb = b2g[tx * 8 + cii];
#pragma unroll
    for (int ri = 0; ri < 4; ++ri)
      H2t[(tx * 8 + cii) * 68 + ty * 4 + ri] = fmaxf(acc2[ri][cii] + bb, 0.f);
  }
  __syncthreads();

  float acc3[4][8];
#pragma unroll
  for (int i = 0; i < 4; ++i)
#pragma unroll
    for (int j = 0; j < 8; ++j) acc3[i][j] = 0.f;

  for (int kt = 0; kt < 4; ++kt) {
#pragma unroll
    for (int p = 0; p < 16; ++p) {
      int v = t + 256 * p;
      int k = v >> 7, c = v & 127;
      wc[k * 128 + c] = w3[(kt * 32 + k) * 128 + c];
    }
    __syncthreads();
    for (int k = 0; k < 32; ++k) {
      float4 a = *(const float4*)&H2t[(kt * 32 + k) * 68 + ty * 4];
      float4 b0 = *(const float4*)&wc[k * 128 + tx * 8];
      float4 b1 = *(const float4*)&wc[k * 128 + tx * 8 + 4];
      float aa[4] = {a.x, a.y, a.z, a.w};
      float bb[8] = {b0.x, b0.y, b0.z, b0.w, b1.x, b1.y, b1.z, b1.w};
#pragma unroll
      for (int ri = 0; ri < 4; ++ri)
#pragma unroll
        for (int cii = 0; cii < 8; ++cii) acc3[ri][cii] += aa[ri] * bb[cii];
    }
    __syncthreads();
  }

  // max over the thread's 4 rows (all same node), then across the 4 ty's of that node
  float* red = A1c;  // 16 x 128 fits in A1c area
#pragma unroll
  for (int cii = 0; cii < 8; ++cii) {
    float m = fmaxf(fmaxf(acc3[0][cii], acc3[1][cii]), fmaxf(acc3[2][cii], acc3[3][cii]));
    red[ty * 128 + tx * 8 + cii] = m;
  }
  __syncthreads();
#pragma unroll
  for (int p = 0; p < 2; ++p) {
    int v = t * 2 + p;
    int g = v >> 7, c = v & 127;
    float m = fmaxf(fmaxf(red[(g * 4 + 0) * 128 + c], red[(g * 4 + 1) * 128 + c]),
                    fmaxf(red[(g * 4 + 2) * 128 + c], red[(g * 4 + 3) * 128 + c]));
    eout[(n0 + g) * 128 + c] = m + b3g[c];
  }
}

// ---------------- small epilogues ----------------
__global__ void k_e1n1(const float* __restrict__ e1, const float* __restrict__ n1,
                       float* s1) {
  int t = threadIdx.x;
  int node = blockIdx.x * 4 + (t >> 6);
  int lane = t & 63;
  float v0 = e1[node * 128 + lane] + n1[node * 128 + lane];
  float v1 = e1[node * 128 + 64 + lane] + n1[node * 128 + 64 + lane];
  float ss = v0 * v0 + v1 * v1;
#pragma unroll
  for (int off = 32; off; off >>= 1) ss += __shfl_down(ss, off, 64);
  if (lane == 0) s1[node] = sqrtf(ss);
}

__global__ void k_addinto(float* __restrict__ e, const float* __restrict__ n) {
  int v = blockIdx.x * 256 + threadIdx.x;
  e[v] += n[v];
}

__global__ void k_final(const float* __restrict__ s1, const float* __restrict__ e2n2,
                        const float* __restrict__ e3n3, float* __restrict__ out) {
  int t = threadIdx.x;
  int node = blockIdx.x * 4 + (t >> 6);
  int lane = t & 63;
  float s = s1[node];
  float z0 = s * e2n2[node * 128 + lane] * e3n3[node * 128 + lane];
  float z1 = s * e2n2[node * 128 + 64 + lane] * e3n3[node * 128 + 64 + lane];
  float m = fmaxf(z0, z1);
#pragma unroll
  for (int off = 32; off; off >>= 1) m = fmaxf(m, __shfl_xor(m, off, 64));
  float ex = expf(z0 - m) + expf(z1 - m);
#pragma unroll
  for (int off = 32; off; off >>= 1) ex += __shfl_xor(ex, off, 64);
  float lse = m + logf(ex);
  out[node * 128 + lane] = z0 - lse;
  out[node * 128 + 64 + lane] = z1 - lse;
}

// ---------------- host ----------------
extern "C" void kernel_launch(void* const* d_in, const int* in_sizes, int n_in,
                              void* d_out, int out_size, void* d_ws, size_t ws_size,
                              hipStream_t stream) {
  (void)in_sizes; (void)n_in; (void)out_size;
  const float* x  = (const float*)d_in[0];
  const int* ei   = (const int*)d_in[1];
  const float* ew = (const float*)d_in[2];
  const float* wg[3] = {(const float*)d_in[3], (const float*)d_in[5], (const float*)d_in[7]};
  const float* bg[3] = {(const float*)d_in[4], (const float*)d_in[6], (const float*)d_in[8]};
  const float* ew1[3] = {(const float*)d_in[9],  (const float*)d_in[15], (const float*)d_in[21]};
  const float* eb1[3] = {(const float*)d_in[10], (const float*)d_in[16], (const float*)d_in[22]};
  const float* ew2[3] = {(const float*)d_in[11], (const float*)d_in[17], (const float*)d_in[23]};
  const float* eb2[3] = {(const float*)d_in[12], (const float*)d_in[18], (const float*)d_in[24]};
  const float* ew3[3] = {(const float*)d_in[13], (const float*)d_in[19], (const float*)d_in[25]};
  const float* eb3[3] = {(const float*)d_in[14], (const float*)d_in[20], (const float*)d_in[26]};

  size_t need = (size_t)(19 * N_ + 8 * N_ * H_) * sizeof(float);
  if (ws_size < need) return;  // fail loudly via poisoned output

  float* ws  = (float*)d_ws;
  float* dis = ws;                    // N
  float* sn  = ws + N_;               // N
  float* S1  = ws + 2 * N_;           // N
  int* idx   = (int*)(ws + 3 * N_);   // N*16 ints
  float* h   = ws + 19 * N_;
  float* n1  = h + N_ * H_;
  float* n2  = n1 + N_ * H_;
  float* n3  = n2 + N_ * H_;
  float* E1  = n3 + N_ * H_;          // e1, then e3/e3+n3
  float* E2  = E1 + N_ * H_;          // e2, then e2+n2
  float* ab  = E2 + N_ * H_;
  float* nT  = ab + N_ * H_;

  float* nl[3] = {n1, n2, n3};

  k_deg_init<<<N_ / 256, 256, 0, stream>>>(dis);
  k_deg_scatter<<<E_ / 256, 256, 0, stream>>>(ei, ew, dis);
  k_dis<<<N_ / 256, 256, 0, stream>>>(dis);

  for (int l = 0; l < 3; ++l) {
    const float* inp = (l == 0) ? x : nl[l - 1];
    k_gemm128<<<256, 256, 0, stream>>>(inp, wg[l], h, 0);
    k_gcn_init<<<N_ * H_ / 256, 256, 0, stream>>>(h, dis, nl[l]);
    k_gcn_scatter<<<E_ / 2, 256, 0, stream>>>(ei, ew, dis, h, nl[l]);
    k_gcn_fin<<<N_ / 2, 256, 0, stream>>>(nl[l], bg[l], nl[l], sn);
    k_transpose<<<dim3(256, 4), 256, 0, stream>>>(nl[l], nT);
    k_knn<<<256, 256, 0, stream>>>(nl[l], nT, sn, idx);
    k_gemm128<<<256, 256, 0, stream>>>(nl[l], ew1[l], ab, 1);
    float* etgt = (l == 1) ? E2 : E1;
    k_mlp<<<N_ / 4, 256, 0, stream>>>(ab, idx, ew2[l], eb1[l], eb2[l], ew3[l], eb3[l], etgt);
    if (l == 0) k_e1n1<<<N_ / 4, 256, 0, stream>>>(E1, n1, S1);
    if (l == 1) k_addinto<<<N_ * H_ / 256, 256, 0, stream>>>(E2, n2);
    if (l == 2) k_addinto<<<N_ * H_ / 256, 256, 0, stream>>>(E1, n3);
  }
  k_final<<<N_ / 4, 256, 0, stream>>>(S1, E2, E1, (float*)d_out);
}

// Round 2
// 3792.120 us; speedup vs baseline: 1.4555x; 1.4555x over previous
//
#include <hip/hip_runtime.h>
#include <math.h>

#define N_ 8192
#define H_ 128
#define E_ 262144
#define K_ 16
#define SLABJ 2048

typedef __attribute__((ext_vector_type(8))) short bshort8;
typedef __attribute__((ext_vector_type(16))) float f32x16;

// ---------------- degree / normalization ----------------
__global__ void k_deg_init(float* deg) {
  int i = blockIdx.x * 256 + threadIdx.x;
  deg[i] = 1.0f;  // self-loop weight
}

__global__ void k_deg_scatter(const int* __restrict__ ei, const float* __restrict__ ew,
                              float* deg) {
  int e = blockIdx.x * 256 + threadIdx.x;
  atomicAdd(&deg[ei[E_ + e]], ew[e]);
}

__global__ void k_dis(float* deg) {
  int i = blockIdx.x * 256 + threadIdx.x;
  deg[i] = rsqrtf(deg[i]);  // deg >= 1 always
}

// ---------------- generic [M x 128] @ [128 x 128] GEMM ----------------
__global__ __launch_bounds__(256) void k_gemm128(const float* __restrict__ A,
                                                 const float* __restrict__ W,
                                                 float* __restrict__ C, int mode) {
  __shared__ float Bs[32 * 132];
  __shared__ float Ast[32 * 33];
  int t = threadIdx.x;
  int r0 = blockIdx.x * 32;
  int ty = t >> 4, tx = t & 15;
  float acc[2][8];
#pragma unroll
  for (int i = 0; i < 2; ++i)
#pragma unroll
    for (int j = 0; j < 8; ++j) acc[i][j] = 0.f;

  for (int kt = 0; kt < 4; ++kt) {
#pragma unroll
    for (int p = 0; p < 16; ++p) {
      int v = t + 256 * p;  // 4096
      int k = v >> 7, c = v & 127;
      int kg = kt * 32 + k;
      float val;
      if (mode == 0) val = W[kg * 128 + c];
      else val = (c < 64) ? (W[kg * 64 + c] - W[(128 + kg) * 64 + c])
                          : W[(128 + kg) * 64 + (c - 64)];
      Bs[k * 132 + c] = val;
    }
#pragma unroll
    for (int p = 0; p < 4; ++p) {
      int v = t + 256 * p;  // 1024
      int r = v >> 5, k = v & 31;
      Ast[k * 33 + r] = A[(r0 + r) * 128 + kt * 32 + k];
    }
    __syncthreads();
    for (int k = 0; k < 32; ++k) {
      float a0 = Ast[k * 33 + ty * 2];
      float a1 = Ast[k * 33 + ty * 2 + 1];
      float4 b0 = *(const float4*)&Bs[k * 132 + tx * 8];
      float4 b1 = *(const float4*)&Bs[k * 132 + tx * 8 + 4];
      float bb[8] = {b0.x, b0.y, b0.z, b0.w, b1.x, b1.y, b1.z, b1.w};
#pragma unroll
      for (int j = 0; j < 8; ++j) {
        acc[0][j] += a0 * bb[j];
        acc[1][j] += a1 * bb[j];
      }
    }
    __syncthreads();
  }
#pragma unroll
  for (int rr = 0; rr < 2; ++rr) {
    float4 o0 = {acc[rr][0], acc[rr][1], acc[rr][2], acc[rr][3]};
    float4 o1 = {acc[rr][4], acc[rr][5], acc[rr][6], acc[rr][7]};
    *(float4*)&C[(r0 + ty * 2 + rr) * 128 + tx * 8] = o0;
    *(float4*)&C[(r0 + ty * 2 + rr) * 128 + tx * 8 + 4] = o1;
  }
}

// ---------------- GCN aggregation ----------------
__global__ void k_gcn_init(const float* __restrict__ h, const float* __restrict__ dis,
                           float* acc) {
  int v = blockIdx.x * 256 + threadIdx.x;
  int i = v >> 7;
  float d = dis[i];
  acc[v] = d * d * h[v];
}

__global__ void k_gcn_scatter(const int* __restrict__ ei, const float* __restrict__ ew,
                              const float* __restrict__ dis, const float* __restrict__ h,
                              float* acc) {
  int t = threadIdx.x;
  int e = blockIdx.x * 2 + (t >> 7);
  int c = t & 127;
  int s = ei[e], d2 = ei[E_ + e];
  float nm = dis[s] * ew[e] * dis[d2];
  atomicAdd(&acc[d2 * 128 + c], nm * h[s * 128 + c]);
}

__global__ void k_gcn_fin(const float* __restrict__ acc, const float* __restrict__ bg,
                          float* n_out, float* sn) {
  __shared__ float part[4];
  int t = threadIdx.x;
  int i = blockIdx.x * 2 + (t >> 7);
  int c = t & 127;
  float v = tanhf(acc[i * 128 + c] + bg[c]);
  n_out[i * 128 + c] = v;
  float vv = v * v;
#pragma unroll
  for (int off = 32; off; off >>= 1) vv += __shfl_down(vv, off, 64);
  if ((t & 63) == 0) part[t >> 6] = vv;
  __syncthreads();
  if ((t & 127) == 0) sn[i] = part[t >> 6] + part[(t >> 6) + 1];
}

// ---------------- bf16 hi/lo split + MFMA fragment packing ----------------
__device__ __forceinline__ unsigned short f2bf_rne(float x) {
  unsigned u = __builtin_bit_cast(unsigned, x);
  unsigned r = ((u >> 16) & 1u) + 0x7fffu;
  return (unsigned short)((u + r) >> 16);
}
__device__ __forceinline__ float bf2f(unsigned short b) {
  unsigned u = ((unsigned)b) << 16;
  return __builtin_bit_cast(float, u);
}

// src: [N][128] fp32 -> fragHi/fragLo: [N/32 tiles][8 ks][64 lanes][8 bf16]
// lane = khalf*32 + (row&31); the lane's 8 elems are k = ks*16 + khalf*8 + i
__global__ void k_fragprep(const float* __restrict__ src, bshort8* __restrict__ hiA,
                           bshort8* __restrict__ loA) {
  int t = blockIdx.x * 256 + threadIdx.x;  // N*16 threads
  int j = t >> 4, slot = t & 15;
  const float* p = src + j * 128 + slot * 8;
  float4 f0 = *(const float4*)p;
  float4 f1 = *(const float4*)(p + 4);
  float f[8] = {f0.x, f0.y, f0.z, f0.w, f1.x, f1.y, f1.z, f1.w};
  bshort8 h, l;
#pragma unroll
  for (int i = 0; i < 8; ++i) {
    unsigned short hb = f2bf_rne(f[i]);
    float lf = f[i] - bf2f(hb);
    h[i] = (short)hb;
    l[i] = (short)f2bf_rne(lf);
  }
  int ks = slot >> 1, half = slot & 1;
  int dst = ((j >> 5) * 8 + ks) * 64 + half * 32 + (j & 31);
  hiA[dst] = h;
  loA[dst] = l;
}

// ---------------- MFMA kNN: Gram tiles + in-register top-16 ----------------
// A operand = j rows (M), B operand = 32 queries of this block (N).
// C layout: col = lane&31 = query (fixed per lane!), rows = 16 j's per lane.
__global__ __launch_bounds__(256, 2) void k_knn(const bshort8* __restrict__ fragHi,
                                                const bshort8* __restrict__ fragLo,
                                                const float* __restrict__ sn,
                                                float* __restrict__ candD,
                                                int* __restrict__ candI) {
  __shared__ float snS[SLABJ];     // 8 KB
  __shared__ float cd[32 * 129];   // 16.1 KB
  __shared__ int ci[32 * 129];     // 16.1 KB
  int t = threadIdx.x;
  int qtile = blockIdx.x, slab = blockIdx.y;
  int wave = t >> 6, lane = t & 63;
  int q = lane & 31, half = lane >> 5;

#pragma unroll
  for (int p = 0; p < 8; ++p) snS[t + 256 * p] = sn[slab * SLABJ + t + 256 * p];

  // resident B fragments: this block's 32 queries
  bshort8 bHi[8], bLo[8];
#pragma unroll
  for (int ks = 0; ks < 8; ++ks) {
    int o = (qtile * 8 + ks) * 64 + lane;
    bHi[ks] = fragHi[o];
    bLo[ks] = fragLo[o];
  }
  __syncthreads();

  float topd[16];
  int topi[16];
#pragma unroll
  for (int s = 0; s < 16; ++s) { topd[s] = INFINITY; topi[s] = 0x7fffffff; }
  float wd = INFINITY;
  int wi = 0x7fffffff, wslot = 15;

  for (int ti = 0; ti < 16; ++ti) {
    int jt = slab * 64 + wave * 16 + ti;  // global 32-row tile index
    bshort8 aHi[8], aLo[8];
#pragma unroll
    for (int ks = 0; ks < 8; ++ks) {
      int o = (jt * 8 + ks) * 64 + lane;
      aHi[ks] = fragHi[o];
      aLo[ks] = fragLo[o];
    }
    f32x16 acc;
#pragma unroll
    for (int r = 0; r < 16; ++r) acc[r] = 0.f;
#pragma unroll
    for (int ks = 0; ks < 8; ++ks) {
      acc = __builtin_amdgcn_mfma_f32_32x32x16_bf16(aLo[ks], bHi[ks], acc, 0, 0, 0);
      acc = __builtin_amdgcn_mfma_f32_32x32x16_bf16(aHi[ks], bLo[ks], acc, 0, 0, 0);
      acc = __builtin_amdgcn_mfma_f32_32x32x16_bf16(aHi[ks], bHi[ks], acc, 0, 0, 0);
    }
    int jbase = (wave * 16 + ti) * 32;  // slab-local
#pragma unroll
    for (int r = 0; r < 16; ++r) {
      int row = (r & 3) + 8 * (r >> 2) + 4 * half;
      int jl = jbase + row;
      float key = snS[jl] - 2.0f * acc[r];  // snq dropped: constant per query
      int jg = slab * SLABJ + jl;
      if (key < wd || (key == wd && jg < wi)) {
#pragma unroll
        for (int s = 0; s < 16; ++s)
          if (s == wslot) { topd[s] = key; topi[s] = jg; }
        float nd = topd[0];
        int ni = topi[0], ns = 0;
#pragma unroll
        for (int s = 1; s < 16; ++s) {
          bool gt = (topd[s] > nd) || (topd[s] == nd && topi[s] > ni);
          if (gt) { nd = topd[s]; ni = topi[s]; ns = s; }
        }
        wd = nd; wi = ni; wslot = ns;
      }
    }
  }

  // dump 8 partial lists per query (wave*2+half), pad stride 129 (conflict-free)
  int g = wave * 2 + half;
#pragma unroll
  for (int s = 0; s < 16; ++s) {
    cd[q * 129 + g * 16 + s] = topd[s];
    ci[q * 129 + g * 16 + s] = topi[s];
  }
  __syncthreads();

  if (t < 32) {
    float td[16]; int tix[16];
#pragma unroll
    for (int s = 0; s < 16; ++s) { td[s] = INFINITY; tix[s] = 0x7fffffff; }
    float w2 = INFINITY; int w2i = 0x7fffffff, w2s = 15;
    for (int i = 0; i < 128; ++i) {
      float d = cd[t * 129 + i];
      int ii = ci[t * 129 + i];
      if (d < w2 || (d == w2 && ii < w2i)) {
#pragma unroll
        for (int s = 0; s < 16; ++s)
          if (s == w2s) { td[s] = d; tix[s] = ii; }
        float nd = td[0]; int ni = tix[0], ns = 0;
#pragma unroll
        for (int s = 1; s < 16; ++s) {
          bool gt = (td[s] > nd) || (td[s] == nd && tix[s] > ni);
          if (gt) { nd = td[s]; ni = tix[s]; ns = s; }
        }
        w2 = nd; w2i = ni; w2s = ns;
      }
    }
#pragma unroll
    for (int s = 0; s < 16; ++s) {
      candD[(slab * 16 + s) * N_ + qtile * 32 + t] = td[s];
      candI[(slab * 16 + s) * N_ + qtile * 32 + t] = tix[s];
    }
  }
}

// merge 4 slabs x 16 candidates -> final 16 (set; order irrelevant for max-agg)
__global__ void k_knnmerge(const float* __restrict__ candD, const int* __restrict__ candI,
                           int* __restrict__ idxo) {
  int qg = blockIdx.x * 256 + threadIdx.x;
  float td[16]; int tix[16];
#pragma unroll
  for (int s = 0; s < 16; ++s) { td[s] = INFINITY; tix[s] = 0x7fffffff; }
  float wd = INFINITY; int wi = 0x7fffffff, ws = 15;
  for (int i = 0; i < 64; ++i) {
    float d = candD[i * N_ + qg];
    int ii = candI[i * N_ + qg];
    if (d < wd || (d == wd && ii < wi)) {
#pragma unroll
      for (int s = 0; s < 16; ++s)
        if (s == ws) { td[s] = d; tix[s] = ii; }
      float nd = td[0]; int ni = tix[0], ns = 0;
#pragma unroll
      for (int s = 1; s < 16; ++s) {
        bool gt = (td[s] > nd) || (td[s] == nd && tix[s] > ni);
        if (gt) { nd = td[s]; ni = tix[s]; ns = s; }
      }
      wd = nd; wi = ni; ws = ns;
    }
  }
#pragma unroll
  for (int s = 0; s < 16; ++s) idxo[qg * 16 + s] = tix[s];
}

// ---------------- fused EdgeConv MLP (h1 gather -> G2 -> G3 -> max) ----------------
__global__ __launch_bounds__(256) void k_mlp(const float* __restrict__ ab,
                                             const int* __restrict__ idx,
                                             const float* __restrict__ w2,
                                             const float* __restrict__ b1g,
                                             const float* __restrict__ b2g,
                                             const float* __restrict__ w3,
                                             const float* __restrict__ b3g,
                                             float* __restrict__ eout) {
  __shared__ float A1c[32 * 68];
  __shared__ float wc[32 * 128];
  __shared__ float H2t[128 * 68];
  int t = threadIdx.x;
  int n0 = blockIdx.x * 4;
  int ty = t >> 4, tx = t & 15;

  float acc2[4][8];
#pragma unroll
  for (int i = 0; i < 4; ++i)
#pragma unroll
    for (int j = 0; j < 8; ++j) acc2[i][j] = 0.f;

  for (int kc = 0; kc < 2; ++kc) {
#pragma unroll
    for (int p = 0; p < 8; ++p) {
      int v = t + 256 * p;
      int r = v >> 5, k = v & 31;
      int node = n0 + (r >> 4);
      int jn = idx[node * 16 + (r & 15)];
      int kk = kc * 32 + k;
      float val = ab[node * 128 + kk] + ab[jn * 128 + 64 + kk] + b1g[kk];
      A1c[k * 68 + r] = fmaxf(val, 0.f);
    }
#pragma unroll
    for (int p = 0; p < 16; ++p) {
      int v = t + 256 * p;
      int k = v >> 7, c = v & 127;
      wc[k * 128 + c] = w2[(kc * 32 + k) * 128 + c];
    }
    __syncthreads();
    for (int k = 0; k < 32; ++k) {
      float4 a = *(const float4*)&A1c[k * 68 + ty * 4];
      float4 b0 = *(const float4*)&wc[k * 128 + tx * 8];
      float4 b1 = *(const float4*)&wc[k * 128 + tx * 8 + 4];
      float aa[4] = {a.x, a.y, a.z, a.w};
      float bb[8] = {b0.x, b0.y, b0.z, b0.w, b1.x, b1.y, b1.z, b1.w};
#pragma unroll
      for (int ri = 0; ri < 4; ++ri)
#pragma unroll
        for (int cii = 0; cii < 8; ++cii) acc2[ri][cii] += aa[ri] * bb[cii];
    }
    __syncthreads();
  }

#pragma unroll
  for (int cii = 0; cii < 8; ++cii) {
    float bb = b2g[tx * 8 + cii];
#pragma unroll
    for (int ri = 0; ri < 4; ++ri)
      H2t[(tx * 8 + cii) * 68 + ty * 4 + ri] = fmaxf(acc2[ri][cii] + bb, 0.f);
  }
  __syncthreads();

  float acc3[4][8];
#pragma unroll
  for (int i = 0; i < 4; ++i)
#pragma unroll
    for (int j = 0; j < 8; ++j) acc3[i][j] = 0.f;

  for (int kt = 0; kt < 4; ++kt) {
#pragma unroll
    for (int p = 0; p < 16; ++p) {
      int v = t + 256 * p;
      int k = v >> 7, c = v & 127;
      wc[k * 128 + c] = w3[(kt * 32 + k) * 128 + c];
    }
    __syncthreads();
    for (int k = 0; k < 32; ++k) {
      float4 a = *(const float4*)&H2t[(kt * 32 + k) * 68 + ty * 4];
      float4 b0 = *(const float4*)&wc[k * 128 + tx * 8];
      float4 b1 = *(const float4*)&wc[k * 128 + tx * 8 + 4];
      float aa[4] = {a.x, a.y, a.z, a.w};
      float bb[8] = {b0.x, b0.y, b0.z, b0.w, b1.x, b1.y, b1.z, b1.w};
#pragma unroll
      for (int ri = 0; ri < 4; ++ri)
#pragma unroll
        for (int cii = 0; cii < 8; ++cii) acc3[ri][cii] += aa[ri] * bb[cii];
    }
    __syncthreads();
  }

  float* red = A1c;
#pragma unroll
  for (int cii = 0; cii < 8; ++cii) {
    float m = fmaxf(fmaxf(acc3[0][cii], acc3[1][cii]), fmaxf(acc3[2][cii], acc3[3][cii]));
    red[ty * 128 + tx * 8 + cii] = m;
  }
  __syncthreads();
#pragma unroll
  for (int p = 0; p < 2; ++p) {
    int v = t * 2 + p;
    int g = v >> 7, c = v & 127;
    float m = fmaxf(fmaxf(red[(g * 4 + 0) * 128 + c], red[(g * 4 + 1) * 128 + c]),
                    fmaxf(red[(g * 4 + 2) * 128 + c], red[(g * 4 + 3) * 128 + c]));
    eout[(n0 + g) * 128 + c] = m + b3g[c];
  }
}

// ---------------- small epilogues ----------------
__global__ void k_e1n1(const float* __restrict__ e1, const float* __restrict__ n1,
                       float* s1) {
  int t = threadIdx.x;
  int node = blockIdx.x * 4 + (t >> 6);
  int lane = t & 63;
  float v0 = e1[node * 128 + lane] + n1[node * 128 + lane];
  float v1 = e1[node * 128 + 64 + lane] + n1[node * 128 + 64 + lane];
  float ss = v0 * v0 + v1 * v1;
#pragma unroll
  for (int off = 32; off; off >>= 1) ss += __shfl_down(ss, off, 64);
  if (lane == 0) s1[node] = sqrtf(ss);
}

__global__ void k_addinto(float* __restrict__ e, const float* __restrict__ n) {
  int v = blockIdx.x * 256 + threadIdx.x;
  e[v] += n[v];
}

__global__ void k_final(const float* __restrict__ s1, const float* __restrict__ e2n2,
                        const float* __restrict__ e3n3, float* __restrict__ out) {
  int t = threadIdx.x;
  int node = blockIdx.x * 4 + (t >> 6);
  int lane = t & 63;
  float s = s1[node];
  float z0 = s * e2n2[node * 128 + lane] * e3n3[node * 128 + lane];
  float z1 = s * e2n2[node * 128 + 64 + lane] * e3n3[node * 128 + 64 + lane];
  float m = fmaxf(z0, z1);
#pragma unroll
  for (int off = 32; off; off >>= 1) m = fmaxf(m, __shfl_xor(m, off, 64));
  float ex = expf(z0 - m) + expf(z1 - m);
#pragma unroll
  for (int off = 32; off; off >>= 1) ex += __shfl_xor(ex, off, 64);
  float lse = m + logf(ex);
  out[node * 128 + lane] = z0 - lse;
  out[node * 128 + 64 + lane] = z1 - lse;
}

// ---------------- host ----------------
extern "C" void kernel_launch(void* const* d_in, const int* in_sizes, int n_in,
                              void* d_out, int out_size, void* d_ws, size_t ws_size,
                              hipStream_t stream) {
  (void)in_sizes; (void)n_in; (void)out_size;
  const float* x  = (const float*)d_in[0];
  const int* ei   = (const int*)d_in[1];
  const float* ew = (const float*)d_in[2];
  const float* wg[3] = {(const float*)d_in[3], (const float*)d_in[5], (const float*)d_in[7]};
  const float* bg[3] = {(const float*)d_in[4], (const float*)d_in[6], (const float*)d_in[8]};
  const float* ew1[3] = {(const float*)d_in[9],  (const float*)d_in[15], (const float*)d_in[21]};
  const float* eb1[3] = {(const float*)d_in[10], (const float*)d_in[16], (const float*)d_in[22]};
  const float* ew2[3] = {(const float*)d_in[11], (const float*)d_in[17], (const float*)d_in[23]};
  const float* eb2[3] = {(const float*)d_in[12], (const float*)d_in[18], (const float*)d_in[24]};
  const float* ew3[3] = {(const float*)d_in[13], (const float*)d_in[19], (const float*)d_in[25]};
  const float* eb3[3] = {(const float*)d_in[14], (const float*)d_in[20], (const float*)d_in[26]};

  size_t need = (size_t)(19 * N_ + 7 * N_ * H_) * sizeof(float);
  if (ws_size < need) return;

  float* ws  = (float*)d_ws;
  float* dis = ws;                    // N
  float* sn  = ws + N_;               // N
  float* S1  = ws + 2 * N_;           // N
  int* idx   = (int*)(ws + 3 * N_);   // N*16 ints
  float* h   = ws + 19 * N_;          // N*H (doubles as frag arrays)
  float* n1  = h + N_ * H_;
  float* n2  = n1 + N_ * H_;
  float* n3  = n2 + N_ * H_;
  float* E1  = n3 + N_ * H_;
  float* E2  = E1 + N_ * H_;
  float* ab  = E2 + N_ * H_;          // N*H (doubles as cand arrays)

  // frag arrays alias h (free between gcn_fin and next layer's gemm)
  bshort8* fragHi = (bshort8*)h;                      // 2 MB
  bshort8* fragLo = (bshort8*)(h + N_ * H_ / 2);      // 2 MB
  // candidate arrays alias ab (free until mode-1 gemm)
  float* candD = ab;                                  // 64*N floats
  int*   candI = (int*)(ab + 64 * N_);

  float* nl[3] = {n1, n2, n3};

  k_deg_init<<<N_ / 256, 256, 0, stream>>>(dis);
  k_deg_scatter<<<E_ / 256, 256, 0, stream>>>(ei, ew, dis);
  k_dis<<<N_ / 256, 256, 0, stream>>>(dis);

  for (int l = 0; l < 3; ++l) {
    const float* inp = (l == 0) ? x : nl[l - 1];
    k_gemm128<<<256, 256, 0, stream>>>(inp, wg[l], h, 0);
    k_gcn_init<<<N_ * H_ / 256, 256, 0, stream>>>(h, dis, nl[l]);
    k_gcn_scatter<<<E_ / 2, 256, 0, stream>>>(ei, ew, dis, h, nl[l]);
    k_gcn_fin<<<N_ / 2, 256, 0, stream>>>(nl[l], bg[l], nl[l], sn);
    k_fragprep<<<N_ * 16 / 256, 256, 0, stream>>>(nl[l], fragHi, fragLo);
    k_knn<<<dim3(N_ / 32, 4), 256, 0, stream>>>(fragHi, fragLo, sn, candD, candI);
    k_knnmerge<<<N_ / 256, 256, 0, stream>>>(candD, candI, idx);
    k_gemm128<<<256, 256, 0, stream>>>(nl[l], ew1[l], ab, 1);
    float* etgt = (l == 1) ? E2 : E1;
    k_mlp<<<N_ / 4, 256, 0, stream>>>(ab, idx, ew2[l], eb1[l], eb2[l], ew3[l], eb3[l], etgt);
    if (l == 0) k_e1n1<<<N_ / 4, 256, 0, stream>>>(E1, n1, S1);
    if (l == 1) k_addinto<<<N_ * H_ / 256, 256, 0, stream>>>(E2, n2);
    if (l == 2) k_addinto<<<N_ * H_ / 256, 256, 0, stream>>>(E1, n3);
  }
  k_final<<<N_ / 4, 256, 0, stream>>>(S1, E2, E1, (float*)d_out);
}

// Round 3
// 2317.086 us; speedup vs baseline: 2.3821x; 1.6366x over previous
//
#include <hip/hip_runtime.h>
#include <math.h>

#define N_ 8192
#define H_ 128
#define E_ 262144
#define K_ 16
#define SLABJ 1024

typedef __attribute__((ext_vector_type(8))) short bshort8;
typedef __attribute__((ext_vector_type(16))) float f32x16;

// ---------------- degree / normalization ----------------
__global__ void k_deg_init(float* deg) {
  int i = blockIdx.x * 256 + threadIdx.x;
  deg[i] = 1.0f;  // self-loop weight
}

__global__ void k_deg_scatter(const int* __restrict__ ei, const float* __restrict__ ew,
                              float* deg) {
  int e = blockIdx.x * 256 + threadIdx.x;
  atomicAdd(&deg[ei[E_ + e]], ew[e]);
}

__global__ void k_dis(float* deg) {
  int i = blockIdx.x * 256 + threadIdx.x;
  deg[i] = rsqrtf(deg[i]);  // deg >= 1 always
}

// ---------------- generic [M x 128] @ [128 x 128] GEMM ----------------
__global__ __launch_bounds__(256) void k_gemm128(const float* __restrict__ A,
                                                 const float* __restrict__ W,
                                                 float* __restrict__ C, int mode) {
  __shared__ float Bs[32 * 132];
  __shared__ float Ast[32 * 33];
  int t = threadIdx.x;
  int r0 = blockIdx.x * 32;
  int ty = t >> 4, tx = t & 15;
  float acc[2][8];
#pragma unroll
  for (int i = 0; i < 2; ++i)
#pragma unroll
    for (int j = 0; j < 8; ++j) acc[i][j] = 0.f;

  for (int kt = 0; kt < 4; ++kt) {
#pragma unroll
    for (int p = 0; p < 16; ++p) {
      int v = t + 256 * p;  // 4096
      int k = v >> 7, c = v & 127;
      int kg = kt * 32 + k;
      float val;
      if (mode == 0) val = W[kg * 128 + c];
      else val = (c < 64) ? (W[kg * 64 + c] - W[(128 + kg) * 64 + c])
                          : W[(128 + kg) * 64 + (c - 64)];
      Bs[k * 132 + c] = val;
    }
#pragma unroll
    for (int p = 0; p < 4; ++p) {
      int v = t + 256 * p;  // 1024
      int r = v >> 5, k = v & 31;
      Ast[k * 33 + r] = A[(r0 + r) * 128 + kt * 32 + k];
    }
    __syncthreads();
    for (int k = 0; k < 32; ++k) {
      float a0 = Ast[k * 33 + ty * 2];
      float a1 = Ast[k * 33 + ty * 2 + 1];
      float4 b0 = *(const float4*)&Bs[k * 132 + tx * 8];
      float4 b1 = *(const float4*)&Bs[k * 132 + tx * 8 + 4];
      float bb[8] = {b0.x, b0.y, b0.z, b0.w, b1.x, b1.y, b1.z, b1.w};
#pragma unroll
      for (int j = 0; j < 8; ++j) {
        acc[0][j] += a0 * bb[j];
        acc[1][j] += a1 * bb[j];
      }
    }
    __syncthreads();
  }
#pragma unroll
  for (int rr = 0; rr < 2; ++rr) {
    float4 o0 = {acc[rr][0], acc[rr][1], acc[rr][2], acc[rr][3]};
    float4 o1 = {acc[rr][4], acc[rr][5], acc[rr][6], acc[rr][7]};
    *(float4*)&C[(r0 + ty * 2 + rr) * 128 + tx * 8] = o0;
    *(float4*)&C[(r0 + ty * 2 + rr) * 128 + tx * 8 + 4] = o1;
  }
}

// ---------------- GCN aggregation ----------------
__global__ void k_gcn_init(const float* __restrict__ h, const float* __restrict__ dis,
                           float* acc) {
  int v = blockIdx.x * 256 + threadIdx.x;
  int i = v >> 7;
  float d = dis[i];
  acc[v] = d * d * h[v];
}

__global__ void k_gcn_scatter(const int* __restrict__ ei, const float* __restrict__ ew,
                              const float* __restrict__ dis, const float* __restrict__ h,
                              float* acc) {
  int t = threadIdx.x;
  int e = blockIdx.x * 2 + (t >> 7);
  int c = t & 127;
  int s = ei[e], d2 = ei[E_ + e];
  float nm = dis[s] * ew[e] * dis[d2];
  atomicAdd(&acc[d2 * 128 + c], nm * h[s * 128 + c]);
}

__global__ void k_gcn_fin(const float* __restrict__ acc, const float* __restrict__ bg,
                          float* n_out, float* sn) {
  __shared__ float part[4];
  int t = threadIdx.x;
  int i = blockIdx.x * 2 + (t >> 7);
  int c = t & 127;
  float v = tanhf(acc[i * 128 + c] + bg[c]);
  n_out[i * 128 + c] = v;
  float vv = v * v;
#pragma unroll
  for (int off = 32; off; off >>= 1) vv += __shfl_down(vv, off, 64);
  if ((t & 63) == 0) part[t >> 6] = vv;
  __syncthreads();
  if ((t & 127) == 0) sn[i] = part[t >> 6] + part[(t >> 6) + 1];
}

// ---------------- bf16 hi/lo split + MFMA fragment packing ----------------
__device__ __forceinline__ unsigned short f2bf_rne(float x) {
  unsigned u = __builtin_bit_cast(unsigned, x);
  unsigned r = ((u >> 16) & 1u) + 0x7fffu;
  return (unsigned short)((u + r) >> 16);
}
__device__ __forceinline__ float bf2f(unsigned short b) {
  unsigned u = ((unsigned)b) << 16;
  return __builtin_bit_cast(float, u);
}

// src: [N][128] fp32 -> fragHi/fragLo: [N/32 tiles][8 ks][64 lanes][8 bf16]
__global__ void k_fragprep(const float* __restrict__ src, bshort8* __restrict__ hiA,
                           bshort8* __restrict__ loA) {
  int t = blockIdx.x * 256 + threadIdx.x;  // N*16 threads
  int j = t >> 4, slot = t & 15;
  const float* p = src + j * 128 + slot * 8;
  float4 f0 = *(const float4*)p;
  float4 f1 = *(const float4*)(p + 4);
  float f[8] = {f0.x, f0.y, f0.z, f0.w, f1.x, f1.y, f1.z, f1.w};
  bshort8 h, l;
#pragma unroll
  for (int i = 0; i < 8; ++i) {
    unsigned short hb = f2bf_rne(f[i]);
    float lf = f[i] - bf2f(hb);
    h[i] = (short)hb;
    l[i] = (short)f2bf_rne(lf);
  }
  int ks = slot >> 1, half = slot & 1;
  int dst = ((j >> 5) * 8 + ks) * 64 + half * 32 + (j & 31);
  hiA[dst] = h;
  loA[dst] = l;
}

// ---------------- packed-key helpers ----------------
__device__ __forceinline__ unsigned long long packkey(float d, int j) {
  unsigned m = __builtin_bit_cast(unsigned, d);
  m = (m & 0x80000000u) ? ~m : (m | 0x80000000u);  // order-preserving fp32->u32
  return (((unsigned long long)m) << 32) | (unsigned)j;
}

// branchless sorted shift-insert into ascending tk[16]; call only when x < tk[15]
__device__ __forceinline__ void ins16(unsigned long long* tk, unsigned long long x) {
  bool c[16];
#pragma unroll
  for (int s = 0; s < 16; ++s) c[s] = x < tk[s];
#pragma unroll
  for (int s = 15; s >= 1; --s) tk[s] = c[s - 1] ? tk[s - 1] : (c[s] ? x : tk[s]);
  tk[0] = c[0] ? x : tk[0];
}

// ---------------- MFMA kNN: Gram tiles + in-register sorted top-16 ----------------
// A operand = j rows (M), B operand = 32 queries (N). C: col=lane&31=query.
__global__ __launch_bounds__(256, 3) void k_knn(const bshort8* __restrict__ fragHi,
                                                const bshort8* __restrict__ fragLo,
                                                const float* __restrict__ sn,
                                                unsigned long long* __restrict__ candP) {
  __shared__ float snS[SLABJ];                 // 4 KB
  __shared__ unsigned long long mbuf[16 * 133];  // 17 KB
  int t = threadIdx.x;
  int qtile = blockIdx.x, slab = blockIdx.y;
  int wave = t >> 6, lane = t & 63;
  int q = lane & 31, half = lane >> 5;

#pragma unroll
  for (int p = 0; p < 4; ++p) snS[t + 256 * p] = sn[slab * SLABJ + t + 256 * p];

  bshort8 bHi[8], bLo[8];
#pragma unroll
  for (int ks = 0; ks < 8; ++ks) {
    int o = (qtile * 8 + ks) * 64 + lane;
    bHi[ks] = fragHi[o];
    bLo[ks] = fragLo[o];
  }
  __syncthreads();

  unsigned long long tk[16];
#pragma unroll
  for (int s = 0; s < 16; ++s) tk[s] = ~0ULL;

  for (int ti = 0; ti < 8; ++ti) {
    int jt = slab * 32 + wave * 8 + ti;  // global 32-row tile index
    f32x16 acc;
#pragma unroll
    for (int r = 0; r < 16; ++r) acc[r] = 0.f;
#pragma unroll
    for (int ks = 0; ks < 8; ++ks) {
      int o = (jt * 8 + ks) * 64 + lane;
      bshort8 aHi = fragHi[o];
      bshort8 aLo = fragLo[o];
      acc = __builtin_amdgcn_mfma_f32_32x32x16_bf16(aLo, bHi[ks], acc, 0, 0, 0);
      acc = __builtin_amdgcn_mfma_f32_32x32x16_bf16(aHi, bLo[ks], acc, 0, 0, 0);
      acc = __builtin_amdgcn_mfma_f32_32x32x16_bf16(aHi, bHi[ks], acc, 0, 0, 0);
    }
    int jbase = (wave * 8 + ti) * 32;  // slab-local
#pragma unroll
    for (int rp = 0; rp < 8; ++rp) {
      int r0 = rp * 2;
      int row0 = (r0 & 3) + 8 * (r0 >> 2) + 4 * half;  // row1 = row0+1
      float d0 = snS[jbase + row0] - 2.0f * acc[r0];
      float d1 = snS[jbase + row0 + 1] - 2.0f * acc[r0 + 1];
      unsigned long long k0 = packkey(d0, slab * SLABJ + jbase + row0);
      unsigned long long k1 = packkey(d1, slab * SLABJ + jbase + row0 + 1);
      unsigned long long km = k0 < k1 ? k0 : k1;
      if (km < tk[15]) {
        if (k0 < tk[15]) ins16(tk, k0);
        if (k1 < tk[15]) ins16(tk, k1);
      }
    }
  }

  // two-pass 8-way sorted merge (16 queries per pass) -> candP[slab*16+s][query]
  int g = wave * 2 + half;  // 0..7
#pragma unroll
  for (int p = 0; p < 2; ++p) {
    __syncthreads();
    if ((q >> 4) == p) {
#pragma unroll
      for (int s = 0; s < 16; ++s) mbuf[(q & 15) * 133 + g * 16 + s] = tk[s];
    }
    __syncthreads();
    if (t < 16) {
      int qq = qtile * 32 + p * 16 + t;
      int base = t * 133;
      int h0 = 0, h1 = 0, h2 = 0, h3 = 0, h4 = 0, h5 = 0, h6 = 0, h7 = 0;
      for (int step = 0; step < 16; ++step) {
        unsigned long long best = mbuf[base + h0];
        int bg = 0;
        unsigned long long b;
        b = mbuf[base + 16 + h1];  if (b < best) { best = b; bg = 1; }
        b = mbuf[base + 32 + h2];  if (b < best) { best = b; bg = 2; }
        b = mbuf[base + 48 + h3];  if (b < best) { best = b; bg = 3; }
        b = mbuf[base + 64 + h4];  if (b < best) { best = b; bg = 4; }
        b = mbuf[base + 80 + h5];  if (b < best) { best = b; bg = 5; }
        b = mbuf[base + 96 + h6];  if (b < best) { best = b; bg = 6; }
        b = mbuf[base + 112 + h7]; if (b < best) { best = b; bg = 7; }
        candP[(slab * 16 + step) * N_ + qq] = best;
        h0 += (bg == 0); h1 += (bg == 1); h2 += (bg == 2); h3 += (bg == 3);
        h4 += (bg == 4); h5 += (bg == 5); h6 += (bg == 6); h7 += (bg == 7);
      }
    }
  }
}

// merge 8 slabs x 16 sorted candidates -> final 16 indices
__global__ void k_knnmerge(const unsigned long long* __restrict__ candP,
                           int* __restrict__ idxo) {
  int qg = blockIdx.x * 256 + threadIdx.x;
  int h0 = 0, h1 = 0, h2 = 0, h3 = 0, h4 = 0, h5 = 0, h6 = 0, h7 = 0;
  for (int step = 0; step < 16; ++step) {
    unsigned long long best = candP[(0 * 16 + h0) * N_ + qg];
    int bg = 0;
    unsigned long long b;
    b = candP[(1 * 16 + h1) * N_ + qg]; if (b < best) { best = b; bg = 1; }
    b = candP[(2 * 16 + h2) * N_ + qg]; if (b < best) { best = b; bg = 2; }
    b = candP[(3 * 16 + h3) * N_ + qg]; if (b < best) { best = b; bg = 3; }
    b = candP[(4 * 16 + h4) * N_ + qg]; if (b < best) { best = b; bg = 4; }
    b = candP[(5 * 16 + h5) * N_ + qg]; if (b < best) { best = b; bg = 5; }
    b = candP[(6 * 16 + h6) * N_ + qg]; if (b < best) { best = b; bg = 6; }
    b = candP[(7 * 16 + h7) * N_ + qg]; if (b < best) { best = b; bg = 7; }
    idxo[qg * 16 + step] = (int)(unsigned)(best & 0xffffffffULL);
    h0 += (bg == 0); h1 += (bg == 1); h2 += (bg == 2); h3 += (bg == 3);
    h4 += (bg == 4); h5 += (bg == 5); h6 += (bg == 6); h7 += (bg == 7);
  }
}

// ---------------- fused EdgeConv MLP (h1 gather -> G2 -> G3 -> max) ----------------
__global__ __launch_bounds__(256) void k_mlp(const float* __restrict__ ab,
                                             const int* __restrict__ idx,
                                             const float* __restrict__ w2,
                                             const float* __restrict__ b1g,
                                             const float* __restrict__ b2g,
                                             const float* __restrict__ w3,
                                             const float* __restrict__ b3g,
                                             float* __restrict__ eout) {
  __shared__ float A1c[32 * 68];
  __shared__ float wc[32 * 128];
  __shared__ float H2t[128 * 68];
  int t = threadIdx.x;
  int n0 = blockIdx.x * 4;
  int ty = t >> 4, tx = t & 15;

  float acc2[4][8];
#pragma unroll
  for (int i = 0; i < 4; ++i)
#pragma unroll
    for (int j = 0; j < 8; ++j) acc2[i][j] = 0.f;

  for (int kc = 0; kc < 2; ++kc) {
#pragma unroll
    for (int p = 0; p < 8; ++p) {
      int v = t + 256 * p;
      int r = v >> 5, k = v & 31;
      int node = n0 + (r >> 4);
      int jn = idx[node * 16 + (r & 15)];
      int kk = kc * 32 + k;
      float val = ab[node * 128 + kk] + ab[jn * 128 + 64 + kk] + b1g[kk];
      A1c[k * 68 + r] = fmaxf(val, 0.f);
    }
#pragma unroll
    for (int p = 0; p < 16; ++p) {
      int v = t + 256 * p;
      int k = v >> 7, c = v & 127;
      wc[k * 128 + c] = w2[(kc * 32 + k) * 128 + c];
    }
    __syncthreads();
    for (int k = 0; k < 32; ++k) {
      float4 a = *(const float4*)&A1c[k * 68 + ty * 4];
      float4 b0 = *(const float4*)&wc[k * 128 + tx * 8];
      float4 b1 = *(const float4*)&wc[k * 128 + tx * 8 + 4];
      float aa[4] = {a.x, a.y, a.z, a.w};
      float bb[8] = {b0.x, b0.y, b0.z, b0.w, b1.x, b1.y, b1.z, b1.w};
#pragma unroll
      for (int ri = 0; ri < 4; ++ri)
#pragma unroll
        for (int cii = 0; cii < 8; ++cii) acc2[ri][cii] += aa[ri] * bb[cii];
    }
    __syncthreads();
  }

#pragma unroll
  for (int cii = 0; cii < 8; ++cii) {
    float bb = b2g[tx * 8 + cii];
#pragma unroll
    for (int ri = 0; ri < 4; ++ri)
      H2t[(tx * 8 + cii) * 68 + ty * 4 + ri] = fmaxf(acc2[ri][cii] + bb, 0.f);
  }
  __syncthreads();

  float acc3[4][8];
#pragma unroll
  for (int i = 0; i < 4; ++i)
#pragma unroll
    for (int j = 0; j < 8; ++j) acc3[i][j] = 0.f;

  for (int kt = 0; kt < 4; ++kt) {
#pragma unroll
    for (int p = 0; p < 16; ++p) {
      int v = t + 256 * p;
      int k = v >> 7, c = v & 127;
      wc[k * 128 + c] = w3[(kt * 32 + k) * 128 + c];
    }
    __syncthreads();
    for (int k = 0; k < 32; ++k) {
      float4 a = *(const float4*)&H2t[(kt * 32 + k) * 68 + ty * 4];
      float4 b0 = *(const float4*)&wc[k * 128 + tx * 8];
      float4 b1 = *(const float4*)&wc[k * 128 + tx * 8 + 4];
      float aa[4] = {a.x, a.y, a.z, a.w};
      float bb[8] = {b0.x, b0.y, b0.z, b0.w, b1.x, b1.y, b1.z, b1.w};
#pragma unroll
      for (int ri = 0; ri < 4; ++ri)
#pragma unroll
        for (int cii = 0; cii < 8; ++cii) acc3[ri][cii] += aa[ri] * bb[cii];
    }
    __syncthreads();
  }

  float* red = A1c;
#pragma unroll
  for (int cii = 0; cii < 8; ++cii) {
    float m = fmaxf(fmaxf(acc3[0][cii], acc3[1][cii]), fmaxf(acc3[2][cii], acc3[3][cii]));
    red[ty * 128 + tx * 8 + cii] = m;
  }
  __syncthreads();
#pragma unroll
  for (int p = 0; p < 2; ++p) {
    int v = t * 2 + p;
    int g = v >> 7, c = v & 127;
    float m = fmaxf(fmaxf(red[(g * 4 + 0) * 128 + c], red[(g * 4 + 1) * 128 + c]),
                    fmaxf(red[(g * 4 + 2) * 128 + c], red[(g * 4 + 3) * 128 + c]));
    eout[(n0 + g) * 128 + c] = m + b3g[c];
  }
}

// ---------------- small epilogues ----------------
__global__ void k_e1n1(const float* __restrict__ e1, const float* __restrict__ n1,
                       float* s1) {
  int t = threadIdx.x;
  int node = blockIdx.x * 4 + (t >> 6);
  int lane = t & 63;
  float v0 = e1[node * 128 + lane] + n1[node * 128 + lane];
  float v1 = e1[node * 128 + 64 + lane] + n1[node * 128 + 64 + lane];
  float ss = v0 * v0 + v1 * v1;
#pragma unroll
  for (int off = 32; off; off >>= 1) ss += __shfl_down(ss, off, 64);
  if (lane == 0) s1[node] = sqrtf(ss);
}

__global__ void k_addinto(float* __restrict__ e, const float* __restrict__ n) {
  int v = blockIdx.x * 256 + threadIdx.x;
  e[v] += n[v];
}

__global__ void k_final(const float* __restrict__ s1, const float* __restrict__ e2n2,
                        const float* __restrict__ e3n3, float* __restrict__ out) {
  int t = threadIdx.x;
  int node = blockIdx.x * 4 + (t >> 6);
  int lane = t & 63;
  float s = s1[node];
  float z0 = s * e2n2[node * 128 + lane] * e3n3[node * 128 + lane];
  float z1 = s * e2n2[node * 128 + 64 + lane] * e3n3[node * 128 + 64 + lane];
  float m = fmaxf(z0, z1);
#pragma unroll
  for (int off = 32; off; off >>= 1) m = fmaxf(m, __shfl_xor(m, off, 64));
  float ex = expf(z0 - m) + expf(z1 - m);
#pragma unroll
  for (int off = 32; off; off >>= 1) ex += __shfl_xor(ex, off, 64);
  float lse = m + logf(ex);
  out[node * 128 + lane] = z0 - lse;
  out[node * 128 + 64 + lane] = z1 - lse;
}

// ---------------- host ----------------
extern "C" void kernel_launch(void* const* d_in, const int* in_sizes, int n_in,
                              void* d_out, int out_size, void* d_ws, size_t ws_size,
                              hipStream_t stream) {
  (void)in_sizes; (void)n_in; (void)out_size;
  const float* x  = (const float*)d_in[0];
  const int* ei   = (const int*)d_in[1];
  const float* ew = (const float*)d_in[2];
  const float* wg[3] = {(const float*)d_in[3], (const float*)d_in[5], (const float*)d_in[7]};
  const float* bg[3] = {(const float*)d_in[4], (const float*)d_in[6], (const float*)d_in[8]};
  const float* ew1[3] = {(const float*)d_in[9],  (const float*)d_in[15], (const float*)d_in[21]};
  const float* eb1[3] = {(const float*)d_in[10], (const float*)d_in[16], (const float*)d_in[22]};
  const float* ew2[3] = {(const float*)d_in[11], (const float*)d_in[17], (const float*)d_in[23]};
  const float* eb2[3] = {(const float*)d_in[12], (const float*)d_in[18], (const float*)d_in[24]};
  const float* ew3[3] = {(const float*)d_in[13], (const float*)d_in[19], (const float*)d_in[25]};
  const float* eb3[3] = {(const float*)d_in[14], (const float*)d_in[20], (const float*)d_in[26]};

  size_t need = (size_t)(19 * N_ + 7 * N_ * H_) * sizeof(float);
  if (ws_size < need) return;

  float* ws  = (float*)d_ws;
  float* dis = ws;                    // N
  float* sn  = ws + N_;               // N
  float* S1  = ws + 2 * N_;           // N
  int* idx   = (int*)(ws + 3 * N_);   // N*16 ints
  float* h   = ws + 19 * N_;          // N*H (doubles as frag arrays)
  float* n1  = h + N_ * H_;
  float* n2  = n1 + N_ * H_;
  float* n3  = n2 + N_ * H_;
  float* E2  = n3 + N_ * H_;          // e2 / e2+n2 (live l=1..final)
  float* E1  = E2 + N_ * H_;          // e1 (l=0), e3+n3 (l=2); free during knn
  float* ab  = E1 + N_ * H_;          // scratch; adjacent to E1

  // frag arrays alias h (free between gcn_fin and next layer's gemm)
  bshort8* fragHi = (bshort8*)h;                      // 2 MB
  bshort8* fragLo = (bshort8*)(h + N_ * H_ / 2);      // 2 MB
  // packed candidates alias E1+ab (8 MB contiguous, free during knn/knnmerge)
  unsigned long long* candP = (unsigned long long*)E1;  // 128 x N u64

  float* nl[3] = {n1, n2, n3};

  k_deg_init<<<N_ / 256, 256, 0, stream>>>(dis);
  k_deg_scatter<<<E_ / 256, 256, 0, stream>>>(ei, ew, dis);
  k_dis<<<N_ / 256, 256, 0, stream>>>(dis);

  for (int l = 0; l < 3; ++l) {
    const float* inp = (l == 0) ? x : nl[l - 1];
    k_gemm128<<<256, 256, 0, stream>>>(inp, wg[l], h, 0);
    k_gcn_init<<<N_ * H_ / 256, 256, 0, stream>>>(h, dis, nl[l]);
    k_gcn_scatter<<<E_ / 2, 256, 0, stream>>>(ei, ew, dis, h, nl[l]);
    k_gcn_fin<<<N_ / 2, 256, 0, stream>>>(nl[l], bg[l], nl[l], sn);
    k_fragprep<<<N_ * 16 / 256, 256, 0, stream>>>(nl[l], fragHi, fragLo);
    k_knn<<<dim3(N_ / 32, 8), 256, 0, stream>>>(fragHi, fragLo, sn, candP);
    k_knnmerge<<<N_ / 256, 256, 0, stream>>>(candP, idx);
    k_gemm128<<<256, 256, 0, stream>>>(nl[l], ew1[l], ab, 1);
    float* etgt = (l == 1) ? E2 : E1;
    k_mlp<<<N_ / 4, 256, 0, stream>>>(ab, idx, ew2[l], eb1[l], eb2[l], ew3[l], eb3[l], etgt);
    if (l == 0) k_e1n1<<<N_ / 4, 256, 0, stream>>>(E1, n1, S1);
    if (l == 1) k_addinto<<<N_ * H_ / 256, 256, 0, stream>>>(E2, n2);
    if (l == 2) k_addinto<<<N_ * H_ / 256, 256, 0, stream>>>(E1, n3);
  }
  k_final<<<N_ / 4, 256, 0, stream>>>(S1, E2, E1, (float*)d_out);
}

// Round 4
// 2040.738 us; speedup vs baseline: 2.7047x; 1.1354x over previous
//
#include <hip/hip_runtime.h>
#include <math.h>

#define N_ 8192
#define H_ 128
#define E_ 262144
#define K_ 16
#define SLABJ 1024

typedef __attribute__((ext_vector_type(8))) short bshort8;
typedef __attribute__((ext_vector_type(16))) float f32x16;

// ---------------- degree / normalization ----------------
__global__ void k_deg_init(float* deg) {
  int i = blockIdx.x * 256 + threadIdx.x;
  deg[i] = 1.0f;  // self-loop weight
}

__global__ void k_deg_scatter(const int* __restrict__ ei, const float* __restrict__ ew,
                              float* deg) {
  int e = blockIdx.x * 256 + threadIdx.x;
  atomicAdd(&deg[ei[E_ + e]], ew[e]);
}

__global__ void k_dis(float* deg) {
  int i = blockIdx.x * 256 + threadIdx.x;
  deg[i] = rsqrtf(deg[i]);  // deg >= 1 always
}

// ---------------- one-time CSR build (edge list is static) ----------------
__global__ void k_hist(const int* __restrict__ ei, int* hist) {
  int e = blockIdx.x * 256 + threadIdx.x;
  atomicAdd(&hist[ei[E_ + e]], 1);
}

__global__ void k_scan(int* hist, int* rowptr) {  // 1 block, 256 threads
  __shared__ int part[256];
  __shared__ int partx[257];
  int t = threadIdx.x;
  int base = t * 32;
  int loc[32];
  int s = 0;
#pragma unroll
  for (int i = 0; i < 32; ++i) { loc[i] = s; s += hist[base + i]; }
  part[t] = s;
  __syncthreads();
  if (t == 0) {
    int r = 0;
    for (int i = 0; i < 256; ++i) { partx[i] = r; r += part[i]; }
    partx[256] = r;
  }
  __syncthreads();
  int b = partx[t];
#pragma unroll
  for (int i = 0; i < 32; ++i) {
    rowptr[base + i] = b + loc[i];
    hist[base + i] = b + loc[i];  // hist becomes the scatter cursor
  }
  if (t == 0) rowptr[N_] = partx[256];
}

__global__ void k_edgebuild(const int* __restrict__ ei, const float* __restrict__ ew,
                            const float* __restrict__ dis, int* cursor,
                            int* __restrict__ srcS, float* __restrict__ normS) {
  int e = blockIdx.x * 256 + threadIdx.x;
  int s = ei[e], d = ei[E_ + e];
  int pos = atomicAdd(&cursor[d], 1);
  srcS[pos] = s;
  normS[pos] = dis[s] * ew[e] * dis[d];
}

// ---------------- generic [M x 128] @ [128 x 128] GEMM ----------------
__global__ __launch_bounds__(256) void k_gemm128(const float* __restrict__ A,
                                                 const float* __restrict__ W,
                                                 float* __restrict__ C, int mode) {
  __shared__ float Bs[32 * 132];
  __shared__ float Ast[32 * 33];
  int t = threadIdx.x;
  int r0 = blockIdx.x * 32;
  int ty = t >> 4, tx = t & 15;
  float acc[2][8];
#pragma unroll
  for (int i = 0; i < 2; ++i)
#pragma unroll
    for (int j = 0; j < 8; ++j) acc[i][j] = 0.f;

  for (int kt = 0; kt < 4; ++kt) {
#pragma unroll
    for (int p = 0; p < 16; ++p) {
      int v = t + 256 * p;  // 4096
      int k = v >> 7, c = v & 127;
      int kg = kt * 32 + k;
      float val;
      if (mode == 0) val = W[kg * 128 + c];
      else val = (c < 64) ? (W[kg * 64 + c] - W[(128 + kg) * 64 + c])
                          : W[(128 + kg) * 64 + (c - 64)];
      Bs[k * 132 + c] = val;
    }
#pragma unroll
    for (int p = 0; p < 4; ++p) {
      int v = t + 256 * p;  // 1024
      int r = v >> 5, k = v & 31;
      Ast[k * 33 + r] = A[(r0 + r) * 128 + kt * 32 + k];
    }
    __syncthreads();
    for (int k = 0; k < 32; ++k) {
      float a0 = Ast[k * 33 + ty * 2];
      float a1 = Ast[k * 33 + ty * 2 + 1];
      float4 b0 = *(const float4*)&Bs[k * 132 + tx * 8];
      float4 b1 = *(const float4*)&Bs[k * 132 + tx * 8 + 4];
      float bb[8] = {b0.x, b0.y, b0.z, b0.w, b1.x, b1.y, b1.z, b1.w};
#pragma unroll
      for (int j = 0; j < 8; ++j) {
        acc[0][j] += a0 * bb[j];
        acc[1][j] += a1 * bb[j];
      }
    }
    __syncthreads();
  }
#pragma unroll
  for (int rr = 0; rr < 2; ++rr) {
    float4 o0 = {acc[rr][0], acc[rr][1], acc[rr][2], acc[rr][3]};
    float4 o1 = {acc[rr][4], acc[rr][5], acc[rr][6], acc[rr][7]};
    *(float4*)&C[(r0 + ty * 2 + rr) * 128 + tx * 8] = o0;
    *(float4*)&C[(r0 + ty * 2 + rr) * 128 + tx * 8 + 4] = o1;
  }
}

// ---------------- fused GCN aggregation (CSR gather, no atomics) ----------------
__global__ __launch_bounds__(256) void k_gcn_agg(const float* __restrict__ h,
                                                 const float* __restrict__ dis,
                                                 const int* __restrict__ rowptr,
                                                 const int* __restrict__ srcS,
                                                 const float* __restrict__ normS,
                                                 const float* __restrict__ bg,
                                                 float* __restrict__ n_out,
                                                 float* __restrict__ sn) {
  __shared__ float part[4];
  int t = threadIdx.x;
  int i = blockIdx.x * 2 + (t >> 7);
  int c = t & 127;
  float di = dis[i];
  float a0 = di * di * h[i * 128 + c], a1 = 0.f, a2 = 0.f, a3 = 0.f;
  int e0 = rowptr[i], e1 = rowptr[i + 1];
  int e = e0;
  for (; e + 4 <= e1; e += 4) {
    int s0 = srcS[e], s1 = srcS[e + 1], s2 = srcS[e + 2], s3 = srcS[e + 3];
    float w0 = normS[e], w1 = normS[e + 1], w2 = normS[e + 2], w3 = normS[e + 3];
    a0 += w0 * h[s0 * 128 + c];
    a1 += w1 * h[s1 * 128 + c];
    a2 += w2 * h[s2 * 128 + c];
    a3 += w3 * h[s3 * 128 + c];
  }
  for (; e < e1; ++e) a0 += normS[e] * h[srcS[e] * 128 + c];
  float v = tanhf(a0 + a1 + a2 + a3 + bg[c]);
  n_out[i * 128 + c] = v;
  float vv = v * v;
#pragma unroll
  for (int off = 32; off; off >>= 1) vv += __shfl_down(vv, off, 64);
  if ((t & 63) == 0) part[t >> 6] = vv;
  __syncthreads();
  if ((t & 127) == 0) sn[i] = part[t >> 6] + part[(t >> 6) + 1];
}

// ---------------- bf16 hi/lo split + MFMA fragment packing ----------------
__device__ __forceinline__ unsigned short f2bf_rne(float x) {
  unsigned u = __builtin_bit_cast(unsigned, x);
  unsigned r = ((u >> 16) & 1u) + 0x7fffu;
  return (unsigned short)((u + r) >> 16);
}
__device__ __forceinline__ float bf2f(unsigned short b) {
  unsigned u = ((unsigned)b) << 16;
  return __builtin_bit_cast(float, u);
}

// src: [N][128] fp32 -> fragHi/fragLo: [N/32 tiles][8 ks][64 lanes][8 bf16]
__global__ void k_fragprep(const float* __restrict__ src, bshort8* __restrict__ hiA,
                           bshort8* __restrict__ loA) {
  int t = blockIdx.x * 256 + threadIdx.x;  // N*16 threads
  int j = t >> 4, slot = t & 15;
  const float* p = src + j * 128 + slot * 8;
  float4 f0 = *(const float4*)p;
  float4 f1 = *(const float4*)(p + 4);
  float f[8] = {f0.x, f0.y, f0.z, f0.w, f1.x, f1.y, f1.z, f1.w};
  bshort8 h, l;
#pragma unroll
  for (int i = 0; i < 8; ++i) {
    unsigned short hb = f2bf_rne(f[i]);
    float lf = f[i] - bf2f(hb);
    h[i] = (short)hb;
    l[i] = (short)f2bf_rne(lf);
  }
  int ks = slot >> 1, half = slot & 1;
  int dst = ((j >> 5) * 8 + ks) * 64 + half * 32 + (j & 31);
  hiA[dst] = h;
  loA[dst] = l;
}

// ---------------- packed-key helpers ----------------
__device__ __forceinline__ unsigned long long packkey(float d, int j) {
  unsigned m = __builtin_bit_cast(unsigned, d);
  m = (m & 0x80000000u) ? ~m : (m | 0x80000000u);  // order-preserving fp32->u32
  return (((unsigned long long)m) << 32) | (unsigned)j;
}

// branchless sorted shift-insert into ascending tk[16]; call only when x < tk[15]
__device__ __forceinline__ void ins16(unsigned long long* tk, unsigned long long x) {
  bool c[16];
#pragma unroll
  for (int s = 0; s < 16; ++s) c[s] = x < tk[s];
#pragma unroll
  for (int s = 15; s >= 1; --s) tk[s] = c[s - 1] ? tk[s - 1] : (c[s] ? x : tk[s]);
  tk[0] = c[0] ? x : tk[0];
}

// ---------------- MFMA kNN: Gram tiles + in-register sorted top-16 ----------------
// A operand = j rows (M), B operand = 32 queries (N). C: col=lane&31=query.
__global__ __launch_bounds__(256, 3) void k_knn(const bshort8* __restrict__ fragHi,
                                                const bshort8* __restrict__ fragLo,
                                                const float* __restrict__ sn,
                                                unsigned long long* __restrict__ candP) {
  __shared__ float snS[SLABJ];                    // 4 KB
  __shared__ unsigned long long mbuf[32 * 129];   // 33 KB
  int t = threadIdx.x;
  int qtile = blockIdx.x, slab = blockIdx.y;
  int wave = t >> 6, lane = t & 63;
  int q = lane & 31, half = lane >> 5;

#pragma unroll
  for (int p = 0; p < 4; ++p) snS[t + 256 * p] = sn[slab * SLABJ + t + 256 * p];

  bshort8 bHi[8], bLo[8];
#pragma unroll
  for (int ks = 0; ks < 8; ++ks) {
    int o = (qtile * 8 + ks) * 64 + lane;
    bHi[ks] = fragHi[o];
    bLo[ks] = fragLo[o];
  }
  __syncthreads();

  unsigned long long tk[16];
#pragma unroll
  for (int s = 0; s < 16; ++s) tk[s] = ~0ULL;

  for (int ti = 0; ti < 8; ++ti) {
    int jt = slab * 32 + wave * 8 + ti;  // global 32-row tile index
    f32x16 acc;
#pragma unroll
    for (int r = 0; r < 16; ++r) acc[r] = 0.f;

    // half-tile 0: hoist 8 loads (one progressive wait), then 12 MFMAs
    {
      bshort8 aH[4], aL[4];
#pragma unroll
      for (int k4 = 0; k4 < 4; ++k4) {
        int o = (jt * 8 + k4) * 64 + lane;
        aH[k4] = fragHi[o];
        aL[k4] = fragLo[o];
      }
#pragma unroll
      for (int k4 = 0; k4 < 4; ++k4) {
        acc = __builtin_amdgcn_mfma_f32_32x32x16_bf16(aL[k4], bHi[k4], acc, 0, 0, 0);
        acc = __builtin_amdgcn_mfma_f32_32x32x16_bf16(aH[k4], bLo[k4], acc, 0, 0, 0);
        acc = __builtin_amdgcn_mfma_f32_32x32x16_bf16(aH[k4], bHi[k4], acc, 0, 0, 0);
      }
    }
    // half-tile 1
    {
      bshort8 aH[4], aL[4];
#pragma unroll
      for (int k4 = 0; k4 < 4; ++k4) {
        int o = (jt * 8 + 4 + k4) * 64 + lane;
        aH[k4] = fragHi[o];
        aL[k4] = fragLo[o];
      }
#pragma unroll
      for (int k4 = 0; k4 < 4; ++k4) {
        acc = __builtin_amdgcn_mfma_f32_32x32x16_bf16(aL[k4], bHi[4 + k4], acc, 0, 0, 0);
        acc = __builtin_amdgcn_mfma_f32_32x32x16_bf16(aH[k4], bLo[4 + k4], acc, 0, 0, 0);
        acc = __builtin_amdgcn_mfma_f32_32x32x16_bf16(aH[k4], bHi[4 + k4], acc, 0, 0, 0);
      }
    }

    int jbase = (wave * 8 + ti) * 32;  // slab-local
#pragma unroll
    for (int rp = 0; rp < 8; ++rp) {
      int r0 = rp * 2;
      int row0 = (r0 & 3) + 8 * (r0 >> 2) + 4 * half;  // row1 = row0+1
      float d0 = snS[jbase + row0] - 2.0f * acc[r0];
      float d1 = snS[jbase + row0 + 1] - 2.0f * acc[r0 + 1];
      unsigned long long k0 = packkey(d0, slab * SLABJ + jbase + row0);
      unsigned long long k1 = packkey(d1, slab * SLABJ + jbase + row0 + 1);
      unsigned long long km = k0 < k1 ? k0 : k1;
      if (km < tk[15]) {
        if (k0 < tk[15]) ins16(tk, k0);
        if (k1 < tk[15]) ins16(tk, k1);
      }
    }
  }

  // single-pass 8-way sorted merge: all 32 queries at once
  int g = wave * 2 + half;  // partial-list id 0..7
  __syncthreads();
#pragma unroll
  for (int s = 0; s < 16; ++s) mbuf[q * 129 + g * 16 + s] = tk[s];
  __syncthreads();
  if (t < 32) {
    int qq = qtile * 32 + t;
    int base = t * 129;
    int h0 = 0, h1 = 0, h2 = 0, h3 = 0, h4 = 0, h5 = 0, h6 = 0, h7 = 0;
    for (int step = 0; step < 16; ++step) {
      unsigned long long best = mbuf[base + h0];
      int bg = 0;
      unsigned long long b;
      b = mbuf[base + 16 + h1];  if (b < best) { best = b; bg = 1; }
      b = mbuf[base + 32 + h2];  if (b < best) { best = b; bg = 2; }
      b = mbuf[base + 48 + h3];  if (b < best) { best = b; bg = 3; }
      b = mbuf[base + 64 + h4];  if (b < best) { best = b; bg = 4; }
      b = mbuf[base + 80 + h5];  if (b < best) { best = b; bg = 5; }
      b = mbuf[base + 96 + h6];  if (b < best) { best = b; bg = 6; }
      b = mbuf[base + 112 + h7]; if (b < best) { best = b; bg = 7; }
      candP[(slab * 16 + step) * N_ + qq] = best;
      h0 += (bg == 0); h1 += (bg == 1); h2 += (bg == 2); h3 += (bg == 3);
      h4 += (bg == 4); h5 += (bg == 5); h6 += (bg == 6); h7 += (bg == 7);
    }
  }
}

// merge 8 slabs x 16 sorted candidates -> final 16 indices
__global__ void k_knnmerge(const unsigned long long* __restrict__ candP,
                           int* __restrict__ idxo) {
  int qg = blockIdx.x * 256 + threadIdx.x;
  int h0 = 0, h1 = 0, h2 = 0, h3 = 0, h4 = 0, h5 = 0, h6 = 0, h7 = 0;
  for (int step = 0; step < 16; ++step) {
    unsigned long long best = candP[(0 * 16 + h0) * N_ + qg];
    int bg = 0;
    unsigned long long b;
    b = candP[(1 * 16 + h1) * N_ + qg]; if (b < best) { best = b; bg = 1; }
    b = candP[(2 * 16 + h2) * N_ + qg]; if (b < best) { best = b; bg = 2; }
    b = candP[(3 * 16 + h3) * N_ + qg]; if (b < best) { best = b; bg = 3; }
    b = candP[(4 * 16 + h4) * N_ + qg]; if (b < best) { best = b; bg = 4; }
    b = candP[(5 * 16 + h5) * N_ + qg]; if (b < best) { best = b; bg = 5; }
    b = candP[(6 * 16 + h6) * N_ + qg]; if (b < best) { best = b; bg = 6; }
    b = candP[(7 * 16 + h7) * N_ + qg]; if (b < best) { best = b; bg = 7; }
    idxo[qg * 16 + step] = (int)(unsigned)(best & 0xffffffffULL);
    h0 += (bg == 0); h1 += (bg == 1); h2 += (bg == 2); h3 += (bg == 3);
    h4 += (bg == 4); h5 += (bg == 5); h6 += (bg == 6); h7 += (bg == 7);
  }
}

// ---------------- fused EdgeConv MLP (h1 gather -> G2 -> G3 -> max) ----------------
__global__ __launch_bounds__(256) void k_mlp(const float* __restrict__ ab,
                                             const int* __restrict__ idx,
                                             const float* __restrict__ w2,
                                             const float* __restrict__ b1g,
                                             const float* __restrict__ b2g,
                                             const float* __restrict__ w3,
                                             const float* __restrict__ b3g,
                                             float* __restrict__ eout) {
  __shared__ float A1c[32 * 68];
  __shared__ float wc[32 * 128];
  __shared__ float H2t[128 * 68];
  int t = threadIdx.x;
  int n0 = blockIdx.x * 4;
  int ty = t >> 4, tx = t & 15;

  float acc2[4][8];
#pragma unroll
  for (int i = 0; i < 4; ++i)
#pragma unroll
    for (int j = 0; j < 8; ++j) acc2[i][j] = 0.f;

  for (int kc = 0; kc < 2; ++kc) {
#pragma unroll
    for (int p = 0; p < 8; ++p) {
      int v = t + 256 * p;
      int r = v >> 5, k = v & 31;
      int node = n0 + (r >> 4);
      int jn = idx[node * 16 + (r & 15)];
      int kk = kc * 32 + k;
      float val = ab[node * 128 + kk] + ab[jn * 128 + 64 + kk] + b1g[kk];
      A1c[k * 68 + r] = fmaxf(val, 0.f);
    }
#pragma unroll
    for (int p = 0; p < 16; ++p) {
      int v = t + 256 * p;
      int k = v >> 7, c = v & 127;
      wc[k * 128 + c] = w2[(kc * 32 + k) * 128 + c];
    }
    __syncthreads();
    for (int k = 0; k < 32; ++k) {
      float4 a = *(const float4*)&A1c[k * 68 + ty * 4];
      float4 b0 = *(const float4*)&wc[k * 128 + tx * 8];
      float4 b1 = *(const float4*)&wc[k * 128 + tx * 8 + 4];
      float aa[4] = {a.x, a.y, a.z, a.w};
      float bb[8] = {b0.x, b0.y, b0.z, b0.w, b1.x, b1.y, b1.z, b1.w};
#pragma unroll
      for (int ri = 0; ri < 4; ++ri)
#pragma unroll
        for (int cii = 0; cii < 8; ++cii) acc2[ri][cii] += aa[ri] * bb[cii];
    }
    __syncthreads();
  }

#pragma unroll
  for (int cii = 0; cii < 8; ++cii) {
    float bb = b2g[tx * 8 + cii];
#pragma unroll
    for (int ri = 0; ri < 4; ++ri)
      H2t[(tx * 8 + cii) * 68 + ty * 4 + ri] = fmaxf(acc2[ri][cii] + bb, 0.f);
  }
  __syncthreads();

  float acc3[4][8];
#pragma unroll
  for (int i = 0; i < 4; ++i)
#pragma unroll
    for (int j = 0; j < 8; ++j) acc3[i][j] = 0.f;

  for (int kt = 0; kt < 4; ++kt) {
#pragma unroll
    for (int p = 0; p < 16; ++p) {
      int v = t + 256 * p;
      int k = v >> 7, c = v & 127;
      wc[k * 128 + c] = w3[(kt * 32 + k) * 128 + c];
    }
    __syncthreads();
    for (int k = 0; k < 32; ++k) {
      float4 a = *(const float4*)&H2t[(kt * 32 + k) * 68 + ty * 4];
      float4 b0 = *(const float4*)&wc[k * 128 + tx * 8];
      float4 b1 = *(const float4*)&wc[k * 128 + tx * 8 + 4];
      float aa[4] = {a.x, a.y, a.z, a.w};
      float bb[8] = {b0.x, b0.y, b0.z, b0.w, b1.x, b1.y, b1.z, b1.w};
#pragma unroll
      for (int ri = 0; ri < 4; ++ri)
#pragma unroll
        for (int cii = 0; cii < 8; ++cii) acc3[ri][cii] += aa[ri] * bb[cii];
    }
    __syncthreads();
  }

  float* red = A1c;
#pragma unroll
  for (int cii = 0; cii < 8; ++cii) {
    float m = fmaxf(fmaxf(acc3[0][cii], acc3[1][cii]), fmaxf(acc3[2][cii], acc3[3][cii]));
    red[ty * 128 + tx * 8 + cii] = m;
  }
  __syncthreads();
#pragma unroll
  for (int p = 0; p < 2; ++p) {
    int v = t * 2 + p;
    int g = v >> 7, c = v & 127;
    float m = fmaxf(fmaxf(red[(g * 4 + 0) * 128 + c], red[(g * 4 + 1) * 128 + c]),
                    fmaxf(red[(g * 4 + 2) * 128 + c], red[(g * 4 + 3) * 128 + c]));
    eout[(n0 + g) * 128 + c] = m + b3g[c];
  }
}

// ---------------- small epilogues ----------------
__global__ void k_e1n1(const float* __restrict__ e1, const float* __restrict__ n1,
                       float* s1) {
  int t = threadIdx.x;
  int node = blockIdx.x * 4 + (t >> 6);
  int lane = t & 63;
  float v0 = e1[node * 128 + lane] + n1[node * 128 + lane];
  float v1 = e1[node * 128 + 64 + lane] + n1[node * 128 + 64 + lane];
  float ss = v0 * v0 + v1 * v1;
#pragma unroll
  for (int off = 32; off; off >>= 1) ss += __shfl_down(ss, off, 64);
  if (lane == 0) s1[node] = sqrtf(ss);
}

__global__ void k_addinto(float* __restrict__ e, const float* __restrict__ n) {
  int v = blockIdx.x * 256 + threadIdx.x;
  e[v] += n[v];
}

__global__ void k_final(const float* __restrict__ s1, const float* __restrict__ e2n2,
                        const float* __restrict__ e3n3, float* __restrict__ out) {
  int t = threadIdx.x;
  int node = blockIdx.x * 4 + (t >> 6);
  int lane = t & 63;
  float s = s1[node];
  float z0 = s * e2n2[node * 128 + lane] * e3n3[node * 128 + lane];
  float z1 = s * e2n2[node * 128 + 64 + lane] * e3n3[node * 128 + 64 + lane];
  float m = fmaxf(z0, z1);
#pragma unroll
  for (int off = 32; off; off >>= 1) m = fmaxf(m, __shfl_xor(m, off, 64));
  float ex = expf(z0 - m) + expf(z1 - m);
#pragma unroll
  for (int off = 32; off; off >>= 1) ex += __shfl_xor(ex, off, 64);
  float lse = m + logf(ex);
  out[node * 128 + lane] = z0 - lse;
  out[node * 128 + 64 + lane] = z1 - lse;
}

// ---------------- host ----------------
extern "C" void kernel_launch(void* const* d_in, const int* in_sizes, int n_in,
                              void* d_out, int out_size, void* d_ws, size_t ws_size,
                              hipStream_t stream) {
  (void)in_sizes; (void)n_in; (void)out_size;
  const float* x  = (const float*)d_in[0];
  const int* ei   = (const int*)d_in[1];
  const float* ew = (const float*)d_in[2];
  const float* wg[3] = {(const float*)d_in[3], (const float*)d_in[5], (const float*)d_in[7]};
  const float* bg[3] = {(const float*)d_in[4], (const float*)d_in[6], (const float*)d_in[8]};
  const float* ew1[3] = {(const float*)d_in[9],  (const float*)d_in[15], (const float*)d_in[21]};
  const float* eb1[3] = {(const float*)d_in[10], (const float*)d_in[16], (const float*)d_in[22]};
  const float* ew2[3] = {(const float*)d_in[11], (const float*)d_in[17], (const float*)d_in[23]};
  const float* eb2[3] = {(const float*)d_in[12], (const float*)d_in[18], (const float*)d_in[24]};
  const float* ew3[3] = {(const float*)d_in[13], (const float*)d_in[19], (const float*)d_in[25]};
  const float* eb3[3] = {(const float*)d_in[14], (const float*)d_in[20], (const float*)d_in[26]};

  // ws layout (floats unless noted):
  // [0,N) dis | [N,2N) sn | [2N,3N) S1 | [3N,19N) idx (int)
  // then rowptr (N+256 int) | hist/cursor (N int) | srcS (E int) | normS (E float)
  // then 7 x N*H buffers
  size_t small = (size_t)(19 * N_ + (N_ + 256) + N_ + 2 * E_);
  size_t need = (small + (size_t)7 * N_ * H_) * sizeof(float);
  if (ws_size < need) return;

  float* ws  = (float*)d_ws;
  float* dis = ws;
  float* sn  = ws + N_;
  float* S1  = ws + 2 * N_;
  int* idx   = (int*)(ws + 3 * N_);
  int* rowptr = (int*)(ws + 19 * N_);
  int* hist   = rowptr + N_ + 256;   // doubles as cursor
  int* srcS   = hist + N_;
  float* normS = (float*)(srcS + E_);
  float* h   = normS + E_;
  float* n1  = h + N_ * H_;
  float* n2  = n1 + N_ * H_;
  float* n3  = n2 + N_ * H_;
  float* E2  = n3 + N_ * H_;          // e2 / e2+n2 (live l=1..final)
  float* E1  = E2 + N_ * H_;          // e1 (l=0), e3+n3 (l=2); free during knn
  float* ab  = E1 + N_ * H_;          // scratch; adjacent to E1

  bshort8* fragHi = (bshort8*)h;                      // 2 MB
  bshort8* fragLo = (bshort8*)(h + N_ * H_ / 2);      // 2 MB
  unsigned long long* candP = (unsigned long long*)E1;  // 128 x N u64 (aliases E1+ab)

  float* nl[3] = {n1, n2, n3};

  k_deg_init<<<N_ / 256, 256, 0, stream>>>(dis);
  k_deg_scatter<<<E_ / 256, 256, 0, stream>>>(ei, ew, dis);
  k_dis<<<N_ / 256, 256, 0, stream>>>(dis);
  hipMemsetAsync(hist, 0, N_ * sizeof(int), stream);
  k_hist<<<E_ / 256, 256, 0, stream>>>(ei, hist);
  k_scan<<<1, 256, 0, stream>>>(hist, rowptr);
  k_edgebuild<<<E_ / 256, 256, 0, stream>>>(ei, ew, dis, hist, srcS, normS);

  for (int l = 0; l < 3; ++l) {
    const float* inp = (l == 0) ? x : nl[l - 1];
    k_gemm128<<<256, 256, 0, stream>>>(inp, wg[l], h, 0);
    k_gcn_agg<<<N_ / 2, 256, 0, stream>>>(h, dis, rowptr, srcS, normS, bg[l], nl[l], sn);
    k_fragprep<<<N_ * 16 / 256, 256, 0, stream>>>(nl[l], fragHi, fragLo);
    k_knn<<<dim3(N_ / 32, 8), 256, 0, stream>>>(fragHi, fragLo, sn, candP);
    k_knnmerge<<<N_ / 256, 256, 0, stream>>>(candP, idx);
    k_gemm128<<<256, 256, 0, stream>>>(nl[l], ew1[l], ab, 1);
    float* etgt = (l == 1) ? E2 : E1;
    k_mlp<<<N_ / 4, 256, 0, stream>>>(ab, idx, ew2[l], eb1[l], eb2[l], ew3[l], eb3[l], etgt);
    if (l == 0) k_e1n1<<<N_ / 4, 256, 0, stream>>>(E1, n1, S1);
    if (l == 1) k_addinto<<<N_ * H_ / 256, 256, 0, stream>>>(E2, n2);
    if (l == 2) k_addinto<<<N_ * H_ / 256, 256, 0, stream>>>(E1, n3);
  }
  k_final<<<N_ / 4, 256, 0, stream>>>(S1, E2, E1, (float*)d_out);
}

// Round 5
// 1635.421 us; speedup vs baseline: 3.3750x; 1.2478x over previous
//
#include <hip/hip_runtime.h>
#include <math.h>

#define N_ 8192
#define H_ 128
#define E_ 262144
#define K_ 16
#define SLABJ 1024

typedef __attribute__((ext_vector_type(8))) short bshort8;
typedef __attribute__((ext_vector_type(16))) float f32x16;
typedef unsigned long long u64;

// ---------------- degree / normalization ----------------
__global__ void k_deg_init(float* deg) {
  int i = blockIdx.x * 256 + threadIdx.x;
  deg[i] = 1.0f;  // self-loop weight
}

__global__ void k_deg_scatter(const int* __restrict__ ei, const float* __restrict__ ew,
                              float* deg) {
  int e = blockIdx.x * 256 + threadIdx.x;
  atomicAdd(&deg[ei[E_ + e]], ew[e]);
}

__global__ void k_dis(float* deg) {
  int i = blockIdx.x * 256 + threadIdx.x;
  deg[i] = rsqrtf(deg[i]);  // deg >= 1 always
}

// ---------------- one-time CSR build (edge list is static) ----------------
__global__ void k_hist(const int* __restrict__ ei, int* hist) {
  int e = blockIdx.x * 256 + threadIdx.x;
  atomicAdd(&hist[ei[E_ + e]], 1);
}

__global__ void k_scan(int* hist, int* rowptr) {  // 1 block, 256 threads
  __shared__ int part[256];
  __shared__ int partx[257];
  int t = threadIdx.x;
  int base = t * 32;
  int loc[32];
  int s = 0;
#pragma unroll
  for (int i = 0; i < 32; ++i) { loc[i] = s; s += hist[base + i]; }
  part[t] = s;
  __syncthreads();
  if (t == 0) {
    int r = 0;
    for (int i = 0; i < 256; ++i) { partx[i] = r; r += part[i]; }
    partx[256] = r;
  }
  __syncthreads();
  int b = partx[t];
#pragma unroll
  for (int i = 0; i < 32; ++i) {
    rowptr[base + i] = b + loc[i];
    hist[base + i] = b + loc[i];  // hist becomes the scatter cursor
  }
  if (t == 0) rowptr[N_] = partx[256];
}

__global__ void k_edgebuild(const int* __restrict__ ei, const float* __restrict__ ew,
                            const float* __restrict__ dis, int* cursor,
                            int* __restrict__ srcS, float* __restrict__ normS) {
  int e = blockIdx.x * 256 + threadIdx.x;
  int s = ei[e], d = ei[E_ + e];
  int pos = atomicAdd(&cursor[d], 1);
  srcS[pos] = s;
  normS[pos] = dis[s] * ew[e] * dis[d];
}

// ---------------- generic [M x 128] @ [128 x 128] GEMM ----------------
__global__ __launch_bounds__(256) void k_gemm128(const float* __restrict__ A,
                                                 const float* __restrict__ W,
                                                 float* __restrict__ C, int mode) {
  __shared__ float Bs[32 * 132];
  __shared__ float Ast[32 * 33];
  int t = threadIdx.x;
  int r0 = blockIdx.x * 32;
  int ty = t >> 4, tx = t & 15;
  float acc[2][8];
#pragma unroll
  for (int i = 0; i < 2; ++i)
#pragma unroll
    for (int j = 0; j < 8; ++j) acc[i][j] = 0.f;

  for (int kt = 0; kt < 4; ++kt) {
#pragma unroll
    for (int p = 0; p < 16; ++p) {
      int v = t + 256 * p;  // 4096
      int k = v >> 7, c = v & 127;
      int kg = kt * 32 + k;
      float val;
      if (mode == 0) val = W[kg * 128 + c];
      else val = (c < 64) ? (W[kg * 64 + c] - W[(128 + kg) * 64 + c])
                          : W[(128 + kg) * 64 + (c - 64)];
      Bs[k * 132 + c] = val;
    }
#pragma unroll
    for (int p = 0; p < 4; ++p) {
      int v = t + 256 * p;  // 1024
      int r = v >> 5, k = v & 31;
      Ast[k * 33 + r] = A[(r0 + r) * 128 + kt * 32 + k];
    }
    __syncthreads();
    for (int k = 0; k < 32; ++k) {
      float a0 = Ast[k * 33 + ty * 2];
      float a1 = Ast[k * 33 + ty * 2 + 1];
      float4 b0 = *(const float4*)&Bs[k * 132 + tx * 8];
      float4 b1 = *(const float4*)&Bs[k * 132 + tx * 8 + 4];
      float bb[8] = {b0.x, b0.y, b0.z, b0.w, b1.x, b1.y, b1.z, b1.w};
#pragma unroll
      for (int j = 0; j < 8; ++j) {
        acc[0][j] += a0 * bb[j];
        acc[1][j] += a1 * bb[j];
      }
    }
    __syncthreads();
  }
#pragma unroll
  for (int rr = 0; rr < 2; ++rr) {
    float4 o0 = {acc[rr][0], acc[rr][1], acc[rr][2], acc[rr][3]};
    float4 o1 = {acc[rr][4], acc[rr][5], acc[rr][6], acc[rr][7]};
    *(float4*)&C[(r0 + ty * 2 + rr) * 128 + tx * 8] = o0;
    *(float4*)&C[(r0 + ty * 2 + rr) * 128 + tx * 8 + 4] = o1;
  }
}

// ---------------- fused GCN aggregation (CSR gather, no atomics) ----------------
__global__ __launch_bounds__(256) void k_gcn_agg(const float* __restrict__ h,
                                                 const float* __restrict__ dis,
                                                 const int* __restrict__ rowptr,
                                                 const int* __restrict__ srcS,
                                                 const float* __restrict__ normS,
                                                 const float* __restrict__ bg,
                                                 float* __restrict__ n_out,
                                                 float* __restrict__ sn) {
  __shared__ float part[4];
  int t = threadIdx.x;
  int i = blockIdx.x * 2 + (t >> 7);
  int c = t & 127;
  float di = dis[i];
  float a0 = di * di * h[i * 128 + c], a1 = 0.f, a2 = 0.f, a3 = 0.f;
  int e0 = rowptr[i], e1 = rowptr[i + 1];
  int e = e0;
  for (; e + 4 <= e1; e += 4) {
    int s0 = srcS[e], s1 = srcS[e + 1], s2 = srcS[e + 2], s3 = srcS[e + 3];
    float w0 = normS[e], w1 = normS[e + 1], w2 = normS[e + 2], w3 = normS[e + 3];
    a0 += w0 * h[s0 * 128 + c];
    a1 += w1 * h[s1 * 128 + c];
    a2 += w2 * h[s2 * 128 + c];
    a3 += w3 * h[s3 * 128 + c];
  }
  for (; e < e1; ++e) a0 += normS[e] * h[srcS[e] * 128 + c];
  float v = tanhf(a0 + a1 + a2 + a3 + bg[c]);
  n_out[i * 128 + c] = v;
  float vv = v * v;
#pragma unroll
  for (int off = 32; off; off >>= 1) vv += __shfl_down(vv, off, 64);
  if ((t & 63) == 0) part[t >> 6] = vv;
  __syncthreads();
  if ((t & 127) == 0) sn[i] = part[t >> 6] + part[(t >> 6) + 1];
}

// ---------------- bf16 hi/lo split + MFMA fragment packing ----------------
__device__ __forceinline__ unsigned short f2bf_rne(float x) {
  unsigned u = __builtin_bit_cast(unsigned, x);
  unsigned r = ((u >> 16) & 1u) + 0x7fffu;
  return (unsigned short)((u + r) >> 16);
}
__device__ __forceinline__ float bf2f(unsigned short b) {
  unsigned u = ((unsigned)b) << 16;
  return __builtin_bit_cast(float, u);
}

// src: [N][128] fp32 -> fragHi/fragLo: [N/32 tiles][8 ks][64 lanes][8 bf16]
__global__ void k_fragprep(const float* __restrict__ src, bshort8* __restrict__ hiA,
                           bshort8* __restrict__ loA) {
  int t = blockIdx.x * 256 + threadIdx.x;  // N*16 threads
  int j = t >> 4, slot = t & 15;
  const float* p = src + j * 128 + slot * 8;
  float4 f0 = *(const float4*)p;
  float4 f1 = *(const float4*)(p + 4);
  float f[8] = {f0.x, f0.y, f0.z, f0.w, f1.x, f1.y, f1.z, f1.w};
  bshort8 h, l;
#pragma unroll
  for (int i = 0; i < 8; ++i) {
    unsigned short hb = f2bf_rne(f[i]);
    float lf = f[i] - bf2f(hb);
    h[i] = (short)hb;
    l[i] = (short)f2bf_rne(lf);
  }
  int ks = slot >> 1, half = slot & 1;
  int dst = ((j >> 5) * 8 + ks) * 64 + half * 32 + (j & 31);
  hiA[dst] = h;
  loA[dst] = l;
}

// ---------------- packed-key helpers ----------------
__device__ __forceinline__ u64 packkey(float d, int j) {
  unsigned m = __builtin_bit_cast(unsigned, d);
  m = (m & 0x80000000u) ? ~m : (m | 0x80000000u);  // order-preserving fp32->u32
  return (((u64)m) << 32) | (unsigned)j;
}

__device__ __forceinline__ void ins8(u64* tk, u64 x) {
  bool c[8];
#pragma unroll
  for (int s = 0; s < 8; ++s) c[s] = x < tk[s];
#pragma unroll
  for (int s = 7; s >= 1; --s) tk[s] = c[s - 1] ? tk[s - 1] : (c[s] ? x : tk[s]);
  tk[0] = c[0] ? x : tk[0];
}

__device__ __forceinline__ void ins16(u64* tk, u64 x) {
  bool c[16];
#pragma unroll
  for (int s = 0; s < 16; ++s) c[s] = x < tk[s];
#pragma unroll
  for (int s = 15; s >= 1; --s) tk[s] = c[s - 1] ? tk[s - 1] : (c[s] ? x : tk[s]);
  tk[0] = c[0] ? x : tk[0];
}

// ---------------- phase A: per-slab sorted-16 (from per-lane top-8) ----------------
// Scans slabs 0..3 (first 4096 j). Produces candA[(slab*16+s)*N + q], sorted per slab.
__global__ __launch_bounds__(256, 3) void k_knnA(const bshort8* __restrict__ fragHi,
                                                 const bshort8* __restrict__ fragLo,
                                                 const float* __restrict__ sn,
                                                 u64* __restrict__ candA) {
  __shared__ float snS[SLABJ];        // 4 KB
  __shared__ u64 mbuf[32 * 65];       // 16.6 KB
  int t = threadIdx.x;
  int qtile = blockIdx.x, slab = blockIdx.y;
  int wave = t >> 6, lane = t & 63;
  int q = lane & 31, half = lane >> 5;

#pragma unroll
  for (int p = 0; p < 4; ++p) snS[t + 256 * p] = sn[slab * SLABJ + t + 256 * p];

  bshort8 bHi[8], bLo[8];
#pragma unroll
  for (int ks = 0; ks < 8; ++ks) {
    int o = (qtile * 8 + ks) * 64 + lane;
    bHi[ks] = fragHi[o];
    bLo[ks] = fragLo[o];
  }
  __syncthreads();

  u64 tk[8];
#pragma unroll
  for (int s = 0; s < 8; ++s) tk[s] = ~0ULL;

  for (int ti = 0; ti < 8; ++ti) {
    int jt = slab * 32 + wave * 8 + ti;
    f32x16 acc;
#pragma unroll
    for (int r = 0; r < 16; ++r) acc[r] = 0.f;
    {
      bshort8 aH[4], aL[4];
#pragma unroll
      for (int k4 = 0; k4 < 4; ++k4) {
        int o = (jt * 8 + k4) * 64 + lane;
        aH[k4] = fragHi[o];
        aL[k4] = fragLo[o];
      }
#pragma unroll
      for (int k4 = 0; k4 < 4; ++k4) {
        acc = __builtin_amdgcn_mfma_f32_32x32x16_bf16(aL[k4], bHi[k4], acc, 0, 0, 0);
        acc = __builtin_amdgcn_mfma_f32_32x32x16_bf16(aH[k4], bLo[k4], acc, 0, 0, 0);
        acc = __builtin_amdgcn_mfma_f32_32x32x16_bf16(aH[k4], bHi[k4], acc, 0, 0, 0);
      }
    }
    {
      bshort8 aH[4], aL[4];
#pragma unroll
      for (int k4 = 0; k4 < 4; ++k4) {
        int o = (jt * 8 + 4 + k4) * 64 + lane;
        aH[k4] = fragHi[o];
        aL[k4] = fragLo[o];
      }
#pragma unroll
      for (int k4 = 0; k4 < 4; ++k4) {
        acc = __builtin_amdgcn_mfma_f32_32x32x16_bf16(aL[k4], bHi[4 + k4], acc, 0, 0, 0);
        acc = __builtin_amdgcn_mfma_f32_32x32x16_bf16(aH[k4], bLo[4 + k4], acc, 0, 0, 0);
        acc = __builtin_amdgcn_mfma_f32_32x32x16_bf16(aH[k4], bHi[4 + k4], acc, 0, 0, 0);
      }
    }

    int jbase = (wave * 8 + ti) * 32;
#pragma unroll
    for (int rp = 0; rp < 8; ++rp) {
      int r0 = rp * 2;
      int row0 = (r0 & 3) + 8 * (r0 >> 2) + 4 * half;
      float d0 = snS[jbase + row0] - 2.0f * acc[r0];
      float d1 = snS[jbase + row0 + 1] - 2.0f * acc[r0 + 1];
      u64 k0 = packkey(d0, slab * SLABJ + jbase + row0);
      u64 k1 = packkey(d1, slab * SLABJ + jbase + row0 + 1);
      u64 km = k0 < k1 ? k0 : k1;
      if (km < tk[7]) {
        if (k0 < tk[7]) ins8(tk, k0);
        if (k1 < tk[7]) ins8(tk, k1);
      }
    }
  }

  int g = wave * 2 + half;  // list id 0..7
  __syncthreads();
#pragma unroll
  for (int s = 0; s < 8; ++s) mbuf[q * 65 + g * 8 + s] = tk[s];
  __syncthreads();
  if (t < 32) {
    int qq = qtile * 32 + t;
    int base = t * 65;
    int h0 = 0, h1 = 0, h2 = 0, h3 = 0, h4 = 0, h5 = 0, h6 = 0, h7 = 0;
    for (int step = 0; step < 16; ++step) {
      u64 best = (h0 < 8) ? mbuf[base + h0] : ~0ULL;
      int bg = 0;
      u64 b;
      b = (h1 < 8) ? mbuf[base + 8 + h1] : ~0ULL;  if (b < best) { best = b; bg = 1; }
      b = (h2 < 8) ? mbuf[base + 16 + h2] : ~0ULL; if (b < best) { best = b; bg = 2; }
      b = (h3 < 8) ? mbuf[base + 24 + h3] : ~0ULL; if (b < best) { best = b; bg = 3; }
      b = (h4 < 8) ? mbuf[base + 32 + h4] : ~0ULL; if (b < best) { best = b; bg = 4; }
      b = (h5 < 8) ? mbuf[base + 40 + h5] : ~0ULL; if (b < best) { best = b; bg = 5; }
      b = (h6 < 8) ? mbuf[base + 48 + h6] : ~0ULL; if (b < best) { best = b; bg = 6; }
      b = (h7 < 8) ? mbuf[base + 56 + h7] : ~0ULL; if (b < best) { best = b; bg = 7; }
      candA[(slab * 16 + step) * N_ + qq] = best;
      h0 += (bg == 0); h1 += (bg == 1); h2 += (bg == 2); h3 += (bg == 3);
      h4 += (bg == 4); h5 += (bg == 5); h6 += (bg == 6); h7 += (bg == 7);
    }
  }
}

// tau = 16th smallest of the 4 slabs' sorted-16 union (provable upper bound on d16)
__global__ void k_tau(const u64* __restrict__ candA, u64* __restrict__ tauKey) {
  int q = blockIdx.x * 256 + threadIdx.x;
  int h0 = 0, h1 = 0, h2 = 0, h3 = 0;
  u64 best = 0;
  for (int step = 0; step < 16; ++step) {
    best = candA[h0 * N_ + q];
    int bg = 0;
    u64 b;
    b = candA[(16 + h1) * N_ + q]; if (b < best) { best = b; bg = 1; }
    b = candA[(32 + h2) * N_ + q]; if (b < best) { best = b; bg = 2; }
    b = candA[(48 + h3) * N_ + q]; if (b < best) { best = b; bg = 3; }
    h0 += (bg == 0); h1 += (bg == 1); h2 += (bg == 2); h3 += (bg == 3);
  }
  tauKey[q] = best;
}

// ---------------- phase B: dense scan with tau filter, append accepts ----------------
__global__ __launch_bounds__(256, 3) void k_knnB(const bshort8* __restrict__ fragHi,
                                                 const bshort8* __restrict__ fragLo,
                                                 const float* __restrict__ sn,
                                                 const u64* __restrict__ tauKey,
                                                 int* __restrict__ cursor,
                                                 u64* __restrict__ accept) {
  __shared__ float snS[SLABJ];  // 4 KB
  int t = threadIdx.x;
  int qtile = blockIdx.x, slab = blockIdx.y;
  int wave = t >> 6, lane = t & 63;
  int q = lane & 31, half = lane >> 5;
  int qg = qtile * 32 + q;

#pragma unroll
  for (int p = 0; p < 4; ++p) snS[t + 256 * p] = sn[slab * SLABJ + t + 256 * p];

  bshort8 bHi[8], bLo[8];
#pragma unroll
  for (int ks = 0; ks < 8; ++ks) {
    int o = (qtile * 8 + ks) * 64 + lane;
    bHi[ks] = fragHi[o];
    bLo[ks] = fragLo[o];
  }
  u64 tau = tauKey[qg];
  __syncthreads();

  for (int ti = 0; ti < 8; ++ti) {
    int jt = slab * 32 + wave * 8 + ti;
    f32x16 acc;
#pragma unroll
    for (int r = 0; r < 16; ++r) acc[r] = 0.f;
    {
      bshort8 aH[4], aL[4];
#pragma unroll
      for (int k4 = 0; k4 < 4; ++k4) {
        int o = (jt * 8 + k4) * 64 + lane;
        aH[k4] = fragHi[o];
        aL[k4] = fragLo[o];
      }
#pragma unroll
      for (int k4 = 0; k4 < 4; ++k4) {
        acc = __builtin_amdgcn_mfma_f32_32x32x16_bf16(aL[k4], bHi[k4], acc, 0, 0, 0);
        acc = __builtin_amdgcn_mfma_f32_32x32x16_bf16(aH[k4], bLo[k4], acc, 0, 0, 0);
        acc = __builtin_amdgcn_mfma_f32_32x32x16_bf16(aH[k4], bHi[k4], acc, 0, 0, 0);
      }
    }
    {
      bshort8 aH[4], aL[4];
#pragma unroll
      for (int k4 = 0; k4 < 4; ++k4) {
        int o = (jt * 8 + 4 + k4) * 64 + lane;
        aH[k4] = fragHi[o];
        aL[k4] = fragLo[o];
      }
#pragma unroll
      for (int k4 = 0; k4 < 4; ++k4) {
        acc = __builtin_amdgcn_mfma_f32_32x32x16_bf16(aL[k4], bHi[4 + k4], acc, 0, 0, 0);
        acc = __builtin_amdgcn_mfma_f32_32x32x16_bf16(aH[k4], bLo[4 + k4], acc, 0, 0, 0);
        acc = __builtin_amdgcn_mfma_f32_32x32x16_bf16(aH[k4], bHi[4 + k4], acc, 0, 0, 0);
      }
    }

    int jbase = (wave * 8 + ti) * 32;
#pragma unroll
    for (int rp = 0; rp < 8; ++rp) {
      int r0 = rp * 2;
      int row0 = (r0 & 3) + 8 * (r0 >> 2) + 4 * half;
      float d0 = snS[jbase + row0] - 2.0f * acc[r0];
      float d1 = snS[jbase + row0 + 1] - 2.0f * acc[r0 + 1];
      u64 k0 = packkey(d0, slab * SLABJ + jbase + row0);
      u64 k1 = packkey(d1, slab * SLABJ + jbase + row0 + 1);
      if (k0 <= tau) {
        int pos = atomicAdd(&cursor[qg], 1);
        if (pos < 128) accept[pos * N_ + qg] = k0;
      }
      if (k1 <= tau) {
        int pos = atomicAdd(&cursor[qg], 1);
        if (pos < 128) accept[pos * N_ + qg] = k1;
      }
    }
  }
}

// ---------------- phase C: exact top-16 of survivors ----------------
__global__ void k_select(const u64* __restrict__ accept, const int* __restrict__ cursor,
                         int* __restrict__ idxo) {
  int q = blockIdx.x * 256 + threadIdx.x;
  int c = cursor[q];
  if (c > 128) c = 128;
  u64 tk[16];
#pragma unroll
  for (int s = 0; s < 16; ++s) tk[s] = ~0ULL;
  for (int i = 0; i < c; ++i) {
    u64 x = accept[i * N_ + q];
    if (x < tk[15]) ins16(tk, x);
  }
#pragma unroll
  for (int s = 0; s < 16; ++s) idxo[q * 16 + s] = (int)(unsigned)(tk[s] & 0xffffffffULL);
}

// ---------------- fused EdgeConv MLP (h1 gather -> G2 -> G3 -> max) ----------------
__global__ __launch_bounds__(256) void k_mlp(const float* __restrict__ ab,
                                             const int* __restrict__ idx,
                                             const float* __restrict__ w2,
                                             const float* __restrict__ b1g,
                                             const float* __restrict__ b2g,
                                             const float* __restrict__ w3,
                                             const float* __restrict__ b3g,
                                             float* __restrict__ eout) {
  __shared__ float A1c[32 * 68];
  __shared__ float wc[32 * 128];
  __shared__ float H2t[128 * 68];
  int t = threadIdx.x;
  int n0 = blockIdx.x * 4;
  int ty = t >> 4, tx = t & 15;

  float acc2[4][8];
#pragma unroll
  for (int i = 0; i < 4; ++i)
#pragma unroll
    for (int j = 0; j < 8; ++j) acc2[i][j] = 0.f;

  for (int kc = 0; kc < 2; ++kc) {
#pragma unroll
    for (int p = 0; p < 8; ++p) {
      int v = t + 256 * p;
      int r = v >> 5, k = v & 31;
      int node = n0 + (r >> 4);
      int jn = idx[node * 16 + (r & 15)];
      int kk = kc * 32 + k;
      float val = ab[node * 128 + kk] + ab[jn * 128 + 64 + kk] + b1g[kk];
      A1c[k * 68 + r] = fmaxf(val, 0.f);
    }
#pragma unroll
    for (int p = 0; p < 16; ++p) {
      int v = t + 256 * p;
      int k = v >> 7, c = v & 127;
      wc[k * 128 + c] = w2[(kc * 32 + k) * 128 + c];
    }
    __syncthreads();
    for (int k = 0; k < 32; ++k) {
      float4 a = *(const float4*)&A1c[k * 68 + ty * 4];
      float4 b0 = *(const float4*)&wc[k * 128 + tx * 8];
      float4 b1 = *(const float4*)&wc[k * 128 + tx * 8 + 4];
      float aa[4] = {a.x, a.y, a.z, a.w};
      float bb[8] = {b0.x, b0.y, b0.z, b0.w, b1.x, b1.y, b1.z, b1.w};
#pragma unroll
      for (int ri = 0; ri < 4; ++ri)
#pragma unroll
        for (int cii = 0; cii < 8; ++cii) acc2[ri][cii] += aa[ri] * bb[cii];
    }
    __syncthreads();
  }

#pragma unroll
  for (int cii = 0; cii < 8; ++cii) {
    float bb = b2g[tx * 8 + cii];
#pragma unroll
    for (int ri = 0; ri < 4; ++ri)
      H2t[(tx * 8 + cii) * 68 + ty * 4 + ri] = fmaxf(acc2[ri][cii] + bb, 0.f);
  }
  __syncthreads();

  float acc3[4][8];
#pragma unroll
  for (int i = 0; i < 4; ++i)
#pragma unroll
    for (int j = 0; j < 8; ++j) acc3[i][j] = 0.f;

  for (int kt = 0; kt < 4; ++kt) {
#pragma unroll
    for (int p = 0; p < 16; ++p) {
      int v = t + 256 * p;
      int k = v >> 7, c = v & 127;
      wc[k * 128 + c] = w3[(kt * 32 + k) * 128 + c];
    }
    __syncthreads();
    for (int k = 0; k < 32; ++k) {
      float4 a = *(const float4*)&H2t[(kt * 32 + k) * 68 + ty * 4];
      float4 b0 = *(const float4*)&wc[k * 128 + tx * 8];
      float4 b1 = *(const float4*)&wc[k * 128 + tx * 8 + 4];
      float aa[4] = {a.x, a.y, a.z, a.w};
      float bb[8] = {b0.x, b0.y, b0.z, b0.w, b1.x, b1.y, b1.z, b1.w};
#pragma unroll
      for (int ri = 0; ri < 4; ++ri)
#pragma unroll
        for (int cii = 0; cii < 8; ++cii) acc3[ri][cii] += aa[ri] * bb[cii];
    }
    __syncthreads();
  }

  float* red = A1c;
#pragma unroll
  for (int cii = 0; cii < 8; ++cii) {
    float m = fmaxf(fmaxf(acc3[0][cii], acc3[1][cii]), fmaxf(acc3[2][cii], acc3[3][cii]));
    red[ty * 128 + tx * 8 + cii] = m;
  }
  __syncthreads();
#pragma unroll
  for (int p = 0; p < 2; ++p) {
    int v = t * 2 + p;
    int g = v >> 7, c = v & 127;
    float m = fmaxf(fmaxf(red[(g * 4 + 0) * 128 + c], red[(g * 4 + 1) * 128 + c]),
                    fmaxf(red[(g * 4 + 2) * 128 + c], red[(g * 4 + 3) * 128 + c]));
    eout[(n0 + g) * 128 + c] = m + b3g[c];
  }
}

// ---------------- small epilogues ----------------
__global__ void k_e1n1(const float* __restrict__ e1, const float* __restrict__ n1,
                       float* s1) {
  int t = threadIdx.x;
  int node = blockIdx.x * 4 + (t >> 6);
  int lane = t & 63;
  float v0 = e1[node * 128 + lane] + n1[node * 128 + lane];
  float v1 = e1[node * 128 + 64 + lane] + n1[node * 128 + 64 + lane];
  float ss = v0 * v0 + v1 * v1;
#pragma unroll
  for (int off = 32; off; off >>= 1) ss += __shfl_down(ss, off, 64);
  if (lane == 0) s1[node] = sqrtf(ss);
}

__global__ void k_addinto(float* __restrict__ e, const float* __restrict__ n) {
  int v = blockIdx.x * 256 + threadIdx.x;
  e[v] += n[v];
}

__global__ void k_final(const float* __restrict__ s1, const float* __restrict__ e2n2,
                        const float* __restrict__ e3n3, float* __restrict__ out) {
  int t = threadIdx.x;
  int node = blockIdx.x * 4 + (t >> 6);
  int lane = t & 63;
  float s = s1[node];
  float z0 = s * e2n2[node * 128 + lane] * e3n3[node * 128 + lane];
  float z1 = s * e2n2[node * 128 + 64 + lane] * e3n3[node * 128 + 64 + lane];
  float m = fmaxf(z0, z1);
#pragma unroll
  for (int off = 32; off; off >>= 1) m = fmaxf(m, __shfl_xor(m, off, 64));
  float ex = expf(z0 - m) + expf(z1 - m);
#pragma unroll
  for (int off = 32; off; off >>= 1) ex += __shfl_xor(ex, off, 64);
  float lse = m + logf(ex);
  out[node * 128 + lane] = z0 - lse;
  out[node * 128 + 64 + lane] = z1 - lse;
}

// ---------------- host ----------------
extern "C" void kernel_launch(void* const* d_in, const int* in_sizes, int n_in,
                              void* d_out, int out_size, void* d_ws, size_t ws_size,
                              hipStream_t stream) {
  (void)in_sizes; (void)n_in; (void)out_size;
  const float* x  = (const float*)d_in[0];
  const int* ei   = (const int*)d_in[1];
  const float* ew = (const float*)d_in[2];
  const float* wg[3] = {(const float*)d_in[3], (const float*)d_in[5], (const float*)d_in[7]};
  const float* bg[3] = {(const float*)d_in[4], (const float*)d_in[6], (const float*)d_in[8]};
  const float* ew1[3] = {(const float*)d_in[9],  (const float*)d_in[15], (const float*)d_in[21]};
  const float* eb1[3] = {(const float*)d_in[10], (const float*)d_in[16], (const float*)d_in[22]};
  const float* ew2[3] = {(const float*)d_in[11], (const float*)d_in[17], (const float*)d_in[23]};
  const float* eb2[3] = {(const float*)d_in[12], (const float*)d_in[18], (const float*)d_in[24]};
  const float* ew3[3] = {(const float*)d_in[13], (const float*)d_in[19], (const float*)d_in[25]};
  const float* eb3[3] = {(const float*)d_in[14], (const float*)d_in[20], (const float*)d_in[26]};

  // ws floats:
  // [0,N) dis | [N,2N) sn | [2N,3N) S1 | [3N,19N) idx(int) | [19N,21N) tauKey(u64)
  // [21N,22N) cursor(int) | rowptr(N+256 int) | hist(N int) | srcS(E int) | normS(E f)
  // then 7 x N*H float buffers
  size_t small = (size_t)(22 * N_ + (N_ + 256) + N_ + 2 * E_);
  size_t need = (small + (size_t)7 * N_ * H_) * sizeof(float);
  if (ws_size < need) return;

  float* ws  = (float*)d_ws;
  float* dis = ws;
  float* sn  = ws + N_;
  float* S1  = ws + 2 * N_;
  int* idx   = (int*)(ws + 3 * N_);
  u64* tauKey = (u64*)(ws + 19 * N_);
  int* cursor = (int*)(ws + 21 * N_);
  int* rowptr = (int*)(ws + 22 * N_);
  int* hist   = rowptr + N_ + 256;
  int* srcS   = hist + N_;
  float* normS = (float*)(srcS + E_);
  float* h   = normS + E_;
  float* n1  = h + N_ * H_;
  float* n2  = n1 + N_ * H_;
  float* n3  = n2 + N_ * H_;
  float* E2  = n3 + N_ * H_;          // e2 / e2+n2 (live l=1..final)
  float* E1  = E2 + N_ * H_;          // e1 (l=0), e3+n3 (l=2); free during knn
  float* ab  = E1 + N_ * H_;          // scratch; adjacent to E1

  bshort8* fragHi = (bshort8*)h;                 // 2 MB
  bshort8* fragLo = (bshort8*)(h + N_ * H_ / 2); // 2 MB
  u64* candA  = (u64*)E1;                        // 64 x N u64 (4 MB), phase A only
  u64* accept = (u64*)E1;                        // 128 x N u64 (8 MB = E1+ab)

  float* nl[3] = {n1, n2, n3};

  k_deg_init<<<N_ / 256, 256, 0, stream>>>(dis);
  k_deg_scatter<<<E_ / 256, 256, 0, stream>>>(ei, ew, dis);
  k_dis<<<N_ / 256, 256, 0, stream>>>(dis);
  hipMemsetAsync(hist, 0, N_ * sizeof(int), stream);
  k_hist<<<E_ / 256, 256, 0, stream>>>(ei, hist);
  k_scan<<<1, 256, 0, stream>>>(hist, rowptr);
  k_edgebuild<<<E_ / 256, 256, 0, stream>>>(ei, ew, dis, hist, srcS, normS);

  for (int l = 0; l < 3; ++l) {
    const float* inp = (l == 0) ? x : nl[l - 1];
    k_gemm128<<<256, 256, 0, stream>>>(inp, wg[l], h, 0);
    k_gcn_agg<<<N_ / 2, 256, 0, stream>>>(h, dis, rowptr, srcS, normS, bg[l], nl[l], sn);
    k_fragprep<<<N_ * 16 / 256, 256, 0, stream>>>(nl[l], fragHi, fragLo);
    k_knnA<<<dim3(N_ / 32, 4), 256, 0, stream>>>(fragHi, fragLo, sn, candA);
    k_tau<<<N_ / 256, 256, 0, stream>>>(candA, tauKey);
    hipMemsetAsync(cursor, 0, N_ * sizeof(int), stream);
    k_knnB<<<dim3(N_ / 32, 8), 256, 0, stream>>>(fragHi, fragLo, sn, tauKey, cursor, accept);
    k_select<<<N_ / 256, 256, 0, stream>>>(accept, cursor, idx);
    k_gemm128<<<256, 256, 0, stream>>>(nl[l], ew1[l], ab, 1);
    float* etgt = (l == 1) ? E2 : E1;
    k_mlp<<<N_ / 4, 256, 0, stream>>>(ab, idx, ew2[l], eb1[l], eb2[l], ew3[l], eb3[l], etgt);
    if (l == 0) k_e1n1<<<N_ / 4, 256, 0, stream>>>(E1, n1, S1);
    if (l == 1) k_addinto<<<N_ * H_ / 256, 256, 0, stream>>>(E2, n2);
    if (l == 2) k_addinto<<<N_ * H_ / 256, 256, 0, stream>>>(E1, n3);
  }
  k_final<<<N_ / 4, 256, 0, stream>>>(S1, E2, E1, (float*)d_out);
}

// Round 6
// 1194.332 us; speedup vs baseline: 4.6214x; 1.3693x over previous
//
#include <hip/hip_runtime.h>
#include <math.h>

#define N_ 8192
#define H_ 128
#define E_ 262144
#define K_ 16
#define SLABJ 1024

typedef __attribute__((ext_vector_type(8))) short bshort8;
typedef __attribute__((ext_vector_type(16))) float f32x16;
typedef unsigned long long u64;

// ---------------- degree / normalization ----------------
__global__ void k_deg_init(float* deg) {
  int i = blockIdx.x * 256 + threadIdx.x;
  deg[i] = 1.0f;  // self-loop weight
}

__global__ void k_deg_scatter(const int* __restrict__ ei, const float* __restrict__ ew,
                              float* deg) {
  int e = blockIdx.x * 256 + threadIdx.x;
  atomicAdd(&deg[ei[E_ + e]], ew[e]);
}

__global__ void k_dis(float* deg) {
  int i = blockIdx.x * 256 + threadIdx.x;
  deg[i] = rsqrtf(deg[i]);  // deg >= 1 always
}

// ---------------- one-time CSR build (edge list is static) ----------------
__global__ void k_hist(const int* __restrict__ ei, int* hist) {
  int e = blockIdx.x * 256 + threadIdx.x;
  atomicAdd(&hist[ei[E_ + e]], 1);
}

__global__ void k_scan(int* hist, int* rowptr) {  // 1 block, 256 threads
  __shared__ int part[256];
  __shared__ int partx[257];
  int t = threadIdx.x;
  int base = t * 32;
  int loc[32];
  int s = 0;
#pragma unroll
  for (int i = 0; i < 32; ++i) { loc[i] = s; s += hist[base + i]; }
  part[t] = s;
  __syncthreads();
  if (t == 0) {
    int r = 0;
    for (int i = 0; i < 256; ++i) { partx[i] = r; r += part[i]; }
    partx[256] = r;
  }
  __syncthreads();
  int b = partx[t];
#pragma unroll
  for (int i = 0; i < 32; ++i) {
    rowptr[base + i] = b + loc[i];
    hist[base + i] = b + loc[i];  // hist becomes the scatter cursor
  }
  if (t == 0) rowptr[N_] = partx[256];
}

__global__ void k_edgebuild(const int* __restrict__ ei, const float* __restrict__ ew,
                            const float* __restrict__ dis, int* cursor,
                            int* __restrict__ srcS, float* __restrict__ normS) {
  int e = blockIdx.x * 256 + threadIdx.x;
  int s = ei[e], d = ei[E_ + e];
  int pos = atomicAdd(&cursor[d], 1);
  srcS[pos] = s;
  normS[pos] = dis[s] * ew[e] * dis[d];
}

// ---------------- generic [M x 128] @ [128 x 128] GEMM ----------------
__global__ __launch_bounds__(256) void k_gemm128(const float* __restrict__ A,
                                                 const float* __restrict__ W,
                                                 float* __restrict__ C, int mode) {
  __shared__ float Bs[32 * 132];
  __shared__ float Ast[32 * 33];
  int t = threadIdx.x;
  int r0 = blockIdx.x * 32;
  int ty = t >> 4, tx = t & 15;
  float acc[2][8];
#pragma unroll
  for (int i = 0; i < 2; ++i)
#pragma unroll
    for (int j = 0; j < 8; ++j) acc[i][j] = 0.f;

  for (int kt = 0; kt < 4; ++kt) {
#pragma unroll
    for (int p = 0; p < 16; ++p) {
      int v = t + 256 * p;  // 4096
      int k = v >> 7, c = v & 127;
      int kg = kt * 32 + k;
      float val;
      if (mode == 0) val = W[kg * 128 + c];
      else val = (c < 64) ? (W[kg * 64 + c] - W[(128 + kg) * 64 + c])
                          : W[(128 + kg) * 64 + (c - 64)];
      Bs[k * 132 + c] = val;
    }
#pragma unroll
    for (int p = 0; p < 4; ++p) {
      int v = t + 256 * p;  // 1024
      int r = v >> 5, k = v & 31;
      Ast[k * 33 + r] = A[(r0 + r) * 128 + kt * 32 + k];
    }
    __syncthreads();
    for (int k = 0; k < 32; ++k) {
      float a0 = Ast[k * 33 + ty * 2];
      float a1 = Ast[k * 33 + ty * 2 + 1];
      float4 b0 = *(const float4*)&Bs[k * 132 + tx * 8];
      float4 b1 = *(const float4*)&Bs[k * 132 + tx * 8 + 4];
      float bb[8] = {b0.x, b0.y, b0.z, b0.w, b1.x, b1.y, b1.z, b1.w};
#pragma unroll
      for (int j = 0; j < 8; ++j) {
        acc[0][j] += a0 * bb[j];
        acc[1][j] += a1 * bb[j];
      }
    }
    __syncthreads();
  }
#pragma unroll
  for (int rr = 0; rr < 2; ++rr) {
    float4 o0 = {acc[rr][0], acc[rr][1], acc[rr][2], acc[rr][3]};
    float4 o1 = {acc[rr][4], acc[rr][5], acc[rr][6], acc[rr][7]};
    *(float4*)&C[(r0 + ty * 2 + rr) * 128 + tx * 8] = o0;
    *(float4*)&C[(r0 + ty * 2 + rr) * 128 + tx * 8 + 4] = o1;
  }
}

// ---------------- fused GCN aggregation (CSR gather, no atomics) ----------------
__global__ __launch_bounds__(256) void k_gcn_agg(const float* __restrict__ h,
                                                 const float* __restrict__ dis,
                                                 const int* __restrict__ rowptr,
                                                 const int* __restrict__ srcS,
                                                 const float* __restrict__ normS,
                                                 const float* __restrict__ bg,
                                                 float* __restrict__ n_out,
                                                 float* __restrict__ sn) {
  __shared__ float part[4];
  int t = threadIdx.x;
  int i = blockIdx.x * 2 + (t >> 7);
  int c = t & 127;
  float di = dis[i];
  float a0 = di * di * h[i * 128 + c], a1 = 0.f, a2 = 0.f, a3 = 0.f;
  int e0 = rowptr[i], e1 = rowptr[i + 1];
  int e = e0;
  for (; e + 4 <= e1; e += 4) {
    int s0 = srcS[e], s1 = srcS[e + 1], s2 = srcS[e + 2], s3 = srcS[e + 3];
    float w0 = normS[e], w1 = normS[e + 1], w2 = normS[e + 2], w3 = normS[e + 3];
    a0 += w0 * h[s0 * 128 + c];
    a1 += w1 * h[s1 * 128 + c];
    a2 += w2 * h[s2 * 128 + c];
    a3 += w3 * h[s3 * 128 + c];
  }
  for (; e < e1; ++e) a0 += normS[e] * h[srcS[e] * 128 + c];
  float v = tanhf(a0 + a1 + a2 + a3 + bg[c]);
  n_out[i * 128 + c] = v;
  float vv = v * v;
#pragma unroll
  for (int off = 32; off; off >>= 1) vv += __shfl_down(vv, off, 64);
  if ((t & 63) == 0) part[t >> 6] = vv;
  __syncthreads();
  if ((t & 127) == 0) sn[i] = part[t >> 6] + part[(t >> 6) + 1];
}

// ---------------- bf16 hi/lo split + MFMA fragment packing ----------------
__device__ __forceinline__ unsigned short f2bf_rne(float x) {
  unsigned u = __builtin_bit_cast(unsigned, x);
  unsigned r = ((u >> 16) & 1u) + 0x7fffu;
  return (unsigned short)((u + r) >> 16);
}
__device__ __forceinline__ float bf2f(unsigned short b) {
  unsigned u = ((unsigned)b) << 16;
  return __builtin_bit_cast(float, u);
}

// src: [N][128] fp32 -> fragHi/fragLo: [N/32 tiles][8 ks][64 lanes][8 bf16]
__global__ void k_fragprep(const float* __restrict__ src, bshort8* __restrict__ hiA,
                           bshort8* __restrict__ loA) {
  int t = blockIdx.x * 256 + threadIdx.x;  // N*16 threads
  int j = t >> 4, slot = t & 15;
  const float* p = src + j * 128 + slot * 8;
  float4 f0 = *(const float4*)p;
  float4 f1 = *(const float4*)(p + 4);
  float f[8] = {f0.x, f0.y, f0.z, f0.w, f1.x, f1.y, f1.z, f1.w};
  bshort8 h, l;
#pragma unroll
  for (int i = 0; i < 8; ++i) {
    unsigned short hb = f2bf_rne(f[i]);
    float lf = f[i] - bf2f(hb);
    h[i] = (short)hb;
    l[i] = (short)f2bf_rne(lf);
  }
  int ks = slot >> 1, half = slot & 1;
  int dst = ((j >> 5) * 8 + ks) * 64 + half * 32 + (j & 31);
  hiA[dst] = h;
  loA[dst] = l;
}

// ---------------- packed-key helpers ----------------
__device__ __forceinline__ u64 packkey(float d, int j) {
  unsigned m = __builtin_bit_cast(unsigned, d);
  m = (m & 0x80000000u) ? ~m : (m | 0x80000000u);  // order-preserving fp32->u32
  return (((u64)m) << 32) | (unsigned)j;
}

__device__ __forceinline__ void ins8(u64* tk, u64 x) {
  bool c[8];
#pragma unroll
  for (int s = 0; s < 8; ++s) c[s] = x < tk[s];
#pragma unroll
  for (int s = 7; s >= 1; --s) tk[s] = c[s - 1] ? tk[s - 1] : (c[s] ? x : tk[s]);
  tk[0] = c[0] ? x : tk[0];
}

__device__ __forceinline__ void ins16(u64* tk, u64 x) {
  bool c[16];
#pragma unroll
  for (int s = 0; s < 16; ++s) c[s] = x < tk[s];
#pragma unroll
  for (int s = 15; s >= 1; --s) tk[s] = c[s - 1] ? tk[s - 1] : (c[s] ? x : tk[s]);
  tk[0] = c[0] ? x : tk[0];
}

// ---------------- phase A: per-slab sorted-16 (from per-lane top-8) ----------------
__global__ __launch_bounds__(256, 3) void k_knnA(const bshort8* __restrict__ fragHi,
                                                 const bshort8* __restrict__ fragLo,
                                                 const float* __restrict__ sn,
                                                 u64* __restrict__ candA) {
  __shared__ float snS[SLABJ];        // 4 KB
  __shared__ u64 mbuf[32 * 65];       // 16.6 KB
  int t = threadIdx.x;
  int qtile = blockIdx.x, slab = blockIdx.y;
  int wave = t >> 6, lane = t & 63;
  int q = lane & 31, half = lane >> 5;

#pragma unroll
  for (int p = 0; p < 4; ++p) snS[t + 256 * p] = sn[slab * SLABJ + t + 256 * p];

  bshort8 bHi[8], bLo[8];
#pragma unroll
  for (int ks = 0; ks < 8; ++ks) {
    int o = (qtile * 8 + ks) * 64 + lane;
    bHi[ks] = fragHi[o];
    bLo[ks] = fragLo[o];
  }
  __syncthreads();

  u64 tk[8];
#pragma unroll
  for (int s = 0; s < 8; ++s) tk[s] = ~0ULL;

  for (int ti = 0; ti < 8; ++ti) {
    int jt = slab * 32 + wave * 8 + ti;
    f32x16 acc;
#pragma unroll
    for (int r = 0; r < 16; ++r) acc[r] = 0.f;
    {
      bshort8 aH[4], aL[4];
#pragma unroll
      for (int k4 = 0; k4 < 4; ++k4) {
        int o = (jt * 8 + k4) * 64 + lane;
        aH[k4] = fragHi[o];
        aL[k4] = fragLo[o];
      }
#pragma unroll
      for (int k4 = 0; k4 < 4; ++k4) {
        acc = __builtin_amdgcn_mfma_f32_32x32x16_bf16(aL[k4], bHi[k4], acc, 0, 0, 0);
        acc = __builtin_amdgcn_mfma_f32_32x32x16_bf16(aH[k4], bLo[k4], acc, 0, 0, 0);
        acc = __builtin_amdgcn_mfma_f32_32x32x16_bf16(aH[k4], bHi[k4], acc, 0, 0, 0);
      }
    }
    {
      bshort8 aH[4], aL[4];
#pragma unroll
      for (int k4 = 0; k4 < 4; ++k4) {
        int o = (jt * 8 + 4 + k4) * 64 + lane;
        aH[k4] = fragHi[o];
        aL[k4] = fragLo[o];
      }
#pragma unroll
      for (int k4 = 0; k4 < 4; ++k4) {
        acc = __builtin_amdgcn_mfma_f32_32x32x16_bf16(aL[k4], bHi[4 + k4], acc, 0, 0, 0);
        acc = __builtin_amdgcn_mfma_f32_32x32x16_bf16(aH[k4], bLo[4 + k4], acc, 0, 0, 0);
        acc = __builtin_amdgcn_mfma_f32_32x32x16_bf16(aH[k4], bHi[4 + k4], acc, 0, 0, 0);
      }
    }

    int jbase = (wave * 8 + ti) * 32;
#pragma unroll
    for (int rp = 0; rp < 8; ++rp) {
      int r0 = rp * 2;
      int row0 = (r0 & 3) + 8 * (r0 >> 2) + 4 * half;
      float d0 = snS[jbase + row0] - 2.0f * acc[r0];
      float d1 = snS[jbase + row0 + 1] - 2.0f * acc[r0 + 1];
      u64 k0 = packkey(d0, slab * SLABJ + jbase + row0);
      u64 k1 = packkey(d1, slab * SLABJ + jbase + row0 + 1);
      u64 km = k0 < k1 ? k0 : k1;
      if (km < tk[7]) {
        if (k0 < tk[7]) ins8(tk, k0);
        if (k1 < tk[7]) ins8(tk, k1);
      }
    }
  }

  int g = wave * 2 + half;  // list id 0..7
  __syncthreads();
#pragma unroll
  for (int s = 0; s < 8; ++s) mbuf[q * 65 + g * 8 + s] = tk[s];
  __syncthreads();
  if (t < 32) {
    int qq = qtile * 32 + t;
    int base = t * 65;
    int h0 = 0, h1 = 0, h2 = 0, h3 = 0, h4 = 0, h5 = 0, h6 = 0, h7 = 0;
    for (int step = 0; step < 16; ++step) {
      u64 best = (h0 < 8) ? mbuf[base + h0] : ~0ULL;
      int bg = 0;
      u64 b;
      b = (h1 < 8) ? mbuf[base + 8 + h1] : ~0ULL;  if (b < best) { best = b; bg = 1; }
      b = (h2 < 8) ? mbuf[base + 16 + h2] : ~0ULL; if (b < best) { best = b; bg = 2; }
      b = (h3 < 8) ? mbuf[base + 24 + h3] : ~0ULL; if (b < best) { best = b; bg = 3; }
      b = (h4 < 8) ? mbuf[base + 32 + h4] : ~0ULL; if (b < best) { best = b; bg = 4; }
      b = (h5 < 8) ? mbuf[base + 40 + h5] : ~0ULL; if (b < best) { best = b; bg = 5; }
      b = (h6 < 8) ? mbuf[base + 48 + h6] : ~0ULL; if (b < best) { best = b; bg = 6; }
      b = (h7 < 8) ? mbuf[base + 56 + h7] : ~0ULL; if (b < best) { best = b; bg = 7; }
      candA[(slab * 16 + step) * N_ + qq] = best;
      h0 += (bg == 0); h1 += (bg == 1); h2 += (bg == 2); h3 += (bg == 3);
      h4 += (bg == 4); h5 += (bg == 5); h6 += (bg == 6); h7 += (bg == 7);
    }
  }
}

// tau = 16th smallest of the 4 slabs' sorted-16 union (provable upper bound on d16)
__global__ void k_tau(const u64* __restrict__ candA, u64* __restrict__ tauKey) {
  int q = blockIdx.x * 256 + threadIdx.x;
  int h0 = 0, h1 = 0, h2 = 0, h3 = 0;
  u64 best = 0;
  for (int step = 0; step < 16; ++step) {
    best = candA[h0 * N_ + q];
    int bg = 0;
    u64 b;
    b = candA[(16 + h1) * N_ + q]; if (b < best) { best = b; bg = 1; }
    b = candA[(32 + h2) * N_ + q]; if (b < best) { best = b; bg = 2; }
    b = candA[(48 + h3) * N_ + q]; if (b < best) { best = b; bg = 3; }
    h0 += (bg == 0); h1 += (bg == 1); h2 += (bg == 2); h3 += (bg == 3);
  }
  tauKey[q] = best;
}

// ---------------- phase B: dense scan with tau filter, append accepts ----------------
__global__ __launch_bounds__(256, 3) void k_knnB(const bshort8* __restrict__ fragHi,
                                                 const bshort8* __restrict__ fragLo,
                                                 const float* __restrict__ sn,
                                                 const u64* __restrict__ tauKey,
                                                 int* __restrict__ cursor,
                                                 u64* __restrict__ accept) {
  __shared__ float snS[SLABJ];  // 4 KB
  int t = threadIdx.x;
  int qtile = blockIdx.x, slab = blockIdx.y;
  int wave = t >> 6, lane = t & 63;
  int q = lane & 31, half = lane >> 5;
  int qg = qtile * 32 + q;

#pragma unroll
  for (int p = 0; p < 4; ++p) snS[t + 256 * p] = sn[slab * SLABJ + t + 256 * p];

  bshort8 bHi[8], bLo[8];
#pragma unroll
  for (int ks = 0; ks < 8; ++ks) {
    int o = (qtile * 8 + ks) * 64 + lane;
    bHi[ks] = fragHi[o];
    bLo[ks] = fragLo[o];
  }
  u64 tau = tauKey[qg];
  __syncthreads();

  for (int ti = 0; ti < 8; ++ti) {
    int jt = slab * 32 + wave * 8 + ti;
    f32x16 acc;
#pragma unroll
    for (int r = 0; r < 16; ++r) acc[r] = 0.f;
    {
      bshort8 aH[4], aL[4];
#pragma unroll
      for (int k4 = 0; k4 < 4; ++k4) {
        int o = (jt * 8 + k4) * 64 + lane;
        aH[k4] = fragHi[o];
        aL[k4] = fragLo[o];
      }
#pragma unroll
      for (int k4 = 0; k4 < 4; ++k4) {
        acc = __builtin_amdgcn_mfma_f32_32x32x16_bf16(aL[k4], bHi[k4], acc, 0, 0, 0);
        acc = __builtin_amdgcn_mfma_f32_32x32x16_bf16(aH[k4], bLo[k4], acc, 0, 0, 0);
        acc = __builtin_amdgcn_mfma_f32_32x32x16_bf16(aH[k4], bHi[k4], acc, 0, 0, 0);
      }
    }
    {
      bshort8 aH[4], aL[4];
#pragma unroll
      for (int k4 = 0; k4 < 4; ++k4) {
        int o = (jt * 8 + 4 + k4) * 64 + lane;
        aH[k4] = fragHi[o];
        aL[k4] = fragLo[o];
      }
#pragma unroll
      for (int k4 = 0; k4 < 4; ++k4) {
        acc = __builtin_amdgcn_mfma_f32_32x32x16_bf16(aL[k4], bHi[4 + k4], acc, 0, 0, 0);
        acc = __builtin_amdgcn_mfma_f32_32x32x16_bf16(aH[k4], bLo[4 + k4], acc, 0, 0, 0);
        acc = __builtin_amdgcn_mfma_f32_32x32x16_bf16(aH[k4], bHi[4 + k4], acc, 0, 0, 0);
      }
    }

    int jbase = (wave * 8 + ti) * 32;
#pragma unroll
    for (int rp = 0; rp < 8; ++rp) {
      int r0 = rp * 2;
      int row0 = (r0 & 3) + 8 * (r0 >> 2) + 4 * half;
      float d0 = snS[jbase + row0] - 2.0f * acc[r0];
      float d1 = snS[jbase + row0 + 1] - 2.0f * acc[r0 + 1];
      u64 k0 = packkey(d0, slab * SLABJ + jbase + row0);
      u64 k1 = packkey(d1, slab * SLABJ + jbase + row0 + 1);
      if (k0 <= tau) {
        int pos = atomicAdd(&cursor[qg], 1);
        if (pos < 128) accept[pos * N_ + qg] = k0;
      }
      if (k1 <= tau) {
        int pos = atomicAdd(&cursor[qg], 1);
        if (pos < 128) accept[pos * N_ + qg] = k1;
      }
    }
  }
}

// ---------------- phase C: exact top-16 of survivors ----------------
__global__ void k_select(const u64* __restrict__ accept, const int* __restrict__ cursor,
                         int* __restrict__ idxo) {
  int q = blockIdx.x * 256 + threadIdx.x;
  int c = cursor[q];
  if (c > 128) c = 128;
  u64 tk[16];
#pragma unroll
  for (int s = 0; s < 16; ++s) tk[s] = ~0ULL;
  for (int i = 0; i < c; ++i) {
    u64 x = accept[i * N_ + q];
    if (x < tk[15]) ins16(tk, x);
  }
#pragma unroll
  for (int s = 0; s < 16; ++s) idxo[q * 16 + s] = (int)(unsigned)(tk[s] & 0xffffffffULL);
}

// ---------------- weight frag pre-pack for MFMA MLP ----------------
// w2 [64x128] -> [nt 4][ks 4][lane 64][8]; w3 [128x128] -> [nt 4][ks 8][lane 64][8]
__global__ void k_wprep(const float* __restrict__ w2, const float* __restrict__ w3,
                        bshort8* __restrict__ w2fH, bshort8* __restrict__ w2fL,
                        bshort8* __restrict__ w3fH, bshort8* __restrict__ w3fL) {
  int id = blockIdx.x * 256 + threadIdx.x;  // 3072
  const float* src;
  bshort8 *dH, *dL;
  int n, k0, slot;
  if (id < 1024) {
    int lane = id & 63, ks = (id >> 6) & 3, nt = id >> 8;
    n = nt * 32 + (lane & 31);
    k0 = ks * 16 + (lane >> 5) * 8;
    src = w2; dH = w2fH; dL = w2fL; slot = id;
  } else {
    int id2 = id - 1024;
    int lane = id2 & 63, ks = (id2 >> 6) & 7, nt = id2 >> 9;
    n = nt * 32 + (lane & 31);
    k0 = ks * 16 + (lane >> 5) * 8;
    src = w3; dH = w3fH; dL = w3fL; slot = id2;
  }
  bshort8 h, l;
#pragma unroll
  for (int i = 0; i < 8; ++i) {
    float v = src[(k0 + i) * 128 + n];
    unsigned short hb = f2bf_rne(v);
    h[i] = (short)hb;
    l[i] = (short)f2bf_rne(v - bf2f(hb));
  }
  dH[slot] = h;
  dL[slot] = l;
}

// ---------------- MFMA EdgeConv MLP (gather h1 -> G2 -> G3 -> max) ----------------
// Block = 4 nodes = 64 rows. hi/lo split bf16, 3-term MFMA per k-slice.
__global__ __launch_bounds__(256, 3) void k_mlpM(
    const float* __restrict__ ab, const int* __restrict__ idx,
    const bshort8* __restrict__ w2fH, const bshort8* __restrict__ w2fL,
    const bshort8* __restrict__ w3fH, const bshort8* __restrict__ w3fL,
    const float* __restrict__ b1g, const float* __restrict__ b2g,
    const float* __restrict__ b3g, float* __restrict__ eout) {
  __shared__ short h1H[64 * 68], h1L[64 * 68];    // 17 KB (stride 68 bf16 = 136 B, 8-aligned)
  __shared__ short h2H[64 * 132], h2L[64 * 132];  // 33.8 KB (stride 132 bf16 = 264 B)
  int t = threadIdx.x;
  int n0 = blockIdx.x * 4;
  int w = t >> 6, lane = t & 63, q = lane & 31, half = lane >> 5;

  // ---- h1 = relu(a[node] + b[jn] + b1), packed hi/lo into A-frag-readable LDS ----
  {
    int r = t >> 2;            // 0..63
    int kc = (t & 3) * 16;     // 0/16/32/48
    int node = n0 + (r >> 4);
    int jn = idx[node * 16 + (r & 15)];
    const float* pa = ab + node * 128 + kc;
    const float* pb = ab + jn * 128 + 64 + kc;
    const float* p1 = b1g + kc;
#pragma unroll
    for (int e4 = 0; e4 < 4; ++e4) {
      float4 va = *(const float4*)(pa + e4 * 4);
      float4 vb = *(const float4*)(pb + e4 * 4);
      float4 v1 = *(const float4*)(p1 + e4 * 4);
      float vals[4] = {va.x + vb.x + v1.x, va.y + vb.y + v1.y,
                       va.z + vb.z + v1.z, va.w + vb.w + v1.w};
      unsigned short hs[4], ls[4];
#pragma unroll
      for (int i = 0; i < 4; ++i) {
        float v = fmaxf(vals[i], 0.f);
        hs[i] = f2bf_rne(v);
        ls[i] = f2bf_rne(v - bf2f(hs[i]));
      }
      int off = r * 68 + kc + e4 * 4;
      *(u64*)&h1H[off] = ((u64)(unsigned short)hs[0]) | ((u64)(unsigned short)hs[1] << 16) |
                         ((u64)(unsigned short)hs[2] << 32) | ((u64)(unsigned short)hs[3] << 48);
      *(u64*)&h1L[off] = ((u64)(unsigned short)ls[0]) | ((u64)(unsigned short)ls[1] << 16) |
                         ((u64)(unsigned short)ls[2] << 32) | ((u64)(unsigned short)ls[3] << 48);
    }
  }

  // ---- weight B-fragments (per-wave column tile w) ----
  bshort8 c2H[4], c2L[4];
#pragma unroll
  for (int ks = 0; ks < 4; ++ks) {
    c2H[ks] = w2fH[(w * 4 + ks) * 64 + lane];
    c2L[ks] = w2fL[(w * 4 + ks) * 64 + lane];
  }
  bshort8 c3H[8], c3L[8];
#pragma unroll
  for (int ks = 0; ks < 8; ++ks) {
    c3H[ks] = w3fH[(w * 8 + ks) * 64 + lane];
    c3L[ks] = w3fL[(w * 8 + ks) * 64 + lane];
  }
  float bias2 = b2g[w * 32 + q];
  float bias3 = b3g[w * 32 + q];
  __syncthreads();

  // ---- G2: h2 = relu(h1 @ w2 + b2), K=64 ----
#pragma unroll
  for (int rt = 0; rt < 2; ++rt) {
    f32x16 acc;
#pragma unroll
    for (int r = 0; r < 16; ++r) acc[r] = 0.f;
#pragma unroll
    for (int ks = 0; ks < 4; ++ks) {
      int off = (rt * 32 + q) * 68 + ks * 16 + half * 8;
      union { bshort8 v; u64 u[2]; } aH, aL;
      aH.u[0] = *(const u64*)&h1H[off];
      aH.u[1] = *(const u64*)&h1H[off + 4];
      aL.u[0] = *(const u64*)&h1L[off];
      aL.u[1] = *(const u64*)&h1L[off + 4];
      acc = __builtin_amdgcn_mfma_f32_32x32x16_bf16(aL.v, c2H[ks], acc, 0, 0, 0);
      acc = __builtin_amdgcn_mfma_f32_32x32x16_bf16(aH.v, c2L[ks], acc, 0, 0, 0);
      acc = __builtin_amdgcn_mfma_f32_32x32x16_bf16(aH.v, c2H[ks], acc, 0, 0, 0);
    }
#pragma unroll
    for (int reg = 0; reg < 16; ++reg) {
      int row = rt * 32 + (reg & 3) + 8 * (reg >> 2) + 4 * half;
      float v = fmaxf(acc[reg] + bias2, 0.f);
      unsigned short hb = f2bf_rne(v);
      h2H[row * 132 + w * 32 + q] = (short)hb;
      h2L[row * 132 + w * 32 + q] = (short)f2bf_rne(v - bf2f(hb));
    }
  }
  __syncthreads();

  // ---- G3: out = h2 @ w3 + b3, K=128; then max over 16 neighbors ----
#pragma unroll
  for (int rt = 0; rt < 2; ++rt) {
    f32x16 acc;
#pragma unroll
    for (int r = 0; r < 16; ++r) acc[r] = 0.f;
#pragma unroll
    for (int ks = 0; ks < 8; ++ks) {
      int off = (rt * 32 + q) * 132 + ks * 16 + half * 8;
      union { bshort8 v; u64 u[2]; } aH, aL;
      aH.u[0] = *(const u64*)&h2H[off];
      aH.u[1] = *(const u64*)&h2H[off + 4];
      aL.u[0] = *(const u64*)&h2L[off];
      aL.u[1] = *(const u64*)&h2L[off + 4];
      acc = __builtin_amdgcn_mfma_f32_32x32x16_bf16(aL.v, c3H[ks], acc, 0, 0, 0);
      acc = __builtin_amdgcn_mfma_f32_32x32x16_bf16(aH.v, c3L[ks], acc, 0, 0, 0);
      acc = __builtin_amdgcn_mfma_f32_32x32x16_bf16(aH.v, c3H[ks], acc, 0, 0, 0);
    }
    // rows 0..15 of this 32-tile = node rt*2, rows 16..31 = node rt*2+1
    float mA = -INFINITY, mB = -INFINITY;
#pragma unroll
    for (int reg = 0; reg < 8; ++reg) mA = fmaxf(mA, acc[reg]);
#pragma unroll
    for (int reg = 8; reg < 16; ++reg) mB = fmaxf(mB, acc[reg]);
    mA = fmaxf(mA, __shfl_xor(mA, 32, 64));
    mB = fmaxf(mB, __shfl_xor(mB, 32, 64));
    int col = w * 32 + q;
    if (half == 0) eout[(n0 + rt * 2) * 128 + col] = mA + bias3;
    else eout[(n0 + rt * 2 + 1) * 128 + col] = mB + bias3;
  }
}

// ---------------- small epilogues ----------------
__global__ void k_e1n1(const float* __restrict__ e1, const float* __restrict__ n1,
                       float* s1) {
  int t = threadIdx.x;
  int node = blockIdx.x * 4 + (t >> 6);
  int lane = t & 63;
  float v0 = e1[node * 128 + lane] + n1[node * 128 + lane];
  float v1 = e1[node * 128 + 64 + lane] + n1[node * 128 + 64 + lane];
  float ss = v0 * v0 + v1 * v1;
#pragma unroll
  for (int off = 32; off; off >>= 1) ss += __shfl_down(ss, off, 64);
  if (lane == 0) s1[node] = sqrtf(ss);
}

__global__ void k_addinto(float* __restrict__ e, const float* __restrict__ n) {
  int v = blockIdx.x * 256 + threadIdx.x;
  e[v] += n[v];
}

__global__ void k_final(const float* __restrict__ s1, const float* __restrict__ e2n2,
                        const float* __restrict__ e3n3, float* __restrict__ out) {
  int t = threadIdx.x;
  int node = blockIdx.x * 4 + (t >> 6);
  int lane = t & 63;
  float s = s1[node];
  float z0 = s * e2n2[node * 128 + lane] * e3n3[node * 128 + lane];
  float z1 = s * e2n2[node * 128 + 64 + lane] * e3n3[node * 128 + 64 + lane];
  float m = fmaxf(z0, z1);
#pragma unroll
  for (int off = 32; off; off >>= 1) m = fmaxf(m, __shfl_xor(m, off, 64));
  float ex = expf(z0 - m) + expf(z1 - m);
#pragma unroll
  for (int off = 32; off; off >>= 1) ex += __shfl_xor(ex, off, 64);
  float lse = m + logf(ex);
  out[node * 128 + lane] = z0 - lse;
  out[node * 128 + 64 + lane] = z1 - lse;
}

// ---------------- host ----------------
extern "C" void kernel_launch(void* const* d_in, const int* in_sizes, int n_in,
                              void* d_out, int out_size, void* d_ws, size_t ws_size,
                              hipStream_t stream) {
  (void)in_sizes; (void)n_in; (void)out_size;
  const float* x  = (const float*)d_in[0];
  const int* ei   = (const int*)d_in[1];
  const float* ew = (const float*)d_in[2];
  const float* wg[3] = {(const float*)d_in[3], (const float*)d_in[5], (const float*)d_in[7]};
  const float* bg[3] = {(const float*)d_in[4], (const float*)d_in[6], (const float*)d_in[8]};
  const float* ew1[3] = {(const float*)d_in[9],  (const float*)d_in[15], (const float*)d_in[21]};
  const float* eb1[3] = {(const float*)d_in[10], (const float*)d_in[16], (const float*)d_in[22]};
  const float* ew2[3] = {(const float*)d_in[11], (const float*)d_in[17], (const float*)d_in[23]};
  const float* eb2[3] = {(const float*)d_in[12], (const float*)d_in[18], (const float*)d_in[24]};
  const float* ew3[3] = {(const float*)d_in[13], (const float*)d_in[19], (const float*)d_in[25]};
  const float* eb3[3] = {(const float*)d_in[14], (const float*)d_in[20], (const float*)d_in[26]};

  size_t small = (size_t)(22 * N_ + (N_ + 256) + N_ + 2 * E_);
  size_t need = (small + (size_t)7 * N_ * H_) * sizeof(float);
  if (ws_size < need) return;

  float* ws  = (float*)d_ws;
  float* dis = ws;
  float* sn  = ws + N_;
  float* S1  = ws + 2 * N_;
  int* idx   = (int*)(ws + 3 * N_);
  u64* tauKey = (u64*)(ws + 19 * N_);
  int* cursor = (int*)(ws + 21 * N_);
  int* rowptr = (int*)(ws + 22 * N_);
  int* hist   = rowptr + N_ + 256;
  int* srcS   = hist + N_;
  float* normS = (float*)(srcS + E_);
  float* h   = normS + E_;
  float* n1  = h + N_ * H_;
  float* n2  = n1 + N_ * H_;
  float* n3  = n2 + N_ * H_;
  float* E2  = n3 + N_ * H_;          // e2 / e2+n2 (live l=1..final)
  float* E1  = E2 + N_ * H_;          // e1 (l=0), e3+n3 (l=2); free during knn
  float* ab  = E1 + N_ * H_;          // scratch; adjacent to E1

  bshort8* fragHi = (bshort8*)h;                 // 2 MB (dead after knnB)
  bshort8* fragLo = (bshort8*)(h + N_ * H_ / 2); // 2 MB
  u64* candA  = (u64*)E1;                        // 64 x N u64 (phase A)
  u64* accept = (u64*)E1;                        // 128 x N u64 (phase B, E1+ab)
  // weight frags alias h (frags dead after k_select; h rewritten next layer)
  bshort8* w2fH = (bshort8*)h;
  bshort8* w2fL = w2fH + 1024;
  bshort8* w3fH = w2fL + 1024;
  bshort8* w3fL = w3fH + 2048;

  float* nl[3] = {n1, n2, n3};

  k_deg_init<<<N_ / 256, 256, 0, stream>>>(dis);
  k_deg_scatter<<<E_ / 256, 256, 0, stream>>>(ei, ew, dis);
  k_dis<<<N_ / 256, 256, 0, stream>>>(dis);
  hipMemsetAsync(hist, 0, N_ * sizeof(int), stream);
  k_hist<<<E_ / 256, 256, 0, stream>>>(ei, hist);
  k_scan<<<1, 256, 0, stream>>>(hist, rowptr);
  k_edgebuild<<<E_ / 256, 256, 0, stream>>>(ei, ew, dis, hist, srcS, normS);

  for (int l = 0; l < 3; ++l) {
    const float* inp = (l == 0) ? x : nl[l - 1];
    k_gemm128<<<256, 256, 0, stream>>>(inp, wg[l], h, 0);
    k_gcn_agg<<<N_ / 2, 256, 0, stream>>>(h, dis, rowptr, srcS, normS, bg[l], nl[l], sn);
    k_fragprep<<<N_ * 16 / 256, 256, 0, stream>>>(nl[l], fragHi, fragLo);
    k_knnA<<<dim3(N_ / 32, 4), 256, 0, stream>>>(fragHi, fragLo, sn, candA);
    k_tau<<<N_ / 256, 256, 0, stream>>>(candA, tauKey);
    hipMemsetAsync(cursor, 0, N_ * sizeof(int), stream);
    k_knnB<<<dim3(N_ / 32, 8), 256, 0, stream>>>(fragHi, fragLo, sn, tauKey, cursor, accept);
    k_select<<<N_ / 256, 256, 0, stream>>>(accept, cursor, idx);
    k_wprep<<<12, 256, 0, stream>>>(ew2[l], ew3[l], w2fH, w2fL, w3fH, w3fL);
    k_gemm128<<<256, 256, 0, stream>>>(nl[l], ew1[l], ab, 1);
    float* etgt = (l == 1) ? E2 : E1;
    k_mlpM<<<N_ / 4, 256, 0, stream>>>(ab, idx, w2fH, w2fL, w3fH, w3fL,
                                       eb1[l], eb2[l], eb3[l], etgt);
    if (l == 0) k_e1n1<<<N_ / 4, 256, 0, stream>>>(E1, n1, S1);
    if (l == 1) k_addinto<<<N_ * H_ / 256, 256, 0, stream>>>(E2, n2);
    if (l == 2) k_addinto<<<N_ * H_ / 256, 256, 0, stream>>>(E1, n3);
  }
  k_final<<<N_ / 4, 256, 0, stream>>>(S1, E2, E1, (float*)d_out);
}

// Round 7
// 1135.985 us; speedup vs baseline: 4.8588x; 1.0514x over previous
//
#include <hip/hip_runtime.h>
#include <math.h>

#define N_ 8192
#define H_ 128
#define E_ 262144
#define K_ 16
#define SLABJ 1024

typedef __attribute__((ext_vector_type(8))) short bshort8;
typedef __attribute__((ext_vector_type(16))) float f32x16;
typedef unsigned long long u64;

// ---------------- degree / normalization ----------------
__global__ void k_deg_init(float* deg) {
  int i = blockIdx.x * 256 + threadIdx.x;
  deg[i] = 1.0f;  // self-loop weight
}

__global__ void k_deg_scatter(const int* __restrict__ ei, const float* __restrict__ ew,
                              float* deg) {
  int e = blockIdx.x * 256 + threadIdx.x;
  atomicAdd(&deg[ei[E_ + e]], ew[e]);
}

__global__ void k_dis(float* deg) {
  int i = blockIdx.x * 256 + threadIdx.x;
  deg[i] = rsqrtf(deg[i]);  // deg >= 1 always
}

// ---------------- one-time CSR build (edge list is static) ----------------
__global__ void k_hist(const int* __restrict__ ei, int* hist) {
  int e = blockIdx.x * 256 + threadIdx.x;
  atomicAdd(&hist[ei[E_ + e]], 1);
}

__global__ void k_scan(int* hist, int* rowptr) {  // 1 block, 256 threads
  __shared__ int part[256];
  __shared__ int partx[257];
  int t = threadIdx.x;
  int base = t * 32;
  int loc[32];
  int s = 0;
#pragma unroll
  for (int i = 0; i < 32; ++i) { loc[i] = s; s += hist[base + i]; }
  part[t] = s;
  __syncthreads();
  if (t == 0) {
    int r = 0;
    for (int i = 0; i < 256; ++i) { partx[i] = r; r += part[i]; }
    partx[256] = r;
  }
  __syncthreads();
  int b = partx[t];
#pragma unroll
  for (int i = 0; i < 32; ++i) {
    rowptr[base + i] = b + loc[i];
    hist[base + i] = b + loc[i];  // hist becomes the scatter cursor
  }
  if (t == 0) rowptr[N_] = partx[256];
}

__global__ void k_edgebuild(const int* __restrict__ ei, const float* __restrict__ ew,
                            const float* __restrict__ dis, int* cursor,
                            int* __restrict__ srcS, float* __restrict__ normS) {
  int e = blockIdx.x * 256 + threadIdx.x;
  int s = ei[e], d = ei[E_ + e];
  int pos = atomicAdd(&cursor[d], 1);
  srcS[pos] = s;
  normS[pos] = dis[s] * ew[e] * dis[d];
}

// ---------------- generic [M x 128] @ [128 x 128] GEMM ----------------
__global__ __launch_bounds__(256) void k_gemm128(const float* __restrict__ A,
                                                 const float* __restrict__ W,
                                                 float* __restrict__ C, int mode) {
  __shared__ float Bs[32 * 132];
  __shared__ float Ast[32 * 33];
  int t = threadIdx.x;
  int r0 = blockIdx.x * 32;
  int ty = t >> 4, tx = t & 15;
  float acc[2][8];
#pragma unroll
  for (int i = 0; i < 2; ++i)
#pragma unroll
    for (int j = 0; j < 8; ++j) acc[i][j] = 0.f;

  for (int kt = 0; kt < 4; ++kt) {
#pragma unroll
    for (int p = 0; p < 16; ++p) {
      int v = t + 256 * p;  // 4096
      int k = v >> 7, c = v & 127;
      int kg = kt * 32 + k;
      float val;
      if (mode == 0) val = W[kg * 128 + c];
      else val = (c < 64) ? (W[kg * 64 + c] - W[(128 + kg) * 64 + c])
                          : W[(128 + kg) * 64 + (c - 64)];
      Bs[k * 132 + c] = val;
    }
#pragma unroll
    for (int p = 0; p < 4; ++p) {
      int v = t + 256 * p;  // 1024
      int r = v >> 5, k = v & 31;
      Ast[k * 33 + r] = A[(r0 + r) * 128 + kt * 32 + k];
    }
    __syncthreads();
    for (int k = 0; k < 32; ++k) {
      float a0 = Ast[k * 33 + ty * 2];
      float a1 = Ast[k * 33 + ty * 2 + 1];
      float4 b0 = *(const float4*)&Bs[k * 132 + tx * 8];
      float4 b1 = *(const float4*)&Bs[k * 132 + tx * 8 + 4];
      float bb[8] = {b0.x, b0.y, b0.z, b0.w, b1.x, b1.y, b1.z, b1.w};
#pragma unroll
      for (int j = 0; j < 8; ++j) {
        acc[0][j] += a0 * bb[j];
        acc[1][j] += a1 * bb[j];
      }
    }
    __syncthreads();
  }
#pragma unroll
  for (int rr = 0; rr < 2; ++rr) {
    float4 o0 = {acc[rr][0], acc[rr][1], acc[rr][2], acc[rr][3]};
    float4 o1 = {acc[rr][4], acc[rr][5], acc[rr][6], acc[rr][7]};
    *(float4*)&C[(r0 + ty * 2 + rr) * 128 + tx * 8] = o0;
    *(float4*)&C[(r0 + ty * 2 + rr) * 128 + tx * 8 + 4] = o1;
  }
}

// ---------------- fused GCN aggregation (CSR gather, no atomics) ----------------
__global__ __launch_bounds__(256) void k_gcn_agg(const float* __restrict__ h,
                                                 const float* __restrict__ dis,
                                                 const int* __restrict__ rowptr,
                                                 const int* __restrict__ srcS,
                                                 const float* __restrict__ normS,
                                                 const float* __restrict__ bg,
                                                 float* __restrict__ n_out,
                                                 float* __restrict__ sn) {
  __shared__ float part[4];
  int t = threadIdx.x;
  int i = blockIdx.x * 2 + (t >> 7);
  int c = t & 127;
  float di = dis[i];
  float a0 = di * di * h[i * 128 + c], a1 = 0.f, a2 = 0.f, a3 = 0.f;
  int e0 = rowptr[i], e1 = rowptr[i + 1];
  int e = e0;
  for (; e + 4 <= e1; e += 4) {
    int s0 = srcS[e], s1 = srcS[e + 1], s2 = srcS[e + 2], s3 = srcS[e + 3];
    float w0 = normS[e], w1 = normS[e + 1], w2 = normS[e + 2], w3 = normS[e + 3];
    a0 += w0 * h[s0 * 128 + c];
    a1 += w1 * h[s1 * 128 + c];
    a2 += w2 * h[s2 * 128 + c];
    a3 += w3 * h[s3 * 128 + c];
  }
  for (; e < e1; ++e) a0 += normS[e] * h[srcS[e] * 128 + c];
  float v = tanhf(a0 + a1 + a2 + a3 + bg[c]);
  n_out[i * 128 + c] = v;
  float vv = v * v;
#pragma unroll
  for (int off = 32; off; off >>= 1) vv += __shfl_down(vv, off, 64);
  if ((t & 63) == 0) part[t >> 6] = vv;
  __syncthreads();
  if ((t & 127) == 0) sn[i] = part[t >> 6] + part[(t >> 6) + 1];
}

// ---------------- bf16 hi/lo split + MFMA fragment packing ----------------
__device__ __forceinline__ unsigned short f2bf_rne(float x) {
  unsigned u = __builtin_bit_cast(unsigned, x);
  unsigned r = ((u >> 16) & 1u) + 0x7fffu;
  return (unsigned short)((u + r) >> 16);
}
__device__ __forceinline__ float bf2f(unsigned short b) {
  unsigned u = ((unsigned)b) << 16;
  return __builtin_bit_cast(float, u);
}

// src: [N][128] fp32 -> fragHi/fragLo: [N/32 tiles][8 ks][64 lanes][8 bf16]
__global__ void k_fragprep(const float* __restrict__ src, bshort8* __restrict__ hiA,
                           bshort8* __restrict__ loA) {
  int t = blockIdx.x * 256 + threadIdx.x;  // N*16 threads
  int j = t >> 4, slot = t & 15;
  const float* p = src + j * 128 + slot * 8;
  float4 f0 = *(const float4*)p;
  float4 f1 = *(const float4*)(p + 4);
  float f[8] = {f0.x, f0.y, f0.z, f0.w, f1.x, f1.y, f1.z, f1.w};
  bshort8 h, l;
#pragma unroll
  for (int i = 0; i < 8; ++i) {
    unsigned short hb = f2bf_rne(f[i]);
    float lf = f[i] - bf2f(hb);
    h[i] = (short)hb;
    l[i] = (short)f2bf_rne(lf);
  }
  int ks = slot >> 1, half = slot & 1;
  int dst = ((j >> 5) * 8 + ks) * 64 + half * 32 + (j & 31);
  hiA[dst] = h;
  loA[dst] = l;
}

// ---------------- packed-key helpers ----------------
__device__ __forceinline__ u64 packkey(float d, int j) {
  unsigned m = __builtin_bit_cast(unsigned, d);
  m = (m & 0x80000000u) ? ~m : (m | 0x80000000u);  // order-preserving fp32->u32
  return (((u64)m) << 32) | (unsigned)j;
}

__device__ __forceinline__ void ins8(u64* tk, u64 x) {
  bool c[8];
#pragma unroll
  for (int s = 0; s < 8; ++s) c[s] = x < tk[s];
#pragma unroll
  for (int s = 7; s >= 1; --s) tk[s] = c[s - 1] ? tk[s - 1] : (c[s] ? x : tk[s]);
  tk[0] = c[0] ? x : tk[0];
}

__device__ __forceinline__ void ins16(u64* tk, u64 x) {
  bool c[16];
#pragma unroll
  for (int s = 0; s < 16; ++s) c[s] = x < tk[s];
#pragma unroll
  for (int s = 15; s >= 1; --s) tk[s] = c[s - 1] ? tk[s - 1] : (c[s] ? x : tk[s]);
  tk[0] = c[0] ? x : tk[0];
}

// ---------------- phase A: per-slab sorted-16 (from per-lane top-8) ----------------
// Scans slabs 0..3. candA[(slab*16+s)*N + q] sorted ascending per slab.
__global__ __launch_bounds__(256, 3) void k_knnA(const bshort8* __restrict__ fragHi,
                                                 const bshort8* __restrict__ fragLo,
                                                 const float* __restrict__ sn,
                                                 u64* __restrict__ candA) {
  __shared__ float snS[SLABJ];        // 4 KB
  __shared__ u64 mbuf[32 * 65];       // 16.6 KB
  int t = threadIdx.x;
  int qtile = blockIdx.x, slab = blockIdx.y;
  int wave = t >> 6, lane = t & 63;
  int q = lane & 31, half = lane >> 5;

#pragma unroll
  for (int p = 0; p < 4; ++p) snS[t + 256 * p] = sn[slab * SLABJ + t + 256 * p];

  bshort8 bHi[8], bLo[8];
#pragma unroll
  for (int ks = 0; ks < 8; ++ks) {
    int o = (qtile * 8 + ks) * 64 + lane;
    bHi[ks] = fragHi[o];
    bLo[ks] = fragLo[o];
  }
  __syncthreads();

  u64 tk[8];
#pragma unroll
  for (int s = 0; s < 8; ++s) tk[s] = ~0ULL;

  for (int ti = 0; ti < 8; ++ti) {
    int jt = slab * 32 + wave * 8 + ti;
    f32x16 accP, accQ;  // split chains: P = hi*hi (8-deep), Q = cross terms (16-deep)
#pragma unroll
    for (int r = 0; r < 16; ++r) { accP[r] = 0.f; accQ[r] = 0.f; }
    {
      bshort8 aH[4], aL[4];
#pragma unroll
      for (int k4 = 0; k4 < 4; ++k4) {
        int o = (jt * 8 + k4) * 64 + lane;
        aH[k4] = fragHi[o];
        aL[k4] = fragLo[o];
      }
#pragma unroll
      for (int k4 = 0; k4 < 4; ++k4) {
        accQ = __builtin_amdgcn_mfma_f32_32x32x16_bf16(aL[k4], bHi[k4], accQ, 0, 0, 0);
        accQ = __builtin_amdgcn_mfma_f32_32x32x16_bf16(aH[k4], bLo[k4], accQ, 0, 0, 0);
        accP = __builtin_amdgcn_mfma_f32_32x32x16_bf16(aH[k4], bHi[k4], accP, 0, 0, 0);
      }
    }
    {
      bshort8 aH[4], aL[4];
#pragma unroll
      for (int k4 = 0; k4 < 4; ++k4) {
        int o = (jt * 8 + 4 + k4) * 64 + lane;
        aH[k4] = fragHi[o];
        aL[k4] = fragLo[o];
      }
#pragma unroll
      for (int k4 = 0; k4 < 4; ++k4) {
        accQ = __builtin_amdgcn_mfma_f32_32x32x16_bf16(aL[k4], bHi[4 + k4], accQ, 0, 0, 0);
        accQ = __builtin_amdgcn_mfma_f32_32x32x16_bf16(aH[k4], bLo[4 + k4], accQ, 0, 0, 0);
        accP = __builtin_amdgcn_mfma_f32_32x32x16_bf16(aH[k4], bHi[4 + k4], accP, 0, 0, 0);
      }
    }

    int jbase = (wave * 8 + ti) * 32;
#pragma unroll
    for (int rp = 0; rp < 8; ++rp) {
      int r0 = rp * 2;
      int row0 = (r0 & 3) + 8 * (r0 >> 2) + 4 * half;
      float d0 = snS[jbase + row0] - 2.0f * (accP[r0] + accQ[r0]);
      float d1 = snS[jbase + row0 + 1] - 2.0f * (accP[r0 + 1] + accQ[r0 + 1]);
      u64 k0 = packkey(d0, slab * SLABJ + jbase + row0);
      u64 k1 = packkey(d1, slab * SLABJ + jbase + row0 + 1);
      u64 km = k0 < k1 ? k0 : k1;
      if (km < tk[7]) {
        if (k0 < tk[7]) ins8(tk, k0);
        if (k1 < tk[7]) ins8(tk, k1);
      }
    }
  }

  int g = wave * 2 + half;  // list id 0..7
  __syncthreads();
#pragma unroll
  for (int s = 0; s < 8; ++s) mbuf[q * 65 + g * 8 + s] = tk[s];
  __syncthreads();
  if (t < 32) {
    int qq = qtile * 32 + t;
    int base = t * 65;
    int h0 = 0, h1 = 0, h2 = 0, h3 = 0, h4 = 0, h5 = 0, h6 = 0, h7 = 0;
    for (int step = 0; step < 16; ++step) {
      u64 best = (h0 < 8) ? mbuf[base + h0] : ~0ULL;
      int bg = 0;
      u64 b;
      b = (h1 < 8) ? mbuf[base + 8 + h1] : ~0ULL;  if (b < best) { best = b; bg = 1; }
      b = (h2 < 8) ? mbuf[base + 16 + h2] : ~0ULL; if (b < best) { best = b; bg = 2; }
      b = (h3 < 8) ? mbuf[base + 24 + h3] : ~0ULL; if (b < best) { best = b; bg = 3; }
      b = (h4 < 8) ? mbuf[base + 32 + h4] : ~0ULL; if (b < best) { best = b; bg = 4; }
      b = (h5 < 8) ? mbuf[base + 40 + h5] : ~0ULL; if (b < best) { best = b; bg = 5; }
      b = (h6 < 8) ? mbuf[base + 48 + h6] : ~0ULL; if (b < best) { best = b; bg = 6; }
      b = (h7 < 8) ? mbuf[base + 56 + h7] : ~0ULL; if (b < best) { best = b; bg = 7; }
      candA[(slab * 16 + step) * N_ + qq] = best;
      h0 += (bg == 0); h1 += (bg == 1); h2 += (bg == 2); h3 += (bg == 3);
      h4 += (bg == 4); h5 += (bg == 5); h6 += (bg == 6); h7 += (bg == 7);
    }
  }
}

// 4-way merge of candA -> sorted top-16 of first half, seeded directly into accept.
// Sets cursor=16 and tau = 16th key. B then only scans the second half.
__global__ void k_tauseed(const u64* __restrict__ candA, u64* __restrict__ accept,
                          int* __restrict__ cursor, u64* __restrict__ tauKey) {
  int q = blockIdx.x * 256 + threadIdx.x;
  int h0 = 0, h1 = 0, h2 = 0, h3 = 0;
  u64 best = 0;
  for (int step = 0; step < 16; ++step) {
    best = candA[h0 * N_ + q];
    int bg = 0;
    u64 b;
    b = candA[(16 + h1) * N_ + q]; if (b < best) { best = b; bg = 1; }
    b = candA[(32 + h2) * N_ + q]; if (b < best) { best = b; bg = 2; }
    b = candA[(48 + h3) * N_ + q]; if (b < best) { best = b; bg = 3; }
    accept[step * N_ + q] = best;
    h0 += (bg == 0); h1 += (bg == 1); h2 += (bg == 2); h3 += (bg == 3);
  }
  tauKey[q] = best;
  cursor[q] = 16;
}

// ---------------- phase B: dense scan of slabs 4..7 with tau filter ----------------
__global__ __launch_bounds__(256, 3) void k_knnB(const bshort8* __restrict__ fragHi,
                                                 const bshort8* __restrict__ fragLo,
                                                 const float* __restrict__ sn,
                                                 const u64* __restrict__ tauKey,
                                                 int* __restrict__ cursor,
                                                 u64* __restrict__ accept) {
  __shared__ float snS[SLABJ];  // 4 KB
  int t = threadIdx.x;
  int qtile = blockIdx.x, slab = blockIdx.y + 4;  // second half only
  int wave = t >> 6, lane = t & 63;
  int q = lane & 31, half = lane >> 5;
  int qg = qtile * 32 + q;

#pragma unroll
  for (int p = 0; p < 4; ++p) snS[t + 256 * p] = sn[slab * SLABJ + t + 256 * p];

  bshort8 bHi[8], bLo[8];
#pragma unroll
  for (int ks = 0; ks < 8; ++ks) {
    int o = (qtile * 8 + ks) * 64 + lane;
    bHi[ks] = fragHi[o];
    bLo[ks] = fragLo[o];
  }
  u64 tau = tauKey[qg];
  __syncthreads();

  for (int ti = 0; ti < 8; ++ti) {
    int jt = slab * 32 + wave * 8 + ti;
    f32x16 accP, accQ;
#pragma unroll
    for (int r = 0; r < 16; ++r) { accP[r] = 0.f; accQ[r] = 0.f; }
    {
      bshort8 aH[4], aL[4];
#pragma unroll
      for (int k4 = 0; k4 < 4; ++k4) {
        int o = (jt * 8 + k4) * 64 + lane;
        aH[k4] = fragHi[o];
        aL[k4] = fragLo[o];
      }
#pragma unroll
      for (int k4 = 0; k4 < 4; ++k4) {
        accQ = __builtin_amdgcn_mfma_f32_32x32x16_bf16(aL[k4], bHi[k4], accQ, 0, 0, 0);
        accQ = __builtin_amdgcn_mfma_f32_32x32x16_bf16(aH[k4], bLo[k4], accQ, 0, 0, 0);
        accP = __builtin_amdgcn_mfma_f32_32x32x16_bf16(aH[k4], bHi[k4], accP, 0, 0, 0);
      }
    }
    {
      bshort8 aH[4], aL[4];
#pragma unroll
      for (int k4 = 0; k4 < 4; ++k4) {
        int o = (jt * 8 + 4 + k4) * 64 + lane;
        aH[k4] = fragHi[o];
        aL[k4] = fragLo[o];
      }
#pragma unroll
      for (int k4 = 0; k4 < 4; ++k4) {
        accQ = __builtin_amdgcn_mfma_f32_32x32x16_bf16(aL[k4], bHi[4 + k4], accQ, 0, 0, 0);
        accQ = __builtin_amdgcn_mfma_f32_32x32x16_bf16(aH[k4], bLo[4 + k4], accQ, 0, 0, 0);
        accP = __builtin_amdgcn_mfma_f32_32x32x16_bf16(aH[k4], bHi[4 + k4], accP, 0, 0, 0);
      }
    }

    int jbase = (wave * 8 + ti) * 32;
#pragma unroll
    for (int rp = 0; rp < 8; ++rp) {
      int r0 = rp * 2;
      int row0 = (r0 & 3) + 8 * (r0 >> 2) + 4 * half;
      float d0 = snS[jbase + row0] - 2.0f * (accP[r0] + accQ[r0]);
      float d1 = snS[jbase + row0 + 1] - 2.0f * (accP[r0 + 1] + accQ[r0 + 1]);
      u64 k0 = packkey(d0, slab * SLABJ + jbase + row0);
      u64 k1 = packkey(d1, slab * SLABJ + jbase + row0 + 1);
      if (k0 <= tau) {
        int pos = atomicAdd(&cursor[qg], 1);
        if (pos < 128) accept[pos * N_ + qg] = k0;
      }
      if (k1 <= tau) {
        int pos = atomicAdd(&cursor[qg], 1);
        if (pos < 128) accept[pos * N_ + qg] = k1;
      }
    }
  }
}

// ---------------- phase C: exact top-16 of survivors ----------------
__global__ void k_select(const u64* __restrict__ accept, const int* __restrict__ cursor,
                         int* __restrict__ idxo) {
  int q = blockIdx.x * 256 + threadIdx.x;
  int c = cursor[q];
  if (c > 128) c = 128;
  u64 tk[16];
#pragma unroll
  for (int s = 0; s < 16; ++s) tk[s] = ~0ULL;
  for (int i = 0; i < c; ++i) {
    u64 x = accept[i * N_ + q];
    if (x < tk[15]) ins16(tk, x);
  }
#pragma unroll
  for (int s = 0; s < 16; ++s) idxo[q * 16 + s] = (int)(unsigned)(tk[s] & 0xffffffffULL);
}

// ---------------- weight frag pre-pack for MFMA MLP ----------------
__global__ void k_wprep(const float* __restrict__ w2, const float* __restrict__ w3,
                        bshort8* __restrict__ w2fH, bshort8* __restrict__ w2fL,
                        bshort8* __restrict__ w3fH, bshort8* __restrict__ w3fL) {
  int id = blockIdx.x * 256 + threadIdx.x;  // 3072
  const float* src;
  bshort8 *dH, *dL;
  int n, k0, slot;
  if (id < 1024) {
    int lane = id & 63, ks = (id >> 6) & 3, nt = id >> 8;
    n = nt * 32 + (lane & 31);
    k0 = ks * 16 + (lane >> 5) * 8;
    src = w2; dH = w2fH; dL = w2fL; slot = id;
  } else {
    int id2 = id - 1024;
    int lane = id2 & 63, ks = (id2 >> 6) & 7, nt = id2 >> 9;
    n = nt * 32 + (lane & 31);
    k0 = ks * 16 + (lane >> 5) * 8;
    src = w3; dH = w3fH; dL = w3fL; slot = id2;
  }
  bshort8 h, l;
#pragma unroll
  for (int i = 0; i < 8; ++i) {
    float v = src[(k0 + i) * 128 + n];
    unsigned short hb = f2bf_rne(v);
    h[i] = (short)hb;
    l[i] = (short)f2bf_rne(v - bf2f(hb));
  }
  dH[slot] = h;
  dL[slot] = l;
}

// ---------------- MFMA EdgeConv MLP (gather h1 -> G2 -> G3 -> max) ----------------
__global__ __launch_bounds__(256, 3) void k_mlpM(
    const float* __restrict__ ab, const int* __restrict__ idx,
    const bshort8* __restrict__ w2fH, const bshort8* __restrict__ w2fL,
    const bshort8* __restrict__ w3fH, const bshort8* __restrict__ w3fL,
    const float* __restrict__ b1g, const float* __restrict__ b2g,
    const float* __restrict__ b3g, float* __restrict__ eout) {
  __shared__ short h1H[64 * 68], h1L[64 * 68];
  __shared__ short h2H[64 * 132], h2L[64 * 132];
  int t = threadIdx.x;
  int n0 = blockIdx.x * 4;
  int w = t >> 6, lane = t & 63, q = lane & 31, half = lane >> 5;

  {
    int r = t >> 2;
    int kc = (t & 3) * 16;
    int node = n0 + (r >> 4);
    int jn = idx[node * 16 + (r & 15)];
    const float* pa = ab + node * 128 + kc;
    const float* pb = ab + jn * 128 + 64 + kc;
    const float* p1 = b1g + kc;
#pragma unroll
    for (int e4 = 0; e4 < 4; ++e4) {
      float4 va = *(const float4*)(pa + e4 * 4);
      float4 vb = *(const float4*)(pb + e4 * 4);
      float4 v1 = *(const float4*)(p1 + e4 * 4);
      float vals[4] = {va.x + vb.x + v1.x, va.y + vb.y + v1.y,
                       va.z + vb.z + v1.z, va.w + vb.w + v1.w};
      unsigned short hs[4], ls[4];
#pragma unroll
      for (int i = 0; i < 4; ++i) {
        float v = fmaxf(vals[i], 0.f);
        hs[i] = f2bf_rne(v);
        ls[i] = f2bf_rne(v - bf2f(hs[i]));
      }
      int off = r * 68 + kc + e4 * 4;
      *(u64*)&h1H[off] = ((u64)(unsigned short)hs[0]) | ((u64)(unsigned short)hs[1] << 16) |
                         ((u64)(unsigned short)hs[2] << 32) | ((u64)(unsigned short)hs[3] << 48);
      *(u64*)&h1L[off] = ((u64)(unsigned short)ls[0]) | ((u64)(unsigned short)ls[1] << 16) |
                         ((u64)(unsigned short)ls[2] << 32) | ((u64)(unsigned short)ls[3] << 48);
    }
  }

  bshort8 c2H[4], c2L[4];
#pragma unroll
  for (int ks = 0; ks < 4; ++ks) {
    c2H[ks] = w2fH[(w * 4 + ks) * 64 + lane];
    c2L[ks] = w2fL[(w * 4 + ks) * 64 + lane];
  }
  bshort8 c3H[8], c3L[8];
#pragma unroll
  for (int ks = 0; ks < 8; ++ks) {
    c3H[ks] = w3fH[(w * 8 + ks) * 64 + lane];
    c3L[ks] = w3fL[(w * 8 + ks) * 64 + lane];
  }
  float bias2 = b2g[w * 32 + q];
  float bias3 = b3g[w * 32 + q];
  __syncthreads();

#pragma unroll
  for (int rt = 0; rt < 2; ++rt) {
    f32x16 acc;
#pragma unroll
    for (int r = 0; r < 16; ++r) acc[r] = 0.f;
#pragma unroll
    for (int ks = 0; ks < 4; ++ks) {
      int off = (rt * 32 + q) * 68 + ks * 16 + half * 8;
      union { bshort8 v; u64 u[2]; } aH, aL;
      aH.u[0] = *(const u64*)&h1H[off];
      aH.u[1] = *(const u64*)&h1H[off + 4];
      aL.u[0] = *(const u64*)&h1L[off];
      aL.u[1] = *(const u64*)&h1L[off + 4];
      acc = __builtin_amdgcn_mfma_f32_32x32x16_bf16(aL.v, c2H[ks], acc, 0, 0, 0);
      acc = __builtin_amdgcn_mfma_f32_32x32x16_bf16(aH.v, c2L[ks], acc, 0, 0, 0);
      acc = __builtin_amdgcn_mfma_f32_32x32x16_bf16(aH.v, c2H[ks], acc, 0, 0, 0);
    }
#pragma unroll
    for (int reg = 0; reg < 16; ++reg) {
      int row = rt * 32 + (reg & 3) + 8 * (reg >> 2) + 4 * half;
      float v = fmaxf(acc[reg] + bias2, 0.f);
      unsigned short hb = f2bf_rne(v);
      h2H[row * 132 + w * 32 + q] = (short)hb;
      h2L[row * 132 + w * 32 + q] = (short)f2bf_rne(v - bf2f(hb));
    }
  }
  __syncthreads();

#pragma unroll
  for (int rt = 0; rt < 2; ++rt) {
    f32x16 acc;
#pragma unroll
    for (int r = 0; r < 16; ++r) acc[r] = 0.f;
#pragma unroll
    for (int ks = 0; ks < 8; ++ks) {
      int off = (rt * 32 + q) * 132 + ks * 16 + half * 8;
      union { bshort8 v; u64 u[2]; } aH, aL;
      aH.u[0] = *(const u64*)&h2H[off];
      aH.u[1] = *(const u64*)&h2H[off + 4];
      aL.u[0] = *(const u64*)&h2L[off];
      aL.u[1] = *(const u64*)&h2L[off + 4];
      acc = __builtin_amdgcn_mfma_f32_32x32x16_bf16(aL.v, c3H[ks], acc, 0, 0, 0);
      acc = __builtin_amdgcn_mfma_f32_32x32x16_bf16(aH.v, c3L[ks], acc, 0, 0, 0);
      acc = __builtin_amdgcn_mfma_f32_32x32x16_bf16(aH.v, c3H[ks], acc, 0, 0, 0);
    }
    float mA = -INFINITY, mB = -INFINITY;
#pragma unroll
    for (int reg = 0; reg < 8; ++reg) mA = fmaxf(mA, acc[reg]);
#pragma unroll
    for (int reg = 8; reg < 16; ++reg) mB = fmaxf(mB, acc[reg]);
    mA = fmaxf(mA, __shfl_xor(mA, 32, 64));
    mB = fmaxf(mB, __shfl_xor(mB, 32, 64));
    int col = w * 32 + q;
    if (half == 0) eout[(n0 + rt * 2) * 128 + col] = mA + bias3;
    else eout[(n0 + rt * 2 + 1) * 128 + col] = mB + bias3;
  }
}

// ---------------- small epilogues ----------------
__global__ void k_e1n1(const float* __restrict__ e1, const float* __restrict__ n1,
                       float* s1) {
  int t = threadIdx.x;
  int node = blockIdx.x * 4 + (t >> 6);
  int lane = t & 63;
  float v0 = e1[node * 128 + lane] + n1[node * 128 + lane];
  float v1 = e1[node * 128 + 64 + lane] + n1[node * 128 + 64 + lane];
  float ss = v0 * v0 + v1 * v1;
#pragma unroll
  for (int off = 32; off; off >>= 1) ss += __shfl_down(ss, off, 64);
  if (lane == 0) s1[node] = sqrtf(ss);
}

__global__ void k_addinto(float* __restrict__ e, const float* __restrict__ n) {
  int v = blockIdx.x * 256 + threadIdx.x;
  e[v] += n[v];
}

__global__ void k_final(const float* __restrict__ s1, const float* __restrict__ e2n2,
                        const float* __restrict__ e3n3, float* __restrict__ out) {
  int t = threadIdx.x;
  int node = blockIdx.x * 4 + (t >> 6);
  int lane = t & 63;
  float s = s1[node];
  float z0 = s * e2n2[node * 128 + lane] * e3n3[node * 128 + lane];
  float z1 = s * e2n2[node * 128 + 64 + lane] * e3n3[node * 128 + 64 + lane];
  float m = fmaxf(z0, z1);
#pragma unroll
  for (int off = 32; off; off >>= 1) m = fmaxf(m, __shfl_xor(m, off, 64));
  float ex = expf(z0 - m) + expf(z1 - m);
#pragma unroll
  for (int off = 32; off; off >>= 1) ex += __shfl_xor(ex, off, 64);
  float lse = m + logf(ex);
  out[node * 128 + lane] = z0 - lse;
  out[node * 128 + 64 + lane] = z1 - lse;
}

// ---------------- host ----------------
extern "C" void kernel_launch(void* const* d_in, const int* in_sizes, int n_in,
                              void* d_out, int out_size, void* d_ws, size_t ws_size,
                              hipStream_t stream) {
  (void)in_sizes; (void)n_in; (void)out_size;
  const float* x  = (const float*)d_in[0];
  const int* ei   = (const int*)d_in[1];
  const float* ew = (const float*)d_in[2];
  const float* wg[3] = {(const float*)d_in[3], (const float*)d_in[5], (const float*)d_in[7]};
  const float* bg[3] = {(const float*)d_in[4], (const float*)d_in[6], (const float*)d_in[8]};
  const float* ew1[3] = {(const float*)d_in[9],  (const float*)d_in[15], (const float*)d_in[21]};
  const float* eb1[3] = {(const float*)d_in[10], (const float*)d_in[16], (const float*)d_in[22]};
  const float* ew2[3] = {(const float*)d_in[11], (const float*)d_in[17], (const float*)d_in[23]};
  const float* eb2[3] = {(const float*)d_in[12], (const float*)d_in[18], (const float*)d_in[24]};
  const float* ew3[3] = {(const float*)d_in[13], (const float*)d_in[19], (const float*)d_in[25]};
  const float* eb3[3] = {(const float*)d_in[14], (const float*)d_in[20], (const float*)d_in[26]};

  size_t small = (size_t)(22 * N_ + (N_ + 256) + N_ + 2 * E_);
  size_t need = (small + (size_t)7 * N_ * H_) * sizeof(float);
  if (ws_size < need) return;

  float* ws  = (float*)d_ws;
  float* dis = ws;
  float* sn  = ws + N_;
  float* S1  = ws + 2 * N_;
  int* idx   = (int*)(ws + 3 * N_);
  u64* tauKey = (u64*)(ws + 19 * N_);
  int* cursor = (int*)(ws + 21 * N_);
  int* rowptr = (int*)(ws + 22 * N_);
  int* hist   = rowptr + N_ + 256;
  int* srcS   = hist + N_;
  float* normS = (float*)(srcS + E_);
  float* h   = normS + E_;
  float* n1  = h + N_ * H_;
  float* n2  = n1 + N_ * H_;
  float* n3  = n2 + N_ * H_;
  float* E2  = n3 + N_ * H_;          // e2 / e2+n2 (live l=1..final)
  float* E1  = E2 + N_ * H_;          // e1 (l=0), e3+n3 (l=2); scratch during knn
  float* ab  = E1 + N_ * H_;          // scratch; candA home during knn

  bshort8* fragHi = (bshort8*)h;                 // 2 MB (dead after knnB)
  bshort8* fragLo = (bshort8*)(h + N_ * H_ / 2); // 2 MB
  u64* candA  = (u64*)ab;                        // 64 x N u64 (phase A output)
  u64* accept = (u64*)E1;                        // 128 x N u64 (seeded + phase B)
  bshort8* w2fH = (bshort8*)h;                   // weight frags alias h (post-knn)
  bshort8* w2fL = w2fH + 1024;
  bshort8* w3fH = w2fL + 1024;
  bshort8* w3fL = w3fH + 2048;

  float* nl[3] = {n1, n2, n3};

  k_deg_init<<<N_ / 256, 256, 0, stream>>>(dis);
  k_deg_scatter<<<E_ / 256, 256, 0, stream>>>(ei, ew, dis);
  k_dis<<<N_ / 256, 256, 0, stream>>>(dis);
  hipMemsetAsync(hist, 0, N_ * sizeof(int), stream);
  k_hist<<<E_ / 256, 256, 0, stream>>>(ei, hist);
  k_scan<<<1, 256, 0, stream>>>(hist, rowptr);
  k_edgebuild<<<E_ / 256, 256, 0, stream>>>(ei, ew, dis, hist, srcS, normS);

  for (int l = 0; l < 3; ++l) {
    const float* inp = (l == 0) ? x : nl[l - 1];
    k_gemm128<<<256, 256, 0, stream>>>(inp, wg[l], h, 0);
    k_gcn_agg<<<N_ / 2, 256, 0, stream>>>(h, dis, rowptr, srcS, normS, bg[l], nl[l], sn);
    k_fragprep<<<N_ * 16 / 256, 256, 0, stream>>>(nl[l], fragHi, fragLo);
    k_knnA<<<dim3(N_ / 32, 4), 256, 0, stream>>>(fragHi, fragLo, sn, candA);
    k_tauseed<<<N_ / 256, 256, 0, stream>>>(candA, accept, cursor, tauKey);
    k_knnB<<<dim3(N_ / 32, 4), 256, 0, stream>>>(fragHi, fragLo, sn, tauKey, cursor, accept);
    k_select<<<N_ / 256, 256, 0, stream>>>(accept, cursor, idx);
    k_wprep<<<12, 256, 0, stream>>>(ew2[l], ew3[l], w2fH, w2fL, w3fH, w3fL);
    k_gemm128<<<256, 256, 0, stream>>>(nl[l], ew1[l], ab, 1);
    float* etgt = (l == 1) ? E2 : E1;
    k_mlpM<<<N_ / 4, 256, 0, stream>>>(ab, idx, w2fH, w2fL, w3fH, w3fL,
                                       eb1[l], eb2[l], eb3[l], etgt);
    if (l == 0) k_e1n1<<<N_ / 4, 256, 0, stream>>>(E1, n1, S1);
    if (l == 1) k_addinto<<<N_ * H_ / 256, 256, 0, stream>>>(E2, n2);
    if (l == 2) k_addinto<<<N_ * H_ / 256, 256, 0, stream>>>(E1, n3);
  }
  k_final<<<N_ / 4, 256, 0, stream>>>(S1, E2, E1, (float*)d_out);
}